// Round 11
// baseline (898.459 us; speedup 1.0000x reference)
//
#include <hip/hip_runtime.h>
#include <math.h>

#define BB 4
#define SS 8192
#define HID 256
#define NHEADS 4
#define DH 64
#define FFD 1024
#define NLAYERS 2
#define NHASH 2
#define NBUCK 128
#define NROT 64          // NBUCK/2
#define NSEQ (NHASH*SS)  // 16384
#define NCH (NSEQ/64)    // 256 chunks of 64
#define MASKVAL -1e5f
#define PBE ((size_t)SS*HID)

typedef __bf16 bf16x8 __attribute__((ext_vector_type(8)));
typedef float f32x4 __attribute__((ext_vector_type(4)));

__device__ __forceinline__ unsigned short f2bf(float x) {
    unsigned u = __float_as_uint(x);
    unsigned r = (u >> 16) & 1;
    u += 0x7fffu + r;              // RNE
    return (unsigned short)(u >> 16);
}
__device__ __forceinline__ float bf2f(unsigned short h) {
    return __uint_as_float(((unsigned)h) << 16);
}
__device__ __forceinline__ unsigned scale2(unsigned u, float qs) {
    float lo = __uint_as_float(u << 16) * qs;
    float hi = __uint_as_float(u & 0xffff0000u) * qs;
    return (unsigned)f2bf(lo) | (((unsigned)f2bf(hi)) << 16);
}

// ---------------- block reduce (256 threads = 4 waves) ----------------
__device__ __forceinline__ float block_reduce_sum(float v, float* red) {
#pragma unroll
    for (int off = 32; off; off >>= 1) v += __shfl_down(v, off);
    int lane = threadIdx.x & 63, wid = threadIdx.x >> 6;
    __syncthreads();
    if (lane == 0) red[wid] = v;
    __syncthreads();
    return red[0] + red[1] + red[2] + red[3];
}

// ---------------- LayerNorm over 256 -> bf16 out, optional stats ----------------
template <bool STATS>
__global__ void ln256_kernel(const float* __restrict__ x, const float* __restrict__ g,
                             const float* __restrict__ b, unsigned short* __restrict__ ybf,
                             float* __restrict__ mu_out, float* __restrict__ rstd_out) {
    int row = blockIdx.x, tid = threadIdx.x;
    __shared__ float red[4];
    float v = x[(size_t)row * HID + tid];
    float mu = block_reduce_sum(v, red) * (1.f / 256.f);
    float d = v - mu;
    float var = block_reduce_sum(d * d, red) * (1.f / 256.f);
    float rstd = rsqrtf(var + 1e-12f);
    float out = d * rstd * g[tid] + b[tid];
    ybf[(size_t)row * HID + tid] = f2bf(out);
    if (STATS && tid == 0) { mu_out[row] = mu; rstd_out[row] = rstd; }
}

// ---------------- Final LayerNorm over concat(512) ----------------
__global__ void ln512_kernel(const float* __restrict__ a, const float* __restrict__ hd,
                             const float* __restrict__ g, const float* __restrict__ b,
                             float* __restrict__ out) {
    int row = blockIdx.x, tid = threadIdx.x;
    __shared__ float red[4];
    float x0 = a[(size_t)row * HID + tid];
    float x1 = hd[(size_t)row * HID + tid];
    float mu = block_reduce_sum(x0 + x1, red) * (1.f / 512.f);
    float d0 = x0 - mu, d1 = x1 - mu;
    float var = block_reduce_sum(d0 * d0 + d1 * d1, red) * (1.f / 512.f);
    float r = rsqrtf(var + 1e-12f);
    out[(size_t)row * 512 + tid]       = d0 * r * g[tid] + b[tid];
    out[(size_t)row * 512 + 256 + tid] = d1 * r * g[256 + tid] + b[256 + tid];
}

// ---------------- weight transpose + f32->bf16: W[K,N] -> Wt[N,K] ----------------
__global__ void wconv_kernel(const float* __restrict__ W, unsigned short* __restrict__ Wt,
                             int K, int N) {
    __shared__ float t[32][33];
    int k0 = blockIdx.x * 32, n0 = blockIdx.y * 32;
    int tx = threadIdx.x & 31, ty = threadIdx.x >> 5;  // 32 x 8
#pragma unroll
    for (int i = 0; i < 32; i += 8) t[ty + i][tx] = W[(size_t)(k0 + ty + i) * N + n0 + tx];
    __syncthreads();
#pragma unroll
    for (int i = 0; i < 32; i += 8) Wt[(size_t)(n0 + ty + i) * K + k0 + tx] = f2bf(t[tx][ty + i]);
}

// ---------------- fused fp32 Wqk GEMM + LN-on-the-fly + qk-norm + LSH hash ----------------
// K-step 32, float4-vectorized staging (A along k with inline LN, B direct). FMA order over kk
// ascending 0..255 is unchanged vs R10 -> bit-identical buckets.
__global__ __launch_bounds__(256) void qkhash_kernel(
    const float* __restrict__ hid, const float* __restrict__ mu,
    const float* __restrict__ rstd, const float* __restrict__ gamma,
    const float* __restrict__ beta, const float* __restrict__ Wqk,
    const float* __restrict__ rot, unsigned short* __restrict__ kb,
    float* __restrict__ qscale, int* __restrict__ buckets) {
    __shared__ float As[32][68];
    __shared__ float Bs[32][68];
    __shared__ float QsT[64][68];     // [d][row]
    __shared__ float rotLDS[64][132]; // [d][col], both hash rounds
    int bm = blockIdx.x * 64;
    int h = blockIdx.y;
    int tid = threadIdx.x;
    int tx = tid & 15, ty = tid >> 4;
    float acc[4][4] = {};
    for (int k0 = 0; k0 < HID; k0 += 32) {
        // A tile: 64 rows x 32 k, float4 along k, LN applied inline
#pragma unroll
        for (int t = 0; t < 2; ++t) {
            int e = tid + t * 256;            // 0..511
            int lr = e >> 3;                  // local row 0..63
            int kc = (e & 7) * 4;             // 0,4,...,28
            int row = bm + lr;
            float4 x = *(const float4*)(hid + (size_t)row * HID + k0 + kc);
            float m_ = mu[row], rs = rstd[row];
            float4 g4 = *(const float4*)(gamma + k0 + kc);
            float4 b4 = *(const float4*)(beta + k0 + kc);
            As[kc + 0][lr] = (x.x - m_) * rs * g4.x + b4.x;
            As[kc + 1][lr] = (x.y - m_) * rs * g4.y + b4.y;
            As[kc + 2][lr] = (x.z - m_) * rs * g4.z + b4.z;
            As[kc + 3][lr] = (x.w - m_) * rs * g4.w + b4.w;
        }
        // B tile: 32 k x 64 n, float4 direct copy
#pragma unroll
        for (int t = 0; t < 2; ++t) {
            int e = tid + t * 256;            // 0..511
            int kk = e >> 4;                  // 0..31
            int n4 = (e & 15) * 4;            // 0..60
            *(float4*)&Bs[kk][n4] = *(const float4*)(Wqk + (size_t)(k0 + kk) * HID + h * DH + n4);
        }
        __syncthreads();
#pragma unroll
        for (int kk = 0; kk < 32; ++kk) {
            float4 a4 = *(float4*)&As[kk][ty * 4];
            float4 b4 = *(float4*)&Bs[kk][tx * 4];
            float a0[4] = {a4.x, a4.y, a4.z, a4.w};
            float b0[4] = {b4.x, b4.y, b4.z, b4.w};
#pragma unroll
            for (int i = 0; i < 4; ++i)
#pragma unroll
                for (int j = 0; j < 4; ++j) acc[i][j] += a0[i] * b0[j];
        }
        __syncthreads();
    }
    // per-row ||q||^2 over this head's 64 dims (reduce across tx group)
    float ssq_[4];
#pragma unroll
    for (int i = 0; i < 4; ++i) {
        float s = 0;
#pragma unroll
        for (int j = 0; j < 4; ++j) s += acc[i][j] * acc[i][j];
        ssq_[i] = s;
    }
#pragma unroll
    for (int mask = 1; mask <= 8; mask <<= 1)
#pragma unroll
        for (int i = 0; i < 4; ++i) ssq_[i] += __shfl_xor(ssq_[i], mask);
    // write k_bf + qscale
#pragma unroll
    for (int i = 0; i < 4; ++i) {
        int row = bm + ty * 4 + i;
        float nrm = fmaxf(sqrtf(ssq_[i]), 1e-12f);
        float sc = 0.125f / nrm;
        ushort4 kv;
        kv.x = f2bf(acc[i][0] * sc); kv.y = f2bf(acc[i][1] * sc);
        kv.z = f2bf(acc[i][2] * sc); kv.w = f2bf(acc[i][3] * sc);
        *(ushort4*)(kb + (size_t)row * HID + h * DH + tx * 4) = kv;
        if (tx == 0) qscale[(size_t)row * NHEADS + h] = 8.f * nrm;
    }
    // stage QsT via contiguous float4 in transposed layout
#pragma unroll
    for (int j = 0; j < 4; ++j) {
        float4 v = make_float4(acc[0][j], acc[1][j], acc[2][j], acc[3][j]);
        *(float4*)&QsT[tx * 4 + j][ty * 4] = v;
    }
    // load rot[h]: both rounds
    const float* rp = rot + (size_t)h * DH * NHASH * NROT;
#pragma unroll
    for (int t = 0; t < 8; ++t) {
        int e = tid + t * 256;
        int d = e >> 5, c4 = e & 31;
        *(float4*)&rotLDS[d][c4 * 4] = *(const float4*)(rp + d * 128 + c4 * 4);
    }
    __syncthreads();
    // hash: rotated = qk_tile @ rot, argmax over [rot, -rot]
    float acc2[4][8] = {};
#pragma unroll 2
    for (int d = 0; d < 64; ++d) {
        float4 a4 = *(float4*)&QsT[d][ty * 4];
        float a_[4] = {a4.x, a4.y, a4.z, a4.w};
        float4 b0 = *(float4*)&rotLDS[d][tx * 8];
        float4 b1v = *(float4*)&rotLDS[d][tx * 8 + 4];
#pragma unroll
        for (int i = 0; i < 4; ++i) {
            acc2[i][0] += a_[i] * b0.x;  acc2[i][1] += a_[i] * b0.y;
            acc2[i][2] += a_[i] * b0.z;  acc2[i][3] += a_[i] * b0.w;
            acc2[i][4] += a_[i] * b1v.x; acc2[i][5] += a_[i] * b1v.y;
            acc2[i][6] += a_[i] * b1v.z; acc2[i][7] += a_[i] * b1v.w;
        }
    }
    int n = tx >> 3;
#pragma unroll
    for (int i = 0; i < 4; ++i) {
        float bp = -3.4e38f, bn = -3.4e38f;
        int ipx = 0, inx = 0;
#pragma unroll
        for (int j = 0; j < 8; ++j) {
            float v = acc2[i][j];
            int r = ((tx & 7) * 8 + j);
            if (v > bp)  { bp = v;  ipx = r; }
            if (-v > bn) { bn = -v; inx = r; }
        }
#pragma unroll
        for (int mask = 1; mask <= 4; mask <<= 1) {
            float obp = __shfl_xor(bp, mask); int oip = __shfl_xor(ipx, mask);
            float obn = __shfl_xor(bn, mask); int oin = __shfl_xor(inx, mask);
            if (obp > bp || (obp == bp && oip < ipx)) { bp = obp; ipx = oip; }
            if (obn > bn || (obn == bn && oin < inx)) { bn = obn; inx = oin; }
        }
        if ((tx & 7) == 0) {
            int bucket = (bn > bp) ? (NROT + inx) : ipx;
            int row = bm + ty * 4 + i;
            int bb = row >> 13, sl = row & (SS - 1);
            buckets[(size_t)bb * NHEADS * NSEQ + h * NSEQ + n * SS + sl] = bucket + n * NBUCK;
        }
    }
}

// ---------------- bf16 MFMA GEMM: C[M,N] = A[M,K] @ Bt[N,K]^T (+epilogue) ----------------
// EPI: 1 = bias+relu -> bf16, 2 = f32 C += acc, 3 = f32 C += acc + bias, 4 = store bf16,
//      5 = f32 C = Csrc + acc, 6 = f32 C = Csrc + acc + bias
template <int EPI>
__global__ __launch_bounds__(256) void mfma_gemm(
    const unsigned short* __restrict__ A, const unsigned short* __restrict__ Bt,
    const float* __restrict__ bias, void* __restrict__ Cv,
    int M, int N, int K, const float* __restrict__ Csrc) {
    __shared__ unsigned short Asl[128 * 64];
    __shared__ unsigned short Bsl[128 * 64];
    int bm = blockIdx.x * 128, bn = blockIdx.y * 128;
    int tid = threadIdx.x;
    int wave = tid >> 6, lane = tid & 63;
    int wm = (wave >> 1) * 64, wn = (wave & 1) * 64;
    int lrow = lane & 15, lk = lane >> 4;
    f32x4 zero = {0.f, 0.f, 0.f, 0.f};
    f32x4 acc[4][4];
#pragma unroll
    for (int i = 0; i < 4; ++i)
#pragma unroll
        for (int j = 0; j < 4; ++j) acc[i][j] = zero;

    for (int k0 = 0; k0 < K; k0 += 64) {
#pragma unroll
        for (int t = 0; t < 4; ++t) {
            int e = tid + t * 256;
            int r = e >> 3, kc = (e & 7) * 8;
            int4 v = *(const int4*)(A + (size_t)(bm + r) * K + k0 + kc);
            *(int4*)((char*)Asl + r * 128 + ((kc * 2) ^ ((r & 7) << 4))) = v;
        }
#pragma unroll
        for (int t = 0; t < 4; ++t) {
            int e = tid + t * 256;
            int r = e >> 3, kc = (e & 7) * 8;
            int4 v = *(const int4*)(Bt + (size_t)(bn + r) * K + k0 + kc);
            *(int4*)((char*)Bsl + r * 128 + ((kc * 2) ^ ((r & 7) << 4))) = v;
        }
        __syncthreads();
#pragma unroll
        for (int kk = 0; kk < 2; ++kk) {
            int klocal = kk * 32 + lk * 8;
            bf16x8 af[4], bfv[4];
#pragma unroll
            for (int fm = 0; fm < 4; ++fm) {
                int r = wm + fm * 16 + lrow;
                af[fm] = *(const bf16x8*)((const char*)Asl + r * 128 + ((klocal * 2) ^ ((r & 7) << 4)));
            }
#pragma unroll
            for (int fn = 0; fn < 4; ++fn) {
                int r = wn + fn * 16 + lrow;
                bfv[fn] = *(const bf16x8*)((const char*)Bsl + r * 128 + ((klocal * 2) ^ ((r & 7) << 4)));
            }
#pragma unroll
            for (int fm = 0; fm < 4; ++fm)
#pragma unroll
                for (int fn = 0; fn < 4; ++fn)
                    acc[fm][fn] = __builtin_amdgcn_mfma_f32_16x16x32_bf16(af[fm], bfv[fn], acc[fm][fn], 0, 0, 0);
        }
        __syncthreads();
    }
#pragma unroll
    for (int fm = 0; fm < 4; ++fm)
#pragma unroll
        for (int fn = 0; fn < 4; ++fn) {
            int col = bn + wn + fn * 16 + lrow;
#pragma unroll
            for (int r = 0; r < 4; ++r) {
                int row = bm + wm + fm * 16 + lk * 4 + r;
                float v = acc[fm][fn][r];
                if (EPI == 1) {
                    v += bias[col]; v = fmaxf(v, 0.f);
                    ((unsigned short*)Cv)[(size_t)row * N + col] = f2bf(v);
                } else if (EPI == 2) {
                    ((float*)Cv)[(size_t)row * N + col] += v;
                } else if (EPI == 3) {
                    ((float*)Cv)[(size_t)row * N + col] += v + bias[col];
                } else if (EPI == 4) {
                    ((unsigned short*)Cv)[(size_t)row * N + col] = f2bf(v);
                } else if (EPI == 5) {
                    ((float*)Cv)[(size_t)row * N + col] = Csrc[(size_t)row * N + col] + v;
                } else {
                    ((float*)Cv)[(size_t)row * N + col] = Csrc[(size_t)row * N + col] + v + bias[col];
                }
            }
        }
}

// ---------------- parallel stable counting sort: 256 threads, one block per (b,h) ----------------
__global__ __launch_bounds__(256) void sort_kernel(const int* __restrict__ buckets,
                                                   int* __restrict__ sort_idx,
                                                   int* __restrict__ inv) {
    int bh = blockIdx.x;
    const int* bk = buckets + (size_t)bh * NSEQ;
    int* sj = sort_idx + (size_t)bh * NSEQ;
    int* ij = inv + (size_t)bh * NSEQ;
    __shared__ unsigned short cnt[256][258];  // [bin][thread-col], 132 KB
    __shared__ int colsum[256];
    int tid = threadIdx.x;
    unsigned* cz = (unsigned*)&cnt[0][0];
#pragma unroll
    for (int t = 0; t < 129; ++t) cz[tid * 129 + t] = 0;
    __syncthreads();
    int base = tid * 64;  // thread owns 64 contiguous items -> stability
    for (int j = 0; j < 64; j += 4) {
        int4 b4 = *(const int4*)(bk + base + j);
        cnt[b4.x][tid]++; cnt[b4.y][tid]++; cnt[b4.z][tid]++; cnt[b4.w][tid]++;
    }
    __syncthreads();
    {
        int run = 0;
        for (int c = 0; c < 256; ++c) { int v = cnt[tid][c]; cnt[tid][c] = (unsigned short)run; run += v; }
        colsum[tid] = run;
    }
    __syncthreads();
    if (tid == 0) {
        int run = 0;
        for (int j = 0; j < 256; ++j) { int c = colsum[j]; colsum[j] = run; run += c; }
    }
    __syncthreads();
    {
        int bs = colsum[tid];
        for (int c = 0; c < 256; ++c) cnt[tid][c] = (unsigned short)(cnt[tid][c] + bs);
    }
    __syncthreads();
    for (int j = 0; j < 64; j += 4) {
        int4 b4 = *(const int4*)(bk + base + j);
        int i0 = base + j;
        int r;
        r = cnt[b4.x][tid]++; sj[r] = i0;     ij[i0]     = r;
        r = cnt[b4.y][tid]++; sj[r] = i0 + 1; ij[i0 + 1] = r;
        r = cnt[b4.z][tid]++; sj[r] = i0 + 2; ij[i0 + 2] = r;
        r = cnt[b4.w][tid]++; sj[r] = i0 + 3; ij[i0 + 3] = r;
    }
}

// ---------------- MFMA chunked LSH attention (Ps overlays Ks; 45.8 KB LDS) ----------------
// grid (NCH, NHEADS, 2) -- blockIdx.z = local batch within the half
__global__ __launch_bounds__(256) void attn_mfma(
    const unsigned short* __restrict__ kbf, const unsigned short* __restrict__ vbf,
    const float* __restrict__ qscale, const int* __restrict__ sort_idx,
    unsigned short* __restrict__ out_s, float* __restrict__ logit_s) {
    __shared__ unsigned short Qs[64][72];
    __shared__ unsigned short KsPs[128][72];     // Ks during QK^T; Ps [64][136] overlay after
    __shared__ unsigned short VT[64][136];
    __shared__ int qid[64];
    __shared__ int kid[128];
    unsigned short (*Ks)[72] = KsPs;
    unsigned short (*Ps)[136] = (unsigned short(*)[136])&KsPs[0][0];
    int c = blockIdx.x, h = blockIdx.y, z = blockIdx.z;
    kbf += (size_t)z * PBE;
    vbf += (size_t)z * PBE;
    qscale += (size_t)z * SS * NHEADS;
    sort_idx += (size_t)z * NHEADS * NSEQ;
    out_s += (size_t)z * NHEADS * NSEQ * DH;
    logit_s += (size_t)z * NHEADS * NSEQ;
    int tid = threadIdx.x;
    const int* si = sort_idx + (size_t)h * NSEQ;
    int cprev = (c == 0) ? (NCH - 1) : (c - 1);
    if (tid < 64) qid[tid] = si[c * 64 + tid];
    else if (tid < 192) {
        int k = tid - 64;
        kid[k] = (k < 64) ? si[cprev * 64 + k] : si[c * 64 + (k - 64)];
    }
    __syncthreads();
    // Q = K * qscale (reconstruct unnormalized q)
#pragma unroll
    for (int t = 0; t < 2; ++t) {
        int e = tid + t * 256;
        int row = e >> 3, seg = e & 7;
        int s = qid[row] & (SS - 1);
        float qs = qscale[(size_t)s * NHEADS + h];
        int4 raw = *(const int4*)(kbf + ((size_t)s * HID + h * DH + seg * 8));
        int4 o;
        o.x = (int)scale2((unsigned)raw.x, qs);
        o.y = (int)scale2((unsigned)raw.y, qs);
        o.z = (int)scale2((unsigned)raw.z, qs);
        o.w = (int)scale2((unsigned)raw.w, qs);
        *(int4*)&Qs[row][seg * 8] = o;
    }
#pragma unroll
    for (int t = 0; t < 4; ++t) {
        int e = tid + t * 256;
        int row = e >> 3, seg = e & 7;
        int s = kid[row] & (SS - 1);
        *(int4*)&Ks[row][seg * 8] = *(const int4*)(kbf + ((size_t)s * HID + h * DH + seg * 8));
    }
#pragma unroll
    for (int t = 0; t < 4; ++t) {
        int e = tid + t * 256;
        int row = e >> 3, seg = e & 7;
        int s = kid[row] & (SS - 1);
        ushort4 a = *(const ushort4*)(vbf + ((size_t)s * HID + h * DH + seg * 8));
        ushort4 bq = *(const ushort4*)(vbf + ((size_t)s * HID + h * DH + seg * 8 + 4));
        int d0 = seg * 8;
        VT[d0 + 0][row] = a.x;  VT[d0 + 1][row] = a.y;  VT[d0 + 2][row] = a.z;  VT[d0 + 3][row] = a.w;
        VT[d0 + 4][row] = bq.x; VT[d0 + 5][row] = bq.y; VT[d0 + 6][row] = bq.z; VT[d0 + 7][row] = bq.w;
    }
    __syncthreads();
    int wave = tid >> 6, lane = tid & 63;
    int lrow = lane & 15, lk = lane >> 4;
    f32x4 zero = {0.f, 0.f, 0.f, 0.f};
    f32x4 sacc[8];
#pragma unroll
    for (int fn = 0; fn < 8; ++fn) sacc[fn] = zero;
#pragma unroll
    for (int kk = 0; kk < 2; ++kk) {
        bf16x8 af = *(const bf16x8*)&Qs[wave * 16 + lrow][kk * 32 + lk * 8];
#pragma unroll
        for (int fn = 0; fn < 8; ++fn) {
            bf16x8 bv = *(const bf16x8*)&Ks[fn * 16 + lrow][kk * 32 + lk * 8];
            sacc[fn] = __builtin_amdgcn_mfma_f32_16x16x32_bf16(af, bv, sacc[fn], 0, 0, 0);
        }
    }
    __syncthreads();   // all Qs/Ks reads complete before Ps overlays Ks
    int myq[4];
#pragma unroll
    for (int r = 0; r < 4; ++r) myq[r] = qid[wave * 16 + lk * 4 + r];
#pragma unroll
    for (int fn = 0; fn < 8; ++fn) {
        int kv = kid[lrow + fn * 16];
#pragma unroll
        for (int r = 0; r < 4; ++r)
            if (myq[r] == kv) sacc[fn][r] = MASKVAL;
    }
    float mx[4] = {-3.4e38f, -3.4e38f, -3.4e38f, -3.4e38f};
#pragma unroll
    for (int fn = 0; fn < 8; ++fn)
#pragma unroll
        for (int r = 0; r < 4; ++r) mx[r] = fmaxf(mx[r], sacc[fn][r]);
#pragma unroll
    for (int m = 1; m <= 8; m <<= 1)
#pragma unroll
        for (int r = 0; r < 4; ++r) mx[r] = fmaxf(mx[r], __shfl_xor(mx[r], m));
    float se[4] = {0.f, 0.f, 0.f, 0.f};
#pragma unroll
    for (int fn = 0; fn < 8; ++fn)
#pragma unroll
        for (int r = 0; r < 4; ++r) se[r] += __expf(sacc[fn][r] - mx[r]);
#pragma unroll
    for (int m = 1; m <= 8; m <<= 1)
#pragma unroll
        for (int r = 0; r < 4; ++r) se[r] += __shfl_xor(se[r], m);
    float lg[4];
#pragma unroll
    for (int r = 0; r < 4; ++r) lg[r] = mx[r] + __logf(se[r]);
#pragma unroll
    for (int fn = 0; fn < 8; ++fn)
#pragma unroll
        for (int r = 0; r < 4; ++r)
            Ps[wave * 16 + lk * 4 + r][lrow + fn * 16] = f2bf(__expf(sacc[fn][r] - lg[r]));
    if (lrow == 0) {
#pragma unroll
        for (int r = 0; r < 4; ++r)
            logit_s[(size_t)h * NSEQ + c * 64 + wave * 16 + lk * 4 + r] = lg[r];
    }
    __syncthreads();
    f32x4 oacc[4];
#pragma unroll
    for (int fn = 0; fn < 4; ++fn) oacc[fn] = zero;
#pragma unroll
    for (int ks = 0; ks < 4; ++ks) {
        bf16x8 af = *(const bf16x8*)&Ps[wave * 16 + lrow][ks * 32 + lk * 8];
#pragma unroll
        for (int fn = 0; fn < 4; ++fn) {
            bf16x8 bv = *(const bf16x8*)&VT[fn * 16 + lrow][ks * 32 + lk * 8];
            oacc[fn] = __builtin_amdgcn_mfma_f32_16x16x32_bf16(af, bv, oacc[fn], 0, 0, 0);
        }
    }
#pragma unroll
    for (int fn = 0; fn < 4; ++fn)
#pragma unroll
        for (int r = 0; r < 4; ++r) {
            int qrow = c * 64 + wave * 16 + lk * 4 + r;
            out_s[((size_t)h * NSEQ + qrow) * DH + lrow + fn * 16] = f2bf(oacc[fn][r]);
        }
}

// ---------------- unsort + combine hash rounds (per 2-batch half) ----------------
__global__ void combine_kernel(const unsigned short* __restrict__ out_s,
                               const float* __restrict__ logit_s,
                               const int* __restrict__ inv, unsigned short* __restrict__ attn_comb) {
    size_t gid = (size_t)blockIdx.x * 256 + threadIdx.x;  // 2*H*S*16 threads
    int d4 = gid & 15;
    size_t r = gid >> 4;
    int s = (int)(r & (SS - 1));
    int h = (int)((r >> 13) & 3);
    int bl = (int)(r >> 15);
    size_t hb = (size_t)(bl * NHEADS + h) * NSEQ;
    int j0 = inv[hb + s];
    int j1 = inv[hb + SS + s];
    float l0 = logit_s[hb + j0];
    float l1 = logit_s[hb + j1];
    float mxv = fmaxf(l0, l1);
    float e0 = __expf(l0 - mxv), e1 = __expf(l1 - mxv);
    float is = 1.f / (e0 + e1);
    float w0 = e0 * is, w1 = e1 * is;
    ushort4 u0 = *(const ushort4*)(out_s + (hb + j0) * DH + d4 * 4);
    ushort4 u1 = *(const ushort4*)(out_s + (hb + j1) * DH + d4 * 4);
    ushort4 o;
    o.x = f2bf(w0 * bf2f(u0.x) + w1 * bf2f(u1.x));
    o.y = f2bf(w0 * bf2f(u0.y) + w1 * bf2f(u1.y));
    o.z = f2bf(w0 * bf2f(u0.z) + w1 * bf2f(u1.z));
    o.w = f2bf(w0 * bf2f(u0.w) + w1 * bf2f(u1.w));
    *(ushort4*)(attn_comb + ((size_t)bl * SS + s) * HID + h * DH + d4 * 4) = o;
}

// ---------------- launch ----------------
extern "C" void kernel_launch(void* const* d_in, const int* in_sizes, int n_in,
                              void* d_out, int out_size, void* d_ws, size_t ws_size,
                              hipStream_t stream) {
    const float* hs  = (const float*)d_in[0];
    const float* g1  = (const float*)d_in[1];
    const float* b1  = (const float*)d_in[2];
    const float* Wqk = (const float*)d_in[3];
    const float* Wv  = (const float*)d_in[4];
    const float* Wo  = (const float*)d_in[5];
    const float* rot = (const float*)d_in[6];
    const float* g2  = (const float*)d_in[7];
    const float* b2  = (const float*)d_in[8];
    const float* W1  = (const float*)d_in[9];
    const float* bf1 = (const float*)d_in[10];
    const float* W2  = (const float*)d_in[11];
    const float* bf2 = (const float*)d_in[12];
    const float* gf  = (const float*)d_in[13];
    const float* bff = (const float*)d_in[14];

    const size_t NE = (size_t)BB * SS * HID;    // 8,388,608
    const size_t MROWS = (size_t)BB * SS;       // 32768

    // ---- d_ws layout (~74.7 MB) ----
    float* f = (float*)d_ws;
    float* attn_out = f;                               // NE f32
    float* hidden   = f + NE;                          // NE f32
    float* mu       = f + 2 * NE;                      // 32768
    float* rstd     = mu + MROWS;                      // 32768
    float* qscale   = rstd + MROWS;                    // B*S*H = 131072
    float* logit_all = qscale + MROWS * NHEADS;        // B*H*NSEQ = 262144
    int* sortx = (int*)(logit_all + (size_t)BB * NHEADS * NSEQ);
    int* invx  = sortx + (size_t)BB * NHEADS * NSEQ;
    int* buckx = invx + (size_t)BB * NHEADS * NSEQ;
    unsigned short* wbf = (unsigned short*)(buckx + (size_t)BB * NHEADS * NSEQ);

    // ---- d_out scratch (4 slots of 4,194,304 floats) ----
    float* o = (float*)d_out;
    unsigned short* abuf = (unsigned short*)o;              // slot0: xln_bf / attn_comb / h_ln
    unsigned short* outs = (unsigned short*)(o + 4194304);  // slot1: half-batch sorted attn out
    unsigned short* k_bf = (unsigned short*)(o + 8388608);  // slot2
    unsigned short* v_bf = (unsigned short*)(o + 12582912); // slot3
    unsigned short* ffbuf = outs;                           // phase D: slots 1-2

    for (int l = 0; l < NLAYERS; ++l) {
        unsigned short* wl = wbf + (size_t)l * 655360;
        wconv_kernel<<<dim3(HID / 32, HID / 32), 256, 0, stream>>>(Wv + (size_t)l * HID * HID, wl, HID, HID);
        wconv_kernel<<<dim3(HID / 32, HID / 32), 256, 0, stream>>>(Wo + (size_t)l * HID * HID, wl + 65536, HID, HID);
        wconv_kernel<<<dim3(HID / 32, FFD / 32), 256, 0, stream>>>(W1 + (size_t)l * HID * FFD, wl + 131072, HID, FFD);
        wconv_kernel<<<dim3(FFD / 32, HID / 32), 256, 0, stream>>>(W2 + (size_t)l * FFD * HID, wl + 393216, FFD, HID);
    }

    for (int l = 0; l < NLAYERS; ++l) {
        const float* g1l = g1 + l * HID;
        const float* b1l = b1 + l * HID;
        const float* Wqkl = Wqk + (size_t)l * HID * HID;
        const float* rotl = rot + (size_t)l * NHEADS * DH * NHASH * NROT;
        const float* g2l = g2 + l * HID;
        const float* b2l = b2 + l * HID;
        const float* bf1l = bf1 + l * FFD;
        const float* bf2l = bf2 + l * HID;
        unsigned short* Wv_t = wbf + (size_t)l * 655360;
        unsigned short* Wo_t = Wv_t + 65536;
        unsigned short* W1_t = Wv_t + 131072;
        unsigned short* W2_t = Wv_t + 393216;
        const float* hid_in = (l == 0) ? hs : hidden;   // layer 0 reads inputs directly

        // ---- phase A (all-batch): LN(+stats) -> fused Wqk+hash -> Wv ----
        ln256_kernel<true><<<MROWS, 256, 0, stream>>>(hid_in, g1l, b1l, abuf, mu, rstd);
        qkhash_kernel<<<dim3(MROWS / 64, NHEADS), 256, 0, stream>>>(
            hid_in, mu, rstd, g1l, b1l, Wqkl, rotl, k_bf, qscale, buckx);
        mfma_gemm<4><<<dim3(MROWS / 128, HID / 128), 256, 0, stream>>>(abuf, Wv_t, nullptr, v_bf, MROWS, HID, HID, nullptr);

        // ---- phase B: sort all (b,h) ----
        sort_kernel<<<BB * NHEADS, 256, 0, stream>>>(buckx, sortx, invx);

        // ---- phase C: attention in two 2-batch halves, then all-batch Wo ----
        for (int half = 0; half < 2; ++half) {
            size_t boff = (size_t)half * 2;
            attn_mfma<<<dim3(NCH, NHEADS, 2), 256, 0, stream>>>(
                k_bf + boff * PBE, v_bf + boff * PBE, qscale + boff * SS * NHEADS,
                sortx + boff * NHEADS * NSEQ, outs, logit_all + boff * NHEADS * NSEQ);
            combine_kernel<<<(2 * NHEADS * SS * 16) / 256, 256, 0, stream>>>(
                outs, logit_all + boff * NHEADS * NSEQ, invx + boff * NHEADS * NSEQ,
                abuf + boff * PBE);
        }
        if (l == 0)
            mfma_gemm<5><<<dim3(MROWS / 128, HID / 128), 256, 0, stream>>>(abuf, Wo_t, nullptr, attn_out, MROWS, HID, HID, hs);
        else
            mfma_gemm<2><<<dim3(MROWS / 128, HID / 128), 256, 0, stream>>>(abuf, Wo_t, nullptr, attn_out, MROWS, HID, HID, nullptr);

        // ---- phase D: FF (two M=16384 halves through slots 1-2) ----
        ln256_kernel<false><<<MROWS, 256, 0, stream>>>(attn_out, g2l, b2l, abuf, nullptr, nullptr);
        for (int half = 0; half < 2; ++half) {
            const unsigned short* hln_h = abuf + (size_t)half * 16384 * HID;
            float* hid_h = hidden + (size_t)half * 16384 * HID;
            mfma_gemm<1><<<dim3(16384 / 128, FFD / 128), 256, 0, stream>>>(hln_h, W1_t, bf1l, ffbuf, 16384, FFD, HID, nullptr);
            if (l == 0)
                mfma_gemm<6><<<dim3(16384 / 128, HID / 128), 256, 0, stream>>>(ffbuf, W2_t, bf2l, hid_h, 16384, HID, FFD, hs + (size_t)half * 16384 * HID);
            else
                mfma_gemm<3><<<dim3(16384 / 128, HID / 128), 256, 0, stream>>>(ffbuf, W2_t, bf2l, hid_h, 16384, HID, FFD, nullptr);
        }
    }
    ln512_kernel<<<MROWS, 256, 0, stream>>>(attn_out, hidden, gf, bff, (float*)d_out);
}

// Round 12
// 775.073 us; speedup vs baseline: 1.1592x; 1.1592x over previous
//
#include <hip/hip_runtime.h>
#include <math.h>

#define BB 4
#define SS 8192
#define HID 256
#define NHEADS 4
#define DH 64
#define FFD 1024
#define NLAYERS 2
#define NHASH 2
#define NBUCK 128
#define NROT 64          // NBUCK/2
#define NSEQ (NHASH*SS)  // 16384
#define NCH (NSEQ/64)    // 256 chunks of 64
#define MASKVAL -1e5f
#define PBE ((size_t)SS*HID)
#define HNSD ((size_t)NHEADS*NSEQ*DH)   // per-batch outs elems (ushort)

typedef __bf16 bf16x8 __attribute__((ext_vector_type(8)));
typedef float f32x4 __attribute__((ext_vector_type(4)));

__device__ __forceinline__ unsigned short f2bf(float x) {
    unsigned u = __float_as_uint(x);
    unsigned r = (u >> 16) & 1;
    u += 0x7fffu + r;              // RNE
    return (unsigned short)(u >> 16);
}
__device__ __forceinline__ float bf2f(unsigned short h) {
    return __uint_as_float(((unsigned)h) << 16);
}
__device__ __forceinline__ unsigned scale2(unsigned u, float qs) {
    float lo = __uint_as_float(u << 16) * qs;
    float hi = __uint_as_float(u & 0xffff0000u) * qs;
    return (unsigned)f2bf(lo) | (((unsigned)f2bf(hi)) << 16);
}

// ---------------- block reduce (256 threads = 4 waves) ----------------
__device__ __forceinline__ float block_reduce_sum(float v, float* red) {
#pragma unroll
    for (int off = 32; off; off >>= 1) v += __shfl_down(v, off);
    int lane = threadIdx.x & 63, wid = threadIdx.x >> 6;
    __syncthreads();
    if (lane == 0) red[wid] = v;
    __syncthreads();
    return red[0] + red[1] + red[2] + red[3];
}

// ---------------- LayerNorm over 256 -> bf16 out, optional stats ----------------
template <bool STATS>
__global__ void ln256_kernel(const float* __restrict__ x, const float* __restrict__ g,
                             const float* __restrict__ b, unsigned short* __restrict__ ybf,
                             float* __restrict__ mu_out, float* __restrict__ rstd_out) {
    int row = blockIdx.x, tid = threadIdx.x;
    __shared__ float red[4];
    float v = x[(size_t)row * HID + tid];
    float mu = block_reduce_sum(v, red) * (1.f / 256.f);
    float d = v - mu;
    float var = block_reduce_sum(d * d, red) * (1.f / 256.f);
    float rstd = rsqrtf(var + 1e-12f);
    float out = d * rstd * g[tid] + b[tid];
    ybf[(size_t)row * HID + tid] = f2bf(out);
    if (STATS && tid == 0) { mu_out[row] = mu; rstd_out[row] = rstd; }
}

// ---------------- Final LayerNorm over concat(512) ----------------
__global__ void ln512_kernel(const float* __restrict__ a, const float* __restrict__ hd,
                             const float* __restrict__ g, const float* __restrict__ b,
                             float* __restrict__ out) {
    int row = blockIdx.x, tid = threadIdx.x;
    __shared__ float red[4];
    float x0 = a[(size_t)row * HID + tid];
    float x1 = hd[(size_t)row * HID + tid];
    float mu = block_reduce_sum(x0 + x1, red) * (1.f / 512.f);
    float d0 = x0 - mu, d1 = x1 - mu;
    float var = block_reduce_sum(d0 * d0 + d1 * d1, red) * (1.f / 512.f);
    float r = rsqrtf(var + 1e-12f);
    out[(size_t)row * 512 + tid]       = d0 * r * g[tid] + b[tid];
    out[(size_t)row * 512 + 256 + tid] = d1 * r * g[256 + tid] + b[256 + tid];
}

// ---------------- weight transpose + f32->bf16, layer batched: W[K,N] -> Wt[N,K] ----------------
__global__ void wconv_kernel(const float* __restrict__ W, unsigned short* __restrict__ Wt,
                             int K, int N, size_t wstride, size_t tstride) {
    __shared__ float t[32][33];
    int l = blockIdx.z;
    W += (size_t)l * wstride;
    Wt += (size_t)l * tstride;
    int k0 = blockIdx.x * 32, n0 = blockIdx.y * 32;
    int tx = threadIdx.x & 31, ty = threadIdx.x >> 5;  // 32 x 8
#pragma unroll
    for (int i = 0; i < 32; i += 8) t[ty + i][tx] = W[(size_t)(k0 + ty + i) * N + n0 + tx];
    __syncthreads();
#pragma unroll
    for (int i = 0; i < 32; i += 8) Wt[(size_t)(n0 + ty + i) * K + k0 + tx] = f2bf(t[tx][ty + i]);
}

// ---------------- fused fp32 Wqk GEMM + LN-on-the-fly + qk-norm + LSH hash ----------------
// R10 structure exactly (K-step 16, separate LDS arrays, 59.9 KB): measured 135 us.
__global__ __launch_bounds__(256) void qkhash_kernel(
    const float* __restrict__ hid, const float* __restrict__ mu,
    const float* __restrict__ rstd, const float* __restrict__ gamma,
    const float* __restrict__ beta, const float* __restrict__ Wqk,
    const float* __restrict__ rot, unsigned short* __restrict__ kb,
    float* __restrict__ qscale, int* __restrict__ buckets) {
    __shared__ float As[16][68];
    __shared__ float Bs[16][68];
    __shared__ float QsT[64][68];     // [d][row]
    __shared__ float rotLDS[64][132]; // [d][col], both hash rounds
    int bm = blockIdx.x * 64;
    int h = blockIdx.y;
    int tid = threadIdx.x;
    int tx = tid & 15, ty = tid >> 4;
    float acc[4][4] = {};
    for (int k0 = 0; k0 < HID; k0 += 16) {
#pragma unroll
        for (int t = 0; t < 4; ++t) {
            int e = tid + t * 256;
            int m = e >> 4, kk = e & 15;
            int row = bm + m;
            float x = hid[(size_t)row * HID + k0 + kk];
            As[kk][m] = (x - mu[row]) * rstd[row] * gamma[k0 + kk] + beta[k0 + kk];
        }
#pragma unroll
        for (int t = 0; t < 4; ++t) {
            int e = tid + t * 256;
            int kk = e >> 6, n = e & 63;
            Bs[kk][n] = Wqk[(size_t)(k0 + kk) * HID + h * DH + n];
        }
        __syncthreads();
#pragma unroll
        for (int kk = 0; kk < 16; ++kk) {
            float4 a4 = *(float4*)&As[kk][ty * 4];
            float4 b4 = *(float4*)&Bs[kk][tx * 4];
            float a0[4] = {a4.x, a4.y, a4.z, a4.w};
            float b0[4] = {b4.x, b4.y, b4.z, b4.w};
#pragma unroll
            for (int i = 0; i < 4; ++i)
#pragma unroll
                for (int j = 0; j < 4; ++j) acc[i][j] += a0[i] * b0[j];
        }
        __syncthreads();
    }
    // per-row ||q||^2 over this head's 64 dims (reduce across tx group)
    float ssq_[4];
#pragma unroll
    for (int i = 0; i < 4; ++i) {
        float s = 0;
#pragma unroll
        for (int j = 0; j < 4; ++j) s += acc[i][j] * acc[i][j];
        ssq_[i] = s;
    }
#pragma unroll
    for (int mask = 1; mask <= 8; mask <<= 1)
#pragma unroll
        for (int i = 0; i < 4; ++i) ssq_[i] += __shfl_xor(ssq_[i], mask);
    // write k_bf + qscale
#pragma unroll
    for (int i = 0; i < 4; ++i) {
        int row = bm + ty * 4 + i;
        float nrm = fmaxf(sqrtf(ssq_[i]), 1e-12f);
        float sc = 0.125f / nrm;
        ushort4 kv;
        kv.x = f2bf(acc[i][0] * sc); kv.y = f2bf(acc[i][1] * sc);
        kv.z = f2bf(acc[i][2] * sc); kv.w = f2bf(acc[i][3] * sc);
        *(ushort4*)(kb + (size_t)row * HID + h * DH + tx * 4) = kv;
        if (tx == 0) qscale[(size_t)row * NHEADS + h] = 8.f * nrm;
    }
    // stage QsT via contiguous float4 in transposed layout
#pragma unroll
    for (int j = 0; j < 4; ++j) {
        float4 v = make_float4(acc[0][j], acc[1][j], acc[2][j], acc[3][j]);
        *(float4*)&QsT[tx * 4 + j][ty * 4] = v;
    }
    // load rot[h]: both rounds
    const float* rp = rot + (size_t)h * DH * NHASH * NROT;
#pragma unroll
    for (int t = 0; t < 8; ++t) {
        int e = tid + t * 256;
        int d = e >> 5, c4 = e & 31;
        *(float4*)&rotLDS[d][c4 * 4] = *(const float4*)(rp + d * 128 + c4 * 4);
    }
    __syncthreads();
    // hash: rotated = qk_tile @ rot, argmax over [rot, -rot]
    float acc2[4][8] = {};
#pragma unroll 2
    for (int d = 0; d < 64; ++d) {
        float4 a4 = *(float4*)&QsT[d][ty * 4];
        float a_[4] = {a4.x, a4.y, a4.z, a4.w};
        float4 b0 = *(float4*)&rotLDS[d][tx * 8];
        float4 b1v = *(float4*)&rotLDS[d][tx * 8 + 4];
#pragma unroll
        for (int i = 0; i < 4; ++i) {
            acc2[i][0] += a_[i] * b0.x;  acc2[i][1] += a_[i] * b0.y;
            acc2[i][2] += a_[i] * b0.z;  acc2[i][3] += a_[i] * b0.w;
            acc2[i][4] += a_[i] * b1v.x; acc2[i][5] += a_[i] * b1v.y;
            acc2[i][6] += a_[i] * b1v.z; acc2[i][7] += a_[i] * b1v.w;
        }
    }
    int n = tx >> 3;
#pragma unroll
    for (int i = 0; i < 4; ++i) {
        float bp = -3.4e38f, bn = -3.4e38f;
        int ipx = 0, inx = 0;
#pragma unroll
        for (int j = 0; j < 8; ++j) {
            float v = acc2[i][j];
            int r = ((tx & 7) * 8 + j);
            if (v > bp)  { bp = v;  ipx = r; }
            if (-v > bn) { bn = -v; inx = r; }
        }
#pragma unroll
        for (int mask = 1; mask <= 4; mask <<= 1) {
            float obp = __shfl_xor(bp, mask); int oip = __shfl_xor(ipx, mask);
            float obn = __shfl_xor(bn, mask); int oin = __shfl_xor(inx, mask);
            if (obp > bp || (obp == bp && oip < ipx)) { bp = obp; ipx = oip; }
            if (obn > bn || (obn == bn && oin < inx)) { bn = obn; inx = oin; }
        }
        if ((tx & 7) == 0) {
            int bucket = (bn > bp) ? (NROT + inx) : ipx;
            int row = bm + ty * 4 + i;
            int bb = row >> 13, sl = row & (SS - 1);
            buckets[(size_t)bb * NHEADS * NSEQ + h * NSEQ + n * SS + sl] = bucket + n * NBUCK;
        }
    }
}

// ---------------- bf16 MFMA GEMM: C[M,N] = A[M,K] @ Bt[N,K]^T (+epilogue) ----------------
// EPI: 1 = bias+relu -> bf16, 2 = f32 C += acc, 3 = f32 C += acc + bias, 4 = store bf16,
//      5 = f32 C = Csrc + acc, 6 = f32 C = Csrc + acc + bias
template <int EPI>
__global__ __launch_bounds__(256) void mfma_gemm(
    const unsigned short* __restrict__ A, const unsigned short* __restrict__ Bt,
    const float* __restrict__ bias, void* __restrict__ Cv,
    int M, int N, int K, const float* __restrict__ Csrc) {
    __shared__ unsigned short Asl[128 * 64];
    __shared__ unsigned short Bsl[128 * 64];
    int bm = blockIdx.x * 128, bn = blockIdx.y * 128;
    int tid = threadIdx.x;
    int wave = tid >> 6, lane = tid & 63;
    int wm = (wave >> 1) * 64, wn = (wave & 1) * 64;
    int lrow = lane & 15, lk = lane >> 4;
    f32x4 zero = {0.f, 0.f, 0.f, 0.f};
    f32x4 acc[4][4];
#pragma unroll
    for (int i = 0; i < 4; ++i)
#pragma unroll
        for (int j = 0; j < 4; ++j) acc[i][j] = zero;

    for (int k0 = 0; k0 < K; k0 += 64) {
#pragma unroll
        for (int t = 0; t < 4; ++t) {
            int e = tid + t * 256;
            int r = e >> 3, kc = (e & 7) * 8;
            int4 v = *(const int4*)(A + (size_t)(bm + r) * K + k0 + kc);
            *(int4*)((char*)Asl + r * 128 + ((kc * 2) ^ ((r & 7) << 4))) = v;
        }
#pragma unroll
        for (int t = 0; t < 4; ++t) {
            int e = tid + t * 256;
            int r = e >> 3, kc = (e & 7) * 8;
            int4 v = *(const int4*)(Bt + (size_t)(bn + r) * K + k0 + kc);
            *(int4*)((char*)Bsl + r * 128 + ((kc * 2) ^ ((r & 7) << 4))) = v;
        }
        __syncthreads();
#pragma unroll
        for (int kk = 0; kk < 2; ++kk) {
            int klocal = kk * 32 + lk * 8;
            bf16x8 af[4], bfv[4];
#pragma unroll
            for (int fm = 0; fm < 4; ++fm) {
                int r = wm + fm * 16 + lrow;
                af[fm] = *(const bf16x8*)((const char*)Asl + r * 128 + ((klocal * 2) ^ ((r & 7) << 4)));
            }
#pragma unroll
            for (int fn = 0; fn < 4; ++fn) {
                int r = wn + fn * 16 + lrow;
                bfv[fn] = *(const bf16x8*)((const char*)Bsl + r * 128 + ((klocal * 2) ^ ((r & 7) << 4)));
            }
#pragma unroll
            for (int fm = 0; fm < 4; ++fm)
#pragma unroll
                for (int fn = 0; fn < 4; ++fn)
                    acc[fm][fn] = __builtin_amdgcn_mfma_f32_16x16x32_bf16(af[fm], bfv[fn], acc[fm][fn], 0, 0, 0);
        }
        __syncthreads();
    }
#pragma unroll
    for (int fm = 0; fm < 4; ++fm)
#pragma unroll
        for (int fn = 0; fn < 4; ++fn) {
            int col = bn + wn + fn * 16 + lrow;
#pragma unroll
            for (int r = 0; r < 4; ++r) {
                int row = bm + wm + fm * 16 + lk * 4 + r;
                float v = acc[fm][fn][r];
                if (EPI == 1) {
                    v += bias[col]; v = fmaxf(v, 0.f);
                    ((unsigned short*)Cv)[(size_t)row * N + col] = f2bf(v);
                } else if (EPI == 2) {
                    ((float*)Cv)[(size_t)row * N + col] += v;
                } else if (EPI == 3) {
                    ((float*)Cv)[(size_t)row * N + col] += v + bias[col];
                } else if (EPI == 4) {
                    ((unsigned short*)Cv)[(size_t)row * N + col] = f2bf(v);
                } else if (EPI == 5) {
                    ((float*)Cv)[(size_t)row * N + col] = Csrc[(size_t)row * N + col] + v;
                } else {
                    ((float*)Cv)[(size_t)row * N + col] = Csrc[(size_t)row * N + col] + v + bias[col];
                }
            }
        }
}

// ---------------- parallel stable counting sort: 256 threads, one block per (b,h) ----------------
__global__ __launch_bounds__(256) void sort_kernel(const int* __restrict__ buckets,
                                                   int* __restrict__ sort_idx,
                                                   int* __restrict__ inv) {
    int bh = blockIdx.x;
    const int* bk = buckets + (size_t)bh * NSEQ;
    int* sj = sort_idx + (size_t)bh * NSEQ;
    int* ij = inv + (size_t)bh * NSEQ;
    __shared__ unsigned short cnt[256][258];  // [bin][thread-col], 132 KB
    __shared__ int colsum[256];
    int tid = threadIdx.x;
    unsigned* cz = (unsigned*)&cnt[0][0];
#pragma unroll
    for (int t = 0; t < 129; ++t) cz[tid * 129 + t] = 0;
    __syncthreads();
    int base = tid * 64;  // thread owns 64 contiguous items -> stability
    for (int j = 0; j < 64; j += 4) {
        int4 b4 = *(const int4*)(bk + base + j);
        cnt[b4.x][tid]++; cnt[b4.y][tid]++; cnt[b4.z][tid]++; cnt[b4.w][tid]++;
    }
    __syncthreads();
    {
        int run = 0;
        for (int c = 0; c < 256; ++c) { int v = cnt[tid][c]; cnt[tid][c] = (unsigned short)run; run += v; }
        colsum[tid] = run;
    }
    __syncthreads();
    if (tid == 0) {
        int run = 0;
        for (int j = 0; j < 256; ++j) { int c = colsum[j]; colsum[j] = run; run += c; }
    }
    __syncthreads();
    {
        int bs = colsum[tid];
        for (int c = 0; c < 256; ++c) cnt[tid][c] = (unsigned short)(cnt[tid][c] + bs);
    }
    __syncthreads();
    for (int j = 0; j < 64; j += 4) {
        int4 b4 = *(const int4*)(bk + base + j);
        int i0 = base + j;
        int r;
        r = cnt[b4.x][tid]++; sj[r] = i0;     ij[i0]     = r;
        r = cnt[b4.y][tid]++; sj[r] = i0 + 1; ij[i0 + 1] = r;
        r = cnt[b4.z][tid]++; sj[r] = i0 + 2; ij[i0 + 2] = r;
        r = cnt[b4.w][tid]++; sj[r] = i0 + 3; ij[i0 + 3] = r;
    }
}

// ---------------- MFMA chunked LSH attention (Ps overlays Ks; 45.8 KB LDS) ----------------
// grid (NCH, NHEADS, 4) -- blockIdx.z = batch; outs split lo (batches 0-1) / hi (2-3)
__global__ __launch_bounds__(256) void attn_mfma(
    const unsigned short* __restrict__ kbf, const unsigned short* __restrict__ vbf,
    const float* __restrict__ qscale, const int* __restrict__ sort_idx,
    unsigned short* __restrict__ outs_lo, unsigned short* __restrict__ outs_hi,
    float* __restrict__ logit_s) {
    __shared__ unsigned short Qs[64][72];
    __shared__ unsigned short KsPs[128][72];     // Ks during QK^T; Ps [64][136] overlay after
    __shared__ unsigned short VT[64][136];
    __shared__ int qid[64];
    __shared__ int kid[128];
    unsigned short (*Ks)[72] = KsPs;
    unsigned short (*Ps)[136] = (unsigned short(*)[136])&KsPs[0][0];
    int c = blockIdx.x, h = blockIdx.y, z = blockIdx.z;
    kbf += (size_t)z * PBE;
    vbf += (size_t)z * PBE;
    qscale += (size_t)z * SS * NHEADS;
    sort_idx += (size_t)z * NHEADS * NSEQ;
    unsigned short* out_s = (z < 2) ? (outs_lo + (size_t)z * HNSD) : (outs_hi + (size_t)(z - 2) * HNSD);
    logit_s += (size_t)z * NHEADS * NSEQ;
    int tid = threadIdx.x;
    const int* si = sort_idx + (size_t)h * NSEQ;
    int cprev = (c == 0) ? (NCH - 1) : (c - 1);
    if (tid < 64) qid[tid] = si[c * 64 + tid];
    else if (tid < 192) {
        int k = tid - 64;
        kid[k] = (k < 64) ? si[cprev * 64 + k] : si[c * 64 + (k - 64)];
    }
    __syncthreads();
    // Q = K * qscale (reconstruct unnormalized q)
#pragma unroll
    for (int t = 0; t < 2; ++t) {
        int e = tid + t * 256;
        int row = e >> 3, seg = e & 7;
        int s = qid[row] & (SS - 1);
        float qs = qscale[(size_t)s * NHEADS + h];
        int4 raw = *(const int4*)(kbf + ((size_t)s * HID + h * DH + seg * 8));
        int4 o;
        o.x = (int)scale2((unsigned)raw.x, qs);
        o.y = (int)scale2((unsigned)raw.y, qs);
        o.z = (int)scale2((unsigned)raw.z, qs);
        o.w = (int)scale2((unsigned)raw.w, qs);
        *(int4*)&Qs[row][seg * 8] = o;
    }
#pragma unroll
    for (int t = 0; t < 4; ++t) {
        int e = tid + t * 256;
        int row = e >> 3, seg = e & 7;
        int s = kid[row] & (SS - 1);
        *(int4*)&Ks[row][seg * 8] = *(const int4*)(kbf + ((size_t)s * HID + h * DH + seg * 8));
    }
#pragma unroll
    for (int t = 0; t < 4; ++t) {
        int e = tid + t * 256;
        int row = e >> 3, seg = e & 7;
        int s = kid[row] & (SS - 1);
        ushort4 a = *(const ushort4*)(vbf + ((size_t)s * HID + h * DH + seg * 8));
        ushort4 bq = *(const ushort4*)(vbf + ((size_t)s * HID + h * DH + seg * 8 + 4));
        int d0 = seg * 8;
        VT[d0 + 0][row] = a.x;  VT[d0 + 1][row] = a.y;  VT[d0 + 2][row] = a.z;  VT[d0 + 3][row] = a.w;
        VT[d0 + 4][row] = bq.x; VT[d0 + 5][row] = bq.y; VT[d0 + 6][row] = bq.z; VT[d0 + 7][row] = bq.w;
    }
    __syncthreads();
    int wave = tid >> 6, lane = tid & 63;
    int lrow = lane & 15, lk = lane >> 4;
    f32x4 zero = {0.f, 0.f, 0.f, 0.f};
    f32x4 sacc[8];
#pragma unroll
    for (int fn = 0; fn < 8; ++fn) sacc[fn] = zero;
#pragma unroll
    for (int kk = 0; kk < 2; ++kk) {
        bf16x8 af = *(const bf16x8*)&Qs[wave * 16 + lrow][kk * 32 + lk * 8];
#pragma unroll
        for (int fn = 0; fn < 8; ++fn) {
            bf16x8 bv = *(const bf16x8*)&Ks[fn * 16 + lrow][kk * 32 + lk * 8];
            sacc[fn] = __builtin_amdgcn_mfma_f32_16x16x32_bf16(af, bv, sacc[fn], 0, 0, 0);
        }
    }
    __syncthreads();   // all Qs/Ks reads complete before Ps overlays Ks
    int myq[4];
#pragma unroll
    for (int r = 0; r < 4; ++r) myq[r] = qid[wave * 16 + lk * 4 + r];
#pragma unroll
    for (int fn = 0; fn < 8; ++fn) {
        int kv = kid[lrow + fn * 16];
#pragma unroll
        for (int r = 0; r < 4; ++r)
            if (myq[r] == kv) sacc[fn][r] = MASKVAL;
    }
    float mx[4] = {-3.4e38f, -3.4e38f, -3.4e38f, -3.4e38f};
#pragma unroll
    for (int fn = 0; fn < 8; ++fn)
#pragma unroll
        for (int r = 0; r < 4; ++r) mx[r] = fmaxf(mx[r], sacc[fn][r]);
#pragma unroll
    for (int m = 1; m <= 8; m <<= 1)
#pragma unroll
        for (int r = 0; r < 4; ++r) mx[r] = fmaxf(mx[r], __shfl_xor(mx[r], m));
    float se[4] = {0.f, 0.f, 0.f, 0.f};
#pragma unroll
    for (int fn = 0; fn < 8; ++fn)
#pragma unroll
        for (int r = 0; r < 4; ++r) se[r] += __expf(sacc[fn][r] - mx[r]);
#pragma unroll
    for (int m = 1; m <= 8; m <<= 1)
#pragma unroll
        for (int r = 0; r < 4; ++r) se[r] += __shfl_xor(se[r], m);
    float lg[4];
#pragma unroll
    for (int r = 0; r < 4; ++r) lg[r] = mx[r] + __logf(se[r]);
#pragma unroll
    for (int fn = 0; fn < 8; ++fn)
#pragma unroll
        for (int r = 0; r < 4; ++r)
            Ps[wave * 16 + lk * 4 + r][lrow + fn * 16] = f2bf(__expf(sacc[fn][r] - lg[r]));
    if (lrow == 0) {
#pragma unroll
        for (int r = 0; r < 4; ++r)
            logit_s[(size_t)h * NSEQ + c * 64 + wave * 16 + lk * 4 + r] = lg[r];
    }
    __syncthreads();
    f32x4 oacc[4];
#pragma unroll
    for (int fn = 0; fn < 4; ++fn) oacc[fn] = zero;
#pragma unroll
    for (int ks = 0; ks < 4; ++ks) {
        bf16x8 af = *(const bf16x8*)&Ps[wave * 16 + lrow][ks * 32 + lk * 8];
#pragma unroll
        for (int fn = 0; fn < 4; ++fn) {
            bf16x8 bv = *(const bf16x8*)&VT[fn * 16 + lrow][ks * 32 + lk * 8];
            oacc[fn] = __builtin_amdgcn_mfma_f32_16x16x32_bf16(af, bv, oacc[fn], 0, 0, 0);
        }
    }
#pragma unroll
    for (int fn = 0; fn < 4; ++fn)
#pragma unroll
        for (int r = 0; r < 4; ++r) {
            int qrow = c * 64 + wave * 16 + lk * 4 + r;
            out_s[((size_t)h * NSEQ + qrow) * DH + lrow + fn * 16] = f2bf(oacc[fn][r]);
        }
}

// ---------------- unsort + combine hash rounds (all 4 batches) ----------------
__global__ void combine_kernel(const unsigned short* __restrict__ outs_lo,
                               const unsigned short* __restrict__ outs_hi,
                               const float* __restrict__ logit_s,
                               const int* __restrict__ inv, unsigned short* __restrict__ attn_comb) {
    size_t gid = (size_t)blockIdx.x * 256 + threadIdx.x;  // 4*H*S*16 threads
    int d4 = gid & 15;
    size_t r = gid >> 4;
    int s = (int)(r & (SS - 1));
    int h = (int)((r >> 13) & 3);
    int bl = (int)(r >> 15);                              // 0..3
    size_t hb = (size_t)(bl * NHEADS + h) * NSEQ;         // global (b,h) base for inv/logit
    const unsigned short* ob = (bl < 2) ? (outs_lo + (size_t)bl * HNSD)
                                        : (outs_hi + (size_t)(bl - 2) * HNSD);
    int j0 = inv[hb + s];
    int j1 = inv[hb + SS + s];
    float l0 = logit_s[hb + j0];
    float l1 = logit_s[hb + j1];
    float mxv = fmaxf(l0, l1);
    float e0 = __expf(l0 - mxv), e1 = __expf(l1 - mxv);
    float is = 1.f / (e0 + e1);
    float w0 = e0 * is, w1 = e1 * is;
    ushort4 u0 = *(const ushort4*)(ob + ((size_t)h * NSEQ + j0) * DH + d4 * 4);
    ushort4 u1 = *(const ushort4*)(ob + ((size_t)h * NSEQ + j1) * DH + d4 * 4);
    ushort4 o;
    o.x = f2bf(w0 * bf2f(u0.x) + w1 * bf2f(u1.x));
    o.y = f2bf(w0 * bf2f(u0.y) + w1 * bf2f(u1.y));
    o.z = f2bf(w0 * bf2f(u0.z) + w1 * bf2f(u1.z));
    o.w = f2bf(w0 * bf2f(u0.w) + w1 * bf2f(u1.w));
    *(ushort4*)(attn_comb + ((size_t)bl * SS + s) * HID + h * DH + d4 * 4) = o;
}

// ---------------- launch ----------------
extern "C" void kernel_launch(void* const* d_in, const int* in_sizes, int n_in,
                              void* d_out, int out_size, void* d_ws, size_t ws_size,
                              hipStream_t stream) {
    const float* hs  = (const float*)d_in[0];
    const float* g1  = (const float*)d_in[1];
    const float* b1  = (const float*)d_in[2];
    const float* Wqk = (const float*)d_in[3];
    const float* Wv  = (const float*)d_in[4];
    const float* Wo  = (const float*)d_in[5];
    const float* rot = (const float*)d_in[6];
    const float* g2  = (const float*)d_in[7];
    const float* b2  = (const float*)d_in[8];
    const float* W1  = (const float*)d_in[9];
    const float* bf1 = (const float*)d_in[10];
    const float* W2  = (const float*)d_in[11];
    const float* bf2 = (const float*)d_in[12];
    const float* gf  = (const float*)d_in[13];
    const float* bff = (const float*)d_in[14];

    const size_t NE = (size_t)BB * SS * HID;    // 8,388,608
    const size_t MROWS = (size_t)BB * SS;       // 32768

    // ---- d_ws layout (~91.5 MB; <= 93.3 MB proven in R2) ----
    float* f = (float*)d_ws;
    float* attn_out = f;                               // NE f32
    float* hidden   = f + NE;                          // NE f32
    float* mu       = f + 2 * NE;                      // 32768
    float* rstd     = mu + MROWS;                      // 32768
    float* qscale   = rstd + MROWS;                    // B*S*H = 131072
    float* logit_all = qscale + MROWS * NHEADS;        // B*H*NSEQ = 262144
    int* sortx = (int*)(logit_all + (size_t)BB * NHEADS * NSEQ);
    int* invx  = sortx + (size_t)BB * NHEADS * NSEQ;
    int* buckx = invx + (size_t)BB * NHEADS * NSEQ;
    unsigned short* wbf = (unsigned short*)(buckx + (size_t)BB * NHEADS * NSEQ);  // 2*655360 ushort
    unsigned short* outs_hi = wbf + 2 * 655360;        // 2 batches x HNSD ushort = 16.8 MB

    // ---- d_out scratch (4 slots of 4,194,304 floats) ----
    float* o = (float*)d_out;
    unsigned short* abuf = (unsigned short*)o;              // slot0: xln_bf / attn_comb / h_ln
    unsigned short* outs_lo = (unsigned short*)(o + 4194304); // slot1: batches 0-1 sorted attn out
    unsigned short* k_bf = (unsigned short*)(o + 8388608);  // slot2
    unsigned short* v_bf = (unsigned short*)(o + 12582912); // slot3
    unsigned short* ffbuf = outs_lo;                        // phase D: slots 1-2

    // convert + transpose weights to bf16 once (layer-batched grids)
    wconv_kernel<<<dim3(HID / 32, HID / 32, NLAYERS), 256, 0, stream>>>(Wv, wbf, HID, HID, (size_t)HID * HID, 655360);
    wconv_kernel<<<dim3(HID / 32, HID / 32, NLAYERS), 256, 0, stream>>>(Wo, wbf + 65536, HID, HID, (size_t)HID * HID, 655360);
    wconv_kernel<<<dim3(HID / 32, FFD / 32, NLAYERS), 256, 0, stream>>>(W1, wbf + 131072, HID, FFD, (size_t)HID * FFD, 655360);
    wconv_kernel<<<dim3(FFD / 32, HID / 32, NLAYERS), 256, 0, stream>>>(W2, wbf + 393216, FFD, HID, (size_t)FFD * HID, 655360);

    for (int l = 0; l < NLAYERS; ++l) {
        const float* g1l = g1 + l * HID;
        const float* b1l = b1 + l * HID;
        const float* Wqkl = Wqk + (size_t)l * HID * HID;
        const float* rotl = rot + (size_t)l * NHEADS * DH * NHASH * NROT;
        const float* g2l = g2 + l * HID;
        const float* b2l = b2 + l * HID;
        const float* bf1l = bf1 + l * FFD;
        const float* bf2l = bf2 + l * HID;
        unsigned short* Wv_t = wbf + (size_t)l * 655360;
        unsigned short* Wo_t = Wv_t + 65536;
        unsigned short* W1_t = Wv_t + 131072;
        unsigned short* W2_t = Wv_t + 393216;
        const float* hid_in = (l == 0) ? hs : hidden;   // layer 0 reads inputs directly

        // ---- phase A (all-batch): LN(+stats) -> fused Wqk+hash -> Wv ----
        ln256_kernel<true><<<MROWS, 256, 0, stream>>>(hid_in, g1l, b1l, abuf, mu, rstd);
        qkhash_kernel<<<dim3(MROWS / 64, NHEADS), 256, 0, stream>>>(
            hid_in, mu, rstd, g1l, b1l, Wqkl, rotl, k_bf, qscale, buckx);
        mfma_gemm<4><<<dim3(MROWS / 128, HID / 128), 256, 0, stream>>>(abuf, Wv_t, nullptr, v_bf, MROWS, HID, HID, nullptr);

        // ---- phase B: sort all (b,h) ----
        sort_kernel<<<BB * NHEADS, 256, 0, stream>>>(buckx, sortx, invx);

        // ---- phase C: attention (all 4 batches in one launch) + combine + Wo ----
        attn_mfma<<<dim3(NCH, NHEADS, BB), 256, 0, stream>>>(
            k_bf, v_bf, qscale, sortx, outs_lo, outs_hi, logit_all);
        combine_kernel<<<(BB * NHEADS * SS * 16) / 256, 256, 0, stream>>>(
            outs_lo, outs_hi, logit_all, invx, abuf);
        if (l == 0)
            mfma_gemm<5><<<dim3(MROWS / 128, HID / 128), 256, 0, stream>>>(abuf, Wo_t, nullptr, attn_out, MROWS, HID, HID, hs);
        else
            mfma_gemm<2><<<dim3(MROWS / 128, HID / 128), 256, 0, stream>>>(abuf, Wo_t, nullptr, attn_out, MROWS, HID, HID, nullptr);

        // ---- phase D: FF (two M=16384 halves through slots 1-2) ----
        ln256_kernel<false><<<MROWS, 256, 0, stream>>>(attn_out, g2l, b2l, abuf, nullptr, nullptr);
        for (int half = 0; half < 2; ++half) {
            const unsigned short* hln_h = abuf + (size_t)half * 16384 * HID;
            float* hid_h = hidden + (size_t)half * 16384 * HID;
            mfma_gemm<1><<<dim3(16384 / 128, FFD / 128), 256, 0, stream>>>(hln_h, W1_t, bf1l, ffbuf, 16384, FFD, HID, nullptr);
            if (l == 0)
                mfma_gemm<6><<<dim3(16384 / 128, HID / 128), 256, 0, stream>>>(ffbuf, W2_t, bf2l, hid_h, 16384, HID, FFD, hs + (size_t)half * 16384 * HID);
            else
                mfma_gemm<3><<<dim3(16384 / 128, HID / 128), 256, 0, stream>>>(ffbuf, W2_t, bf2l, hid_h, 16384, HID, FFD, nullptr);
        }
    }
    ln512_kernel<<<MROWS, 256, 0, stream>>>(attn_out, hidden, gf, bff, (float*)d_out);
}

// Round 13
// 716.580 us; speedup vs baseline: 1.2538x; 1.0816x over previous
//
#include <hip/hip_runtime.h>
#include <math.h>

#define BB 4
#define SS 8192
#define HID 256
#define NHEADS 4
#define DH 64
#define FFD 1024
#define NLAYERS 2
#define NHASH 2
#define NBUCK 128
#define NROT 64          // NBUCK/2
#define NSEQ (NHASH*SS)  // 16384
#define NCH (NSEQ/64)    // 256 chunks of 64
#define MASKVAL -1e5f
#define PBE ((size_t)SS*HID)
#define HNSD ((size_t)NHEADS*NSEQ*DH)   // per-batch outs elems (ushort)
#define SPLITROW 24576                  // ffbuf part1 holds rows [0,24576), part2 the rest

typedef __bf16 bf16x8 __attribute__((ext_vector_type(8)));
typedef float f32x4 __attribute__((ext_vector_type(4)));

__device__ __forceinline__ unsigned short f2bf(float x) {
    unsigned u = __float_as_uint(x);
    unsigned r = (u >> 16) & 1;
    u += 0x7fffu + r;              // RNE
    return (unsigned short)(u >> 16);
}
__device__ __forceinline__ float bf2f(unsigned short h) {
    return __uint_as_float(((unsigned)h) << 16);
}
__device__ __forceinline__ unsigned scale2(unsigned u, float qs) {
    float lo = __uint_as_float(u << 16) * qs;
    float hi = __uint_as_float(u & 0xffff0000u) * qs;
    return (unsigned)f2bf(lo) | (((unsigned)f2bf(hi)) << 16);
}

// ---------------- block reduce (256 threads = 4 waves) ----------------
__device__ __forceinline__ float block_reduce_sum(float v, float* red) {
#pragma unroll
    for (int off = 32; off; off >>= 1) v += __shfl_down(v, off);
    int lane = threadIdx.x & 63, wid = threadIdx.x >> 6;
    __syncthreads();
    if (lane == 0) red[wid] = v;
    __syncthreads();
    return red[0] + red[1] + red[2] + red[3];
}

// ---------------- LayerNorm over 256 -> bf16 out, optional stats ----------------
template <bool STATS>
__global__ void ln256_kernel(const float* __restrict__ x, const float* __restrict__ g,
                             const float* __restrict__ b, unsigned short* __restrict__ ybf,
                             float* __restrict__ mu_out, float* __restrict__ rstd_out) {
    int row = blockIdx.x, tid = threadIdx.x;
    __shared__ float red[4];
    float v = x[(size_t)row * HID + tid];
    float mu = block_reduce_sum(v, red) * (1.f / 256.f);
    float d = v - mu;
    float var = block_reduce_sum(d * d, red) * (1.f / 256.f);
    float rstd = rsqrtf(var + 1e-12f);
    float out = d * rstd * g[tid] + b[tid];
    ybf[(size_t)row * HID + tid] = f2bf(out);
    if (STATS && tid == 0) { mu_out[row] = mu; rstd_out[row] = rstd; }
}

// ---------------- Final LayerNorm over concat(512) ----------------
__global__ void ln512_kernel(const float* __restrict__ a, const float* __restrict__ hd,
                             const float* __restrict__ g, const float* __restrict__ b,
                             float* __restrict__ out) {
    int row = blockIdx.x, tid = threadIdx.x;
    __shared__ float red[4];
    float x0 = a[(size_t)row * HID + tid];
    float x1 = hd[(size_t)row * HID + tid];
    float mu = block_reduce_sum(x0 + x1, red) * (1.f / 512.f);
    float d0 = x0 - mu, d1 = x1 - mu;
    float var = block_reduce_sum(d0 * d0 + d1 * d1, red) * (1.f / 512.f);
    float r = rsqrtf(var + 1e-12f);
    out[(size_t)row * 512 + tid]       = d0 * r * g[tid] + b[tid];
    out[(size_t)row * 512 + 256 + tid] = d1 * r * g[256 + tid] + b[256 + tid];
}

// ---------------- weight transpose + f32->bf16, layer batched: W[K,N] -> Wt[N,K] ----------------
__global__ void wconv_kernel(const float* __restrict__ W, unsigned short* __restrict__ Wt,
                             int K, int N, size_t wstride, size_t tstride) {
    __shared__ float t[32][33];
    int l = blockIdx.z;
    W += (size_t)l * wstride;
    Wt += (size_t)l * tstride;
    int k0 = blockIdx.x * 32, n0 = blockIdx.y * 32;
    int tx = threadIdx.x & 31, ty = threadIdx.x >> 5;  // 32 x 8
#pragma unroll
    for (int i = 0; i < 32; i += 8) t[ty + i][tx] = W[(size_t)(k0 + ty + i) * N + n0 + tx];
    __syncthreads();
#pragma unroll
    for (int i = 0; i < 32; i += 8) Wt[(size_t)(n0 + ty + i) * K + k0 + tx] = f2bf(t[tx][ty + i]);
}

// ---------------- fused fp32 Wqk GEMM + LN-on-the-fly + qk-norm + LSH hash ----------------
// R10 structure exactly (K-step 16, separate LDS arrays, 59.9 KB): measured 135 us. DO NOT TOUCH.
__global__ __launch_bounds__(256) void qkhash_kernel(
    const float* __restrict__ hid, const float* __restrict__ mu,
    const float* __restrict__ rstd, const float* __restrict__ gamma,
    const float* __restrict__ beta, const float* __restrict__ Wqk,
    const float* __restrict__ rot, unsigned short* __restrict__ kb,
    float* __restrict__ qscale, int* __restrict__ buckets) {
    __shared__ float As[16][68];
    __shared__ float Bs[16][68];
    __shared__ float QsT[64][68];     // [d][row]
    __shared__ float rotLDS[64][132]; // [d][col], both hash rounds
    int bm = blockIdx.x * 64;
    int h = blockIdx.y;
    int tid = threadIdx.x;
    int tx = tid & 15, ty = tid >> 4;
    float acc[4][4] = {};
    for (int k0 = 0; k0 < HID; k0 += 16) {
#pragma unroll
        for (int t = 0; t < 4; ++t) {
            int e = tid + t * 256;
            int m = e >> 4, kk = e & 15;
            int row = bm + m;
            float x = hid[(size_t)row * HID + k0 + kk];
            As[kk][m] = (x - mu[row]) * rstd[row] * gamma[k0 + kk] + beta[k0 + kk];
        }
#pragma unroll
        for (int t = 0; t < 4; ++t) {
            int e = tid + t * 256;
            int kk = e >> 6, n = e & 63;
            Bs[kk][n] = Wqk[(size_t)(k0 + kk) * HID + h * DH + n];
        }
        __syncthreads();
#pragma unroll
        for (int kk = 0; kk < 16; ++kk) {
            float4 a4 = *(float4*)&As[kk][ty * 4];
            float4 b4 = *(float4*)&Bs[kk][tx * 4];
            float a0[4] = {a4.x, a4.y, a4.z, a4.w};
            float b0[4] = {b4.x, b4.y, b4.z, b4.w};
#pragma unroll
            for (int i = 0; i < 4; ++i)
#pragma unroll
                for (int j = 0; j < 4; ++j) acc[i][j] += a0[i] * b0[j];
        }
        __syncthreads();
    }
    // per-row ||q||^2 over this head's 64 dims (reduce across tx group)
    float ssq_[4];
#pragma unroll
    for (int i = 0; i < 4; ++i) {
        float s = 0;
#pragma unroll
        for (int j = 0; j < 4; ++j) s += acc[i][j] * acc[i][j];
        ssq_[i] = s;
    }
#pragma unroll
    for (int mask = 1; mask <= 8; mask <<= 1)
#pragma unroll
        for (int i = 0; i < 4; ++i) ssq_[i] += __shfl_xor(ssq_[i], mask);
    // write k_bf + qscale
#pragma unroll
    for (int i = 0; i < 4; ++i) {
        int row = bm + ty * 4 + i;
        float nrm = fmaxf(sqrtf(ssq_[i]), 1e-12f);
        float sc = 0.125f / nrm;
        ushort4 kv;
        kv.x = f2bf(acc[i][0] * sc); kv.y = f2bf(acc[i][1] * sc);
        kv.z = f2bf(acc[i][2] * sc); kv.w = f2bf(acc[i][3] * sc);
        *(ushort4*)(kb + (size_t)row * HID + h * DH + tx * 4) = kv;
        if (tx == 0) qscale[(size_t)row * NHEADS + h] = 8.f * nrm;
    }
    // stage QsT via contiguous float4 in transposed layout
#pragma unroll
    for (int j = 0; j < 4; ++j) {
        float4 v = make_float4(acc[0][j], acc[1][j], acc[2][j], acc[3][j]);
        *(float4*)&QsT[tx * 4 + j][ty * 4] = v;
    }
    // load rot[h]: both rounds
    const float* rp = rot + (size_t)h * DH * NHASH * NROT;
#pragma unroll
    for (int t = 0; t < 8; ++t) {
        int e = tid + t * 256;
        int d = e >> 5, c4 = e & 31;
        *(float4*)&rotLDS[d][c4 * 4] = *(const float4*)(rp + d * 128 + c4 * 4);
    }
    __syncthreads();
    // hash: rotated = qk_tile @ rot, argmax over [rot, -rot]
    float acc2[4][8] = {};
#pragma unroll 2
    for (int d = 0; d < 64; ++d) {
        float4 a4 = *(float4*)&QsT[d][ty * 4];
        float a_[4] = {a4.x, a4.y, a4.z, a4.w};
        float4 b0 = *(float4*)&rotLDS[d][tx * 8];
        float4 b1v = *(float4*)&rotLDS[d][tx * 8 + 4];
#pragma unroll
        for (int i = 0; i < 4; ++i) {
            acc2[i][0] += a_[i] * b0.x;  acc2[i][1] += a_[i] * b0.y;
            acc2[i][2] += a_[i] * b0.z;  acc2[i][3] += a_[i] * b0.w;
            acc2[i][4] += a_[i] * b1v.x; acc2[i][5] += a_[i] * b1v.y;
            acc2[i][6] += a_[i] * b1v.z; acc2[i][7] += a_[i] * b1v.w;
        }
    }
    int n = tx >> 3;
#pragma unroll
    for (int i = 0; i < 4; ++i) {
        float bp = -3.4e38f, bn = -3.4e38f;
        int ipx = 0, inx = 0;
#pragma unroll
        for (int j = 0; j < 8; ++j) {
            float v = acc2[i][j];
            int r = ((tx & 7) * 8 + j);
            if (v > bp)  { bp = v;  ipx = r; }
            if (-v > bn) { bn = -v; inx = r; }
        }
#pragma unroll
        for (int mask = 1; mask <= 4; mask <<= 1) {
            float obp = __shfl_xor(bp, mask); int oip = __shfl_xor(ipx, mask);
            float obn = __shfl_xor(bn, mask); int oin = __shfl_xor(inx, mask);
            if (obp > bp || (obp == bp && oip < ipx)) { bp = obp; ipx = oip; }
            if (obn > bn || (obn == bn && oin < inx)) { bn = obn; inx = oin; }
        }
        if ((tx & 7) == 0) {
            int bucket = (bn > bp) ? (NROT + inx) : ipx;
            int row = bm + ty * 4 + i;
            int bb = row >> 13, sl = row & (SS - 1);
            buckets[(size_t)bb * NHEADS * NSEQ + h * NSEQ + n * SS + sl] = bucket + n * NBUCK;
        }
    }
}

// ---------------- bf16 MFMA GEMM with optional split-A / split-C at row SPLITROW ----------------
// EPI: 1 = bias+relu -> bf16, 2 = f32 C += acc, 3 = f32 C += acc + bias, 4 = store bf16,
//      5 = f32 C = Csrc + acc, 6 = f32 C = Csrc + acc + bias
template <int EPI>
__global__ __launch_bounds__(256) void mfma_gemm(
    const unsigned short* __restrict__ A, const unsigned short* __restrict__ A2,
    const unsigned short* __restrict__ Bt, const float* __restrict__ bias,
    void* __restrict__ Cv, void* __restrict__ Cv2,
    int M, int N, int K, const float* __restrict__ Csrc) {
    __shared__ unsigned short Asl[128 * 64];
    __shared__ unsigned short Bsl[128 * 64];
    int bm = blockIdx.x * 128, bn = blockIdx.y * 128;
    int tid = threadIdx.x;
    int wave = tid >> 6, lane = tid & 63;
    int wm = (wave >> 1) * 64, wn = (wave & 1) * 64;
    int lrow = lane & 15, lk = lane >> 4;
    // split-A base (tile-uniform: SPLITROW % 128 == 0)
    const unsigned short* Ab = A + (size_t)bm * K;
    if (A2 != nullptr && bm >= SPLITROW) Ab = A2 + (size_t)(bm - SPLITROW) * K;
    bool chi = (Cv2 != nullptr) && (bm >= SPLITROW);
    void* Cb = chi ? Cv2 : Cv;
    int crow0 = chi ? SPLITROW : 0;
    f32x4 zero = {0.f, 0.f, 0.f, 0.f};
    f32x4 acc[4][4];
#pragma unroll
    for (int i = 0; i < 4; ++i)
#pragma unroll
        for (int j = 0; j < 4; ++j) acc[i][j] = zero;

    for (int k0 = 0; k0 < K; k0 += 64) {
#pragma unroll
        for (int t = 0; t < 4; ++t) {
            int e = tid + t * 256;
            int r = e >> 3, kc = (e & 7) * 8;
            int4 v = *(const int4*)(Ab + (size_t)r * K + k0 + kc);
            *(int4*)((char*)Asl + r * 128 + ((kc * 2) ^ ((r & 7) << 4))) = v;
        }
#pragma unroll
        for (int t = 0; t < 4; ++t) {
            int e = tid + t * 256;
            int r = e >> 3, kc = (e & 7) * 8;
            int4 v = *(const int4*)(Bt + (size_t)(bn + r) * K + k0 + kc);
            *(int4*)((char*)Bsl + r * 128 + ((kc * 2) ^ ((r & 7) << 4))) = v;
        }
        __syncthreads();
#pragma unroll
        for (int kk = 0; kk < 2; ++kk) {
            int klocal = kk * 32 + lk * 8;
            bf16x8 af[4], bfv[4];
#pragma unroll
            for (int fm = 0; fm < 4; ++fm) {
                int r = wm + fm * 16 + lrow;
                af[fm] = *(const bf16x8*)((const char*)Asl + r * 128 + ((klocal * 2) ^ ((r & 7) << 4)));
            }
#pragma unroll
            for (int fn = 0; fn < 4; ++fn) {
                int r = wn + fn * 16 + lrow;
                bfv[fn] = *(const bf16x8*)((const char*)Bsl + r * 128 + ((klocal * 2) ^ ((r & 7) << 4)));
            }
#pragma unroll
            for (int fm = 0; fm < 4; ++fm)
#pragma unroll
                for (int fn = 0; fn < 4; ++fn)
                    acc[fm][fn] = __builtin_amdgcn_mfma_f32_16x16x32_bf16(af[fm], bfv[fn], acc[fm][fn], 0, 0, 0);
        }
        __syncthreads();
    }
#pragma unroll
    for (int fm = 0; fm < 4; ++fm)
#pragma unroll
        for (int fn = 0; fn < 4; ++fn) {
            int col = bn + wn + fn * 16 + lrow;
#pragma unroll
            for (int r = 0; r < 4; ++r) {
                int row = bm + wm + fm * 16 + lk * 4 + r;
                size_t crow = (size_t)(row - crow0);
                float v = acc[fm][fn][r];
                if (EPI == 1) {
                    v += bias[col]; v = fmaxf(v, 0.f);
                    ((unsigned short*)Cb)[crow * N + col] = f2bf(v);
                } else if (EPI == 2) {
                    ((float*)Cb)[crow * N + col] += v;
                } else if (EPI == 3) {
                    ((float*)Cb)[crow * N + col] += v + bias[col];
                } else if (EPI == 4) {
                    ((unsigned short*)Cb)[crow * N + col] = f2bf(v);
                } else if (EPI == 5) {
                    ((float*)Cb)[crow * N + col] = Csrc[(size_t)row * N + col] + v;
                } else {
                    ((float*)Cb)[crow * N + col] = Csrc[(size_t)row * N + col] + v + bias[col];
                }
            }
        }
}

// ---------------- parallel stable counting sort: 256 threads, one block per (b,h) ----------------
__global__ __launch_bounds__(256) void sort_kernel(const int* __restrict__ buckets,
                                                   int* __restrict__ sort_idx,
                                                   int* __restrict__ inv) {
    int bh = blockIdx.x;
    const int* bk = buckets + (size_t)bh * NSEQ;
    int* sj = sort_idx + (size_t)bh * NSEQ;
    int* ij = inv + (size_t)bh * NSEQ;
    __shared__ unsigned short cnt[256][258];  // [bin][thread-col], 132 KB
    __shared__ int colsum[256];
    int tid = threadIdx.x;
    unsigned* cz = (unsigned*)&cnt[0][0];
#pragma unroll
    for (int t = 0; t < 129; ++t) cz[tid * 129 + t] = 0;
    __syncthreads();
    int base = tid * 64;  // thread owns 64 contiguous items -> stability
    for (int j = 0; j < 64; j += 4) {
        int4 b4 = *(const int4*)(bk + base + j);
        cnt[b4.x][tid]++; cnt[b4.y][tid]++; cnt[b4.z][tid]++; cnt[b4.w][tid]++;
    }
    __syncthreads();
    {
        int run = 0;
        for (int c = 0; c < 256; ++c) { int v = cnt[tid][c]; cnt[tid][c] = (unsigned short)run; run += v; }
        colsum[tid] = run;
    }
    __syncthreads();
    if (tid == 0) {
        int run = 0;
        for (int j = 0; j < 256; ++j) { int c = colsum[j]; colsum[j] = run; run += c; }
    }
    __syncthreads();
    {
        int bs = colsum[tid];
        for (int c = 0; c < 256; ++c) cnt[tid][c] = (unsigned short)(cnt[tid][c] + bs);
    }
    __syncthreads();
    for (int j = 0; j < 64; j += 4) {
        int4 b4 = *(const int4*)(bk + base + j);
        int i0 = base + j;
        int r;
        r = cnt[b4.x][tid]++; sj[r] = i0;     ij[i0]     = r;
        r = cnt[b4.y][tid]++; sj[r] = i0 + 1; ij[i0 + 1] = r;
        r = cnt[b4.z][tid]++; sj[r] = i0 + 2; ij[i0 + 2] = r;
        r = cnt[b4.w][tid]++; sj[r] = i0 + 3; ij[i0 + 3] = r;
    }
}

// ---------------- MFMA chunked LSH attention (Ps overlays Ks; VT padded to 142) ----------------
// grid (NCH, NHEADS, 4) -- blockIdx.z = batch; outs split lo (batches 0-1) / hi (2-3)
__global__ __launch_bounds__(256) void attn_mfma(
    const unsigned short* __restrict__ kbf, const unsigned short* __restrict__ vbf,
    const float* __restrict__ qscale, const int* __restrict__ sort_idx,
    unsigned short* __restrict__ outs_lo, unsigned short* __restrict__ outs_hi,
    float* __restrict__ logit_s) {
    __shared__ unsigned short Qs[64][72];
    __shared__ unsigned short KsPs[128][72];     // Ks during QK^T; Ps [64][136] overlay after
    __shared__ unsigned short VT[64][142];       // stride 142: 8*71 % 32 = 24 -> 4 bank groups
    __shared__ int qid[64];
    __shared__ int kid[128];
    unsigned short (*Ks)[72] = KsPs;
    unsigned short (*Ps)[136] = (unsigned short(*)[136])&KsPs[0][0];
    int c = blockIdx.x, h = blockIdx.y, z = blockIdx.z;
    kbf += (size_t)z * PBE;
    vbf += (size_t)z * PBE;
    qscale += (size_t)z * SS * NHEADS;
    sort_idx += (size_t)z * NHEADS * NSEQ;
    unsigned short* out_s = (z < 2) ? (outs_lo + (size_t)z * HNSD) : (outs_hi + (size_t)(z - 2) * HNSD);
    logit_s += (size_t)z * NHEADS * NSEQ;
    int tid = threadIdx.x;
    const int* si = sort_idx + (size_t)h * NSEQ;
    int cprev = (c == 0) ? (NCH - 1) : (c - 1);
    if (tid < 64) qid[tid] = si[c * 64 + tid];
    else if (tid < 192) {
        int k = tid - 64;
        kid[k] = (k < 64) ? si[cprev * 64 + k] : si[c * 64 + (k - 64)];
    }
    __syncthreads();
    // Q = K * qscale (reconstruct unnormalized q)
#pragma unroll
    for (int t = 0; t < 2; ++t) {
        int e = tid + t * 256;
        int row = e >> 3, seg = e & 7;
        int s = qid[row] & (SS - 1);
        float qs = qscale[(size_t)s * NHEADS + h];
        int4 raw = *(const int4*)(kbf + ((size_t)s * HID + h * DH + seg * 8));
        int4 o;
        o.x = (int)scale2((unsigned)raw.x, qs);
        o.y = (int)scale2((unsigned)raw.y, qs);
        o.z = (int)scale2((unsigned)raw.z, qs);
        o.w = (int)scale2((unsigned)raw.w, qs);
        *(int4*)&Qs[row][seg * 8] = o;
    }
#pragma unroll
    for (int t = 0; t < 4; ++t) {
        int e = tid + t * 256;
        int row = e >> 3, seg = e & 7;
        int s = kid[row] & (SS - 1);
        *(int4*)&Ks[row][seg * 8] = *(const int4*)(kbf + ((size_t)s * HID + h * DH + seg * 8));
    }
#pragma unroll
    for (int t = 0; t < 4; ++t) {
        int e = tid + t * 256;
        int row = e >> 3, seg = e & 7;
        int s = kid[row] & (SS - 1);
        ushort4 a = *(const ushort4*)(vbf + ((size_t)s * HID + h * DH + seg * 8));
        ushort4 bq = *(const ushort4*)(vbf + ((size_t)s * HID + h * DH + seg * 8 + 4));
        int d0 = seg * 8;
        VT[d0 + 0][row] = a.x;  VT[d0 + 1][row] = a.y;  VT[d0 + 2][row] = a.z;  VT[d0 + 3][row] = a.w;
        VT[d0 + 4][row] = bq.x; VT[d0 + 5][row] = bq.y; VT[d0 + 6][row] = bq.z; VT[d0 + 7][row] = bq.w;
    }
    __syncthreads();
    int wave = tid >> 6, lane = tid & 63;
    int lrow = lane & 15, lk = lane >> 4;
    f32x4 zero = {0.f, 0.f, 0.f, 0.f};
    f32x4 sacc[8];
#pragma unroll
    for (int fn = 0; fn < 8; ++fn) sacc[fn] = zero;
#pragma unroll
    for (int kk = 0; kk < 2; ++kk) {
        bf16x8 af = *(const bf16x8*)&Qs[wave * 16 + lrow][kk * 32 + lk * 8];
#pragma unroll
        for (int fn = 0; fn < 8; ++fn) {
            bf16x8 bv = *(const bf16x8*)&Ks[fn * 16 + lrow][kk * 32 + lk * 8];
            sacc[fn] = __builtin_amdgcn_mfma_f32_16x16x32_bf16(af, bv, sacc[fn], 0, 0, 0);
        }
    }
    __syncthreads();   // all Qs/Ks reads complete before Ps overlays Ks
    int myq[4];
#pragma unroll
    for (int r = 0; r < 4; ++r) myq[r] = qid[wave * 16 + lk * 4 + r];
#pragma unroll
    for (int fn = 0; fn < 8; ++fn) {
        int kv = kid[lrow + fn * 16];
#pragma unroll
        for (int r = 0; r < 4; ++r)
            if (myq[r] == kv) sacc[fn][r] = MASKVAL;
    }
    float mx[4] = {-3.4e38f, -3.4e38f, -3.4e38f, -3.4e38f};
#pragma unroll
    for (int fn = 0; fn < 8; ++fn)
#pragma unroll
        for (int r = 0; r < 4; ++r) mx[r] = fmaxf(mx[r], sacc[fn][r]);
#pragma unroll
    for (int m = 1; m <= 8; m <<= 1)
#pragma unroll
        for (int r = 0; r < 4; ++r) mx[r] = fmaxf(mx[r], __shfl_xor(mx[r], m));
    float se[4] = {0.f, 0.f, 0.f, 0.f};
#pragma unroll
    for (int fn = 0; fn < 8; ++fn)
#pragma unroll
        for (int r = 0; r < 4; ++r) se[r] += __expf(sacc[fn][r] - mx[r]);
#pragma unroll
    for (int m = 1; m <= 8; m <<= 1)
#pragma unroll
        for (int r = 0; r < 4; ++r) se[r] += __shfl_xor(se[r], m);
    float lg[4];
#pragma unroll
    for (int r = 0; r < 4; ++r) lg[r] = mx[r] + __logf(se[r]);
#pragma unroll
    for (int fn = 0; fn < 8; ++fn)
#pragma unroll
        for (int r = 0; r < 4; ++r)
            Ps[wave * 16 + lk * 4 + r][lrow + fn * 16] = f2bf(__expf(sacc[fn][r] - lg[r]));
    if (lrow == 0) {
#pragma unroll
        for (int r = 0; r < 4; ++r)
            logit_s[(size_t)h * NSEQ + c * 64 + wave * 16 + lk * 4 + r] = lg[r];
    }
    __syncthreads();
    f32x4 oacc[4];
#pragma unroll
    for (int fn = 0; fn < 4; ++fn) oacc[fn] = zero;
#pragma unroll
    for (int ks = 0; ks < 4; ++ks) {
        bf16x8 af = *(const bf16x8*)&Ps[wave * 16 + lrow][ks * 32 + lk * 8];
#pragma unroll
        for (int fn = 0; fn < 4; ++fn) {
            bf16x8 bv = *(const bf16x8*)&VT[fn * 16 + lrow][ks * 32 + lk * 8];
            oacc[fn] = __builtin_amdgcn_mfma_f32_16x16x32_bf16(af, bv, oacc[fn], 0, 0, 0);
        }
    }
#pragma unroll
    for (int fn = 0; fn < 4; ++fn)
#pragma unroll
        for (int r = 0; r < 4; ++r) {
            int qrow = c * 64 + wave * 16 + lk * 4 + r;
            out_s[((size_t)h * NSEQ + qrow) * DH + lrow + fn * 16] = f2bf(oacc[fn][r]);
        }
}

// ---------------- unsort + combine hash rounds (all 4 batches) ----------------
__global__ void combine_kernel(const unsigned short* __restrict__ outs_lo,
                               const unsigned short* __restrict__ outs_hi,
                               const float* __restrict__ logit_s,
                               const int* __restrict__ inv, unsigned short* __restrict__ attn_comb) {
    size_t gid = (size_t)blockIdx.x * 256 + threadIdx.x;  // 4*H*S*16 threads
    int d4 = gid & 15;
    size_t r = gid >> 4;
    int s = (int)(r & (SS - 1));
    int h = (int)((r >> 13) & 3);
    int bl = (int)(r >> 15);                              // 0..3
    size_t hb = (size_t)(bl * NHEADS + h) * NSEQ;         // global (b,h) base for inv/logit
    const unsigned short* ob = (bl < 2) ? (outs_lo + (size_t)bl * HNSD)
                                        : (outs_hi + (size_t)(bl - 2) * HNSD);
    int j0 = inv[hb + s];
    int j1 = inv[hb + SS + s];
    float l0 = logit_s[hb + j0];
    float l1 = logit_s[hb + j1];
    float mxv = fmaxf(l0, l1);
    float e0 = __expf(l0 - mxv), e1 = __expf(l1 - mxv);
    float is = 1.f / (e0 + e1);
    float w0 = e0 * is, w1 = e1 * is;
    ushort4 u0 = *(const ushort4*)(ob + ((size_t)h * NSEQ + j0) * DH + d4 * 4);
    ushort4 u1 = *(const ushort4*)(ob + ((size_t)h * NSEQ + j1) * DH + d4 * 4);
    ushort4 o;
    o.x = f2bf(w0 * bf2f(u0.x) + w1 * bf2f(u1.x));
    o.y = f2bf(w0 * bf2f(u0.y) + w1 * bf2f(u1.y));
    o.z = f2bf(w0 * bf2f(u0.z) + w1 * bf2f(u1.z));
    o.w = f2bf(w0 * bf2f(u0.w) + w1 * bf2f(u1.w));
    *(ushort4*)(attn_comb + ((size_t)bl * SS + s) * HID + h * DH + d4 * 4) = o;
}

// ---------------- launch ----------------
extern "C" void kernel_launch(void* const* d_in, const int* in_sizes, int n_in,
                              void* d_out, int out_size, void* d_ws, size_t ws_size,
                              hipStream_t stream) {
    const float* hs  = (const float*)d_in[0];
    const float* g1  = (const float*)d_in[1];
    const float* b1  = (const float*)d_in[2];
    const float* Wqk = (const float*)d_in[3];
    const float* Wv  = (const float*)d_in[4];
    const float* Wo  = (const float*)d_in[5];
    const float* rot = (const float*)d_in[6];
    const float* g2  = (const float*)d_in[7];
    const float* b2  = (const float*)d_in[8];
    const float* W1  = (const float*)d_in[9];
    const float* bf1 = (const float*)d_in[10];
    const float* W2  = (const float*)d_in[11];
    const float* bf2 = (const float*)d_in[12];
    const float* gf  = (const float*)d_in[13];
    const float* bff = (const float*)d_in[14];

    const size_t NE = (size_t)BB * SS * HID;    // 8,388,608
    const size_t MROWS = (size_t)BB * SS;       // 32768

    // ---- d_ws layout (~91.5 MB; <= 93.3 MB proven in R2) ----
    float* f = (float*)d_ws;
    float* attn_out = f;                               // NE f32
    float* hidden   = f + NE;                          // NE f32
    float* mu       = f + 2 * NE;                      // 32768
    float* rstd     = mu + MROWS;                      // 32768
    float* qscale   = rstd + MROWS;                    // B*S*H = 131072
    float* logit_all = qscale + MROWS * NHEADS;        // B*H*NSEQ = 262144
    int* sortx = (int*)(logit_all + (size_t)BB * NHEADS * NSEQ);
    int* invx  = sortx + (size_t)BB * NHEADS * NSEQ;
    int* buckx = invx + (size_t)BB * NHEADS * NSEQ;
    unsigned short* wbf = (unsigned short*)(buckx + (size_t)BB * NHEADS * NSEQ);  // 2*655360 ushort
    unsigned short* outs_hi = wbf + 2 * 655360;        // 16.78 MB: attn outs (b2-3) / ffbuf part2

    // ---- d_out scratch (4 slots of 4,194,304 floats) ----
    float* o = (float*)d_out;
    unsigned short* abuf = (unsigned short*)o;              // slot0: xln_bf / attn_comb / h_ln
    unsigned short* outs_lo = (unsigned short*)(o + 4194304); // slot1: batches 0-1 sorted attn out
    unsigned short* k_bf = (unsigned short*)(o + 8388608);  // slot2
    unsigned short* v_bf = (unsigned short*)(o + 12582912); // slot3
    unsigned short* ffbuf1 = outs_lo;                       // phase D: slots 1-3 = rows [0,24576)
    unsigned short* ffbuf2 = outs_hi;                       // phase D: rows [24576,32768)

    // convert + transpose weights to bf16 once (layer-batched grids)
    wconv_kernel<<<dim3(HID / 32, HID / 32, NLAYERS), 256, 0, stream>>>(Wv, wbf, HID, HID, (size_t)HID * HID, 655360);
    wconv_kernel<<<dim3(HID / 32, HID / 32, NLAYERS), 256, 0, stream>>>(Wo, wbf + 65536, HID, HID, (size_t)HID * HID, 655360);
    wconv_kernel<<<dim3(HID / 32, FFD / 32, NLAYERS), 256, 0, stream>>>(W1, wbf + 131072, HID, FFD, (size_t)HID * FFD, 655360);
    wconv_kernel<<<dim3(FFD / 32, HID / 32, NLAYERS), 256, 0, stream>>>(W2, wbf + 393216, FFD, HID, (size_t)FFD * HID, 655360);

    for (int l = 0; l < NLAYERS; ++l) {
        const float* g1l = g1 + l * HID;
        const float* b1l = b1 + l * HID;
        const float* Wqkl = Wqk + (size_t)l * HID * HID;
        const float* rotl = rot + (size_t)l * NHEADS * DH * NHASH * NROT;
        const float* g2l = g2 + l * HID;
        const float* b2l = b2 + l * HID;
        const float* bf1l = bf1 + l * FFD;
        const float* bf2l = bf2 + l * HID;
        unsigned short* Wv_t = wbf + (size_t)l * 655360;
        unsigned short* Wo_t = Wv_t + 65536;
        unsigned short* W1_t = Wv_t + 131072;
        unsigned short* W2_t = Wv_t + 393216;
        const float* hid_in = (l == 0) ? hs : hidden;   // layer 0 reads inputs directly

        // ---- phase A (all-batch): LN(+stats) -> fused Wqk+hash -> Wv ----
        ln256_kernel<true><<<MROWS, 256, 0, stream>>>(hid_in, g1l, b1l, abuf, mu, rstd);
        qkhash_kernel<<<dim3(MROWS / 64, NHEADS), 256, 0, stream>>>(
            hid_in, mu, rstd, g1l, b1l, Wqkl, rotl, k_bf, qscale, buckx);
        mfma_gemm<4><<<dim3(MROWS / 128, HID / 128), 256, 0, stream>>>(
            abuf, nullptr, Wv_t, nullptr, v_bf, nullptr, MROWS, HID, HID, nullptr);

        // ---- phase B: sort all (b,h) ----
        sort_kernel<<<BB * NHEADS, 256, 0, stream>>>(buckx, sortx, invx);

        // ---- phase C: attention (all 4 batches in one launch) + combine + Wo ----
        attn_mfma<<<dim3(NCH, NHEADS, BB), 256, 0, stream>>>(
            k_bf, v_bf, qscale, sortx, outs_lo, outs_hi, logit_all);
        combine_kernel<<<(BB * NHEADS * SS * 16) / 256, 256, 0, stream>>>(
            outs_lo, outs_hi, logit_all, invx, abuf);
        if (l == 0)
            mfma_gemm<5><<<dim3(MROWS / 128, HID / 128), 256, 0, stream>>>(
                abuf, nullptr, Wo_t, nullptr, attn_out, nullptr, MROWS, HID, HID, hs);
        else
            mfma_gemm<2><<<dim3(MROWS / 128, HID / 128), 256, 0, stream>>>(
                abuf, nullptr, Wo_t, nullptr, attn_out, nullptr, MROWS, HID, HID, nullptr);

        // ---- phase D: FF single-launch over M=32768 with split ffbuf ----
        ln256_kernel<false><<<MROWS, 256, 0, stream>>>(attn_out, g2l, b2l, abuf, nullptr, nullptr);
        mfma_gemm<1><<<dim3(MROWS / 128, FFD / 128), 256, 0, stream>>>(
            abuf, nullptr, W1_t, bf1l, ffbuf1, ffbuf2, MROWS, FFD, HID, nullptr);
        if (l == 0)
            mfma_gemm<6><<<dim3(MROWS / 128, HID / 128), 256, 0, stream>>>(
                ffbuf1, ffbuf2, W2_t, bf2l, hidden, nullptr, MROWS, HID, FFD, hs);
        else
            mfma_gemm<3><<<dim3(MROWS / 128, HID / 128), 256, 0, stream>>>(
                ffbuf1, ffbuf2, W2_t, bf2l, hidden, nullptr, MROWS, HID, FFD, nullptr);
    }
    ln512_kernel<<<MROWS, 256, 0, stream>>>(attn_out, hidden, gf, bff, (float*)d_out);
}

// Round 14
// 711.100 us; speedup vs baseline: 1.2635x; 1.0077x over previous
//
#include <hip/hip_runtime.h>
#include <math.h>

#define BB 4
#define SS 8192
#define HID 256
#define NHEADS 4
#define DH 64
#define FFD 1024
#define NLAYERS 2
#define NHASH 2
#define NBUCK 128
#define NROT 64          // NBUCK/2
#define NSEQ (NHASH*SS)  // 16384
#define NCH (NSEQ/64)    // 256 chunks of 64
#define MASKVAL -1e5f
#define PBE ((size_t)SS*HID)
#define HNSD ((size_t)NHEADS*NSEQ*DH)   // per-batch outs elems (ushort)
#define SPLITROW 24576                  // ffbuf part1 holds rows [0,24576), part2 the rest

typedef __bf16 bf16x8 __attribute__((ext_vector_type(8)));
typedef float f32x4 __attribute__((ext_vector_type(4)));

__device__ __forceinline__ unsigned short f2bf(float x) {
    unsigned u = __float_as_uint(x);
    unsigned r = (u >> 16) & 1;
    u += 0x7fffu + r;              // RNE
    return (unsigned short)(u >> 16);
}
__device__ __forceinline__ float bf2f(unsigned short h) {
    return __uint_as_float(((unsigned)h) << 16);
}
__device__ __forceinline__ unsigned scale2(unsigned u, float qs) {
    float lo = __uint_as_float(u << 16) * qs;
    float hi = __uint_as_float(u & 0xffff0000u) * qs;
    return (unsigned)f2bf(lo) | (((unsigned)f2bf(hi)) << 16);
}

// ---------------- block reduce (256 threads = 4 waves) ----------------
__device__ __forceinline__ float block_reduce_sum(float v, float* red) {
#pragma unroll
    for (int off = 32; off; off >>= 1) v += __shfl_down(v, off);
    int lane = threadIdx.x & 63, wid = threadIdx.x >> 6;
    __syncthreads();
    if (lane == 0) red[wid] = v;
    __syncthreads();
    return red[0] + red[1] + red[2] + red[3];
}

// ---------------- LayerNorm over 256 -> bf16 out, optional stats ----------------
template <bool STATS>
__global__ void ln256_kernel(const float* __restrict__ x, const float* __restrict__ g,
                             const float* __restrict__ b, unsigned short* __restrict__ ybf,
                             float* __restrict__ mu_out, float* __restrict__ rstd_out) {
    int row = blockIdx.x, tid = threadIdx.x;
    __shared__ float red[4];
    float v = x[(size_t)row * HID + tid];
    float mu = block_reduce_sum(v, red) * (1.f / 256.f);
    float d = v - mu;
    float var = block_reduce_sum(d * d, red) * (1.f / 256.f);
    float rstd = rsqrtf(var + 1e-12f);
    float out = d * rstd * g[tid] + b[tid];
    ybf[(size_t)row * HID + tid] = f2bf(out);
    if (STATS && tid == 0) { mu_out[row] = mu; rstd_out[row] = rstd; }
}

// ---------------- Final LayerNorm over concat(512) ----------------
__global__ void ln512_kernel(const float* __restrict__ a, const float* __restrict__ hd,
                             const float* __restrict__ g, const float* __restrict__ b,
                             float* __restrict__ out) {
    int row = blockIdx.x, tid = threadIdx.x;
    __shared__ float red[4];
    float x0 = a[(size_t)row * HID + tid];
    float x1 = hd[(size_t)row * HID + tid];
    float mu = block_reduce_sum(x0 + x1, red) * (1.f / 512.f);
    float d0 = x0 - mu, d1 = x1 - mu;
    float var = block_reduce_sum(d0 * d0 + d1 * d1, red) * (1.f / 512.f);
    float r = rsqrtf(var + 1e-12f);
    out[(size_t)row * 512 + tid]       = d0 * r * g[tid] + b[tid];
    out[(size_t)row * 512 + 256 + tid] = d1 * r * g[256 + tid] + b[256 + tid];
}

// ---------------- weight transpose + f32->bf16, layer batched: W[K,N] -> Wt[N,K] ----------------
__global__ void wconv_kernel(const float* __restrict__ W, unsigned short* __restrict__ Wt,
                             int K, int N, size_t wstride, size_t tstride) {
    __shared__ float t[32][33];
    int l = blockIdx.z;
    W += (size_t)l * wstride;
    Wt += (size_t)l * tstride;
    int k0 = blockIdx.x * 32, n0 = blockIdx.y * 32;
    int tx = threadIdx.x & 31, ty = threadIdx.x >> 5;  // 32 x 8
#pragma unroll
    for (int i = 0; i < 32; i += 8) t[ty + i][tx] = W[(size_t)(k0 + ty + i) * N + n0 + tx];
    __syncthreads();
#pragma unroll
    for (int i = 0; i < 32; i += 8) Wt[(size_t)(n0 + ty + i) * K + k0 + tx] = f2bf(t[tx][ty + i]);
}

// ---------------- fused fp32 Wqk GEMM + LN-on-the-fly + qk-norm + LSH hash ----------------
// R10 structure; ONLY change: hash-loop rot column mapping -> 2-way (free) LDS reads.
// Per-column dot products bit-identical; argmax scan order still index-ascending.
__global__ __launch_bounds__(256) void qkhash_kernel(
    const float* __restrict__ hid, const float* __restrict__ mu,
    const float* __restrict__ rstd, const float* __restrict__ gamma,
    const float* __restrict__ beta, const float* __restrict__ Wqk,
    const float* __restrict__ rot, unsigned short* __restrict__ kb,
    float* __restrict__ qscale, int* __restrict__ buckets) {
    __shared__ float As[16][68];
    __shared__ float Bs[16][68];
    __shared__ float QsT[64][68];     // [d][row]
    __shared__ float rotLDS[64][132]; // [d][col], both hash rounds
    int bm = blockIdx.x * 64;
    int h = blockIdx.y;
    int tid = threadIdx.x;
    int tx = tid & 15, ty = tid >> 4;
    float acc[4][4] = {};
    for (int k0 = 0; k0 < HID; k0 += 16) {
#pragma unroll
        for (int t = 0; t < 4; ++t) {
            int e = tid + t * 256;
            int m = e >> 4, kk = e & 15;
            int row = bm + m;
            float x = hid[(size_t)row * HID + k0 + kk];
            As[kk][m] = (x - mu[row]) * rstd[row] * gamma[k0 + kk] + beta[k0 + kk];
        }
#pragma unroll
        for (int t = 0; t < 4; ++t) {
            int e = tid + t * 256;
            int kk = e >> 6, n = e & 63;
            Bs[kk][n] = Wqk[(size_t)(k0 + kk) * HID + h * DH + n];
        }
        __syncthreads();
#pragma unroll
        for (int kk = 0; kk < 16; ++kk) {
            float4 a4 = *(float4*)&As[kk][ty * 4];
            float4 b4 = *(float4*)&Bs[kk][tx * 4];
            float a0[4] = {a4.x, a4.y, a4.z, a4.w};
            float b0[4] = {b4.x, b4.y, b4.z, b4.w};
#pragma unroll
            for (int i = 0; i < 4; ++i)
#pragma unroll
                for (int j = 0; j < 4; ++j) acc[i][j] += a0[i] * b0[j];
        }
        __syncthreads();
    }
    // per-row ||q||^2 over this head's 64 dims (reduce across tx group)
    float ssq_[4];
#pragma unroll
    for (int i = 0; i < 4; ++i) {
        float s = 0;
#pragma unroll
        for (int j = 0; j < 4; ++j) s += acc[i][j] * acc[i][j];
        ssq_[i] = s;
    }
#pragma unroll
    for (int mask = 1; mask <= 8; mask <<= 1)
#pragma unroll
        for (int i = 0; i < 4; ++i) ssq_[i] += __shfl_xor(ssq_[i], mask);
    // write k_bf + qscale
#pragma unroll
    for (int i = 0; i < 4; ++i) {
        int row = bm + ty * 4 + i;
        float nrm = fmaxf(sqrtf(ssq_[i]), 1e-12f);
        float sc = 0.125f / nrm;
        ushort4 kv;
        kv.x = f2bf(acc[i][0] * sc); kv.y = f2bf(acc[i][1] * sc);
        kv.z = f2bf(acc[i][2] * sc); kv.w = f2bf(acc[i][3] * sc);
        *(ushort4*)(kb + (size_t)row * HID + h * DH + tx * 4) = kv;
        if (tx == 0) qscale[(size_t)row * NHEADS + h] = 8.f * nrm;
    }
    // stage QsT via contiguous float4 in transposed layout
#pragma unroll
    for (int j = 0; j < 4; ++j) {
        float4 v = make_float4(acc[0][j], acc[1][j], acc[2][j], acc[3][j]);
        *(float4*)&QsT[tx * 4 + j][ty * 4] = v;
    }
    // load rot[h]: both rounds
    const float* rp = rot + (size_t)h * DH * NHASH * NROT;
#pragma unroll
    for (int t = 0; t < 8; ++t) {
        int e = tid + t * 256;
        int d = e >> 5, c4 = e & 31;
        *(float4*)&rotLDS[d][c4 * 4] = *(const float4*)(rp + d * 128 + c4 * 4);
    }
    __syncthreads();
    // hash: thread tx owns round n=(tx&1), cols {base..base+3, base+32..base+35}, base=(tx>>1)*4
    int cb = (tx & 1) * 64 + (tx >> 1) * 4;   // rotLDS col base: banks 2-way (free)
    float acc2[4][8] = {};
#pragma unroll 2
    for (int d = 0; d < 64; ++d) {
        float4 a4 = *(float4*)&QsT[d][ty * 4];
        float a_[4] = {a4.x, a4.y, a4.z, a4.w};
        float4 b0 = *(float4*)&rotLDS[d][cb];
        float4 b1v = *(float4*)&rotLDS[d][cb + 32];
#pragma unroll
        for (int i = 0; i < 4; ++i) {
            acc2[i][0] += a_[i] * b0.x;  acc2[i][1] += a_[i] * b0.y;
            acc2[i][2] += a_[i] * b0.z;  acc2[i][3] += a_[i] * b0.w;
            acc2[i][4] += a_[i] * b1v.x; acc2[i][5] += a_[i] * b1v.y;
            acc2[i][6] += a_[i] * b1v.z; acc2[i][7] += a_[i] * b1v.w;
        }
    }
    int n = tx & 1;
    int rbase = (tx >> 1) * 4;
#pragma unroll
    for (int i = 0; i < 4; ++i) {
        float bp = -3.4e38f, bn = -3.4e38f;
        int ipx = 0, inx = 0;
#pragma unroll
        for (int j = 0; j < 8; ++j) {
            float v = acc2[i][j];
            int r = rbase + (j < 4 ? j : 28 + j);   // j 0..3 -> rbase+j ; j 4..7 -> rbase+32+(j-4)
            if (v > bp)  { bp = v;  ipx = r; }
            if (-v > bn) { bn = -v; inx = r; }
        }
#pragma unroll
        for (int mask = 2; mask <= 8; mask <<= 1) {
            float obp = __shfl_xor(bp, mask); int oip = __shfl_xor(ipx, mask);
            float obn = __shfl_xor(bn, mask); int oin = __shfl_xor(inx, mask);
            if (obp > bp || (obp == bp && oip < ipx)) { bp = obp; ipx = oip; }
            if (obn > bn || (obn == bn && oin < inx)) { bn = obn; inx = oin; }
        }
        if ((tx >> 1) == 0) {
            int bucket = (bn > bp) ? (NROT + inx) : ipx;
            int row = bm + ty * 4 + i;
            int bb = row >> 13, sl = row & (SS - 1);
            buckets[(size_t)bb * NHEADS * NSEQ + h * NSEQ + n * SS + sl] = bucket + n * NBUCK;
        }
    }
}

// ---------------- bf16 MFMA GEMM with optional split-A / split-C at row SPLITROW ----------------
// EPI: 1 = bias+relu -> bf16, 2 = f32 C += acc, 3 = f32 C += acc + bias, 4 = store bf16,
//      5 = f32 C = Csrc + acc, 6 = f32 C = Csrc + acc + bias
template <int EPI>
__global__ __launch_bounds__(256) void mfma_gemm(
    const unsigned short* __restrict__ A, const unsigned short* __restrict__ A2,
    const unsigned short* __restrict__ Bt, const float* __restrict__ bias,
    void* __restrict__ Cv, void* __restrict__ Cv2,
    int M, int N, int K, const float* __restrict__ Csrc) {
    __shared__ unsigned short Asl[128 * 64];
    __shared__ unsigned short Bsl[128 * 64];
    int bm = blockIdx.x * 128, bn = blockIdx.y * 128;
    int tid = threadIdx.x;
    int wave = tid >> 6, lane = tid & 63;
    int wm = (wave >> 1) * 64, wn = (wave & 1) * 64;
    int lrow = lane & 15, lk = lane >> 4;
    const unsigned short* Ab = A + (size_t)bm * K;
    if (A2 != nullptr && bm >= SPLITROW) Ab = A2 + (size_t)(bm - SPLITROW) * K;
    bool chi = (Cv2 != nullptr) && (bm >= SPLITROW);
    void* Cb = chi ? Cv2 : Cv;
    int crow0 = chi ? SPLITROW : 0;
    f32x4 zero = {0.f, 0.f, 0.f, 0.f};
    f32x4 acc[4][4];
#pragma unroll
    for (int i = 0; i < 4; ++i)
#pragma unroll
        for (int j = 0; j < 4; ++j) acc[i][j] = zero;

    for (int k0 = 0; k0 < K; k0 += 64) {
#pragma unroll
        for (int t = 0; t < 4; ++t) {
            int e = tid + t * 256;
            int r = e >> 3, kc = (e & 7) * 8;
            int4 v = *(const int4*)(Ab + (size_t)r * K + k0 + kc);
            *(int4*)((char*)Asl + r * 128 + ((kc * 2) ^ ((r & 7) << 4))) = v;
        }
#pragma unroll
        for (int t = 0; t < 4; ++t) {
            int e = tid + t * 256;
            int r = e >> 3, kc = (e & 7) * 8;
            int4 v = *(const int4*)(Bt + (size_t)(bn + r) * K + k0 + kc);
            *(int4*)((char*)Bsl + r * 128 + ((kc * 2) ^ ((r & 7) << 4))) = v;
        }
        __syncthreads();
#pragma unroll
        for (int kk = 0; kk < 2; ++kk) {
            int klocal = kk * 32 + lk * 8;
            bf16x8 af[4], bfv[4];
#pragma unroll
            for (int fm = 0; fm < 4; ++fm) {
                int r = wm + fm * 16 + lrow;
                af[fm] = *(const bf16x8*)((const char*)Asl + r * 128 + ((klocal * 2) ^ ((r & 7) << 4)));
            }
#pragma unroll
            for (int fn = 0; fn < 4; ++fn) {
                int r = wn + fn * 16 + lrow;
                bfv[fn] = *(const bf16x8*)((const char*)Bsl + r * 128 + ((klocal * 2) ^ ((r & 7) << 4)));
            }
#pragma unroll
            for (int fm = 0; fm < 4; ++fm)
#pragma unroll
                for (int fn = 0; fn < 4; ++fn)
                    acc[fm][fn] = __builtin_amdgcn_mfma_f32_16x16x32_bf16(af[fm], bfv[fn], acc[fm][fn], 0, 0, 0);
        }
        __syncthreads();
    }
#pragma unroll
    for (int fm = 0; fm < 4; ++fm)
#pragma unroll
        for (int fn = 0; fn < 4; ++fn) {
            int col = bn + wn + fn * 16 + lrow;
#pragma unroll
            for (int r = 0; r < 4; ++r) {
                int row = bm + wm + fm * 16 + lk * 4 + r;
                size_t crow = (size_t)(row - crow0);
                float v = acc[fm][fn][r];
                if (EPI == 1) {
                    v += bias[col]; v = fmaxf(v, 0.f);
                    ((unsigned short*)Cb)[crow * N + col] = f2bf(v);
                } else if (EPI == 2) {
                    ((float*)Cb)[crow * N + col] += v;
                } else if (EPI == 3) {
                    ((float*)Cb)[crow * N + col] += v + bias[col];
                } else if (EPI == 4) {
                    ((unsigned short*)Cb)[crow * N + col] = f2bf(v);
                } else if (EPI == 5) {
                    ((float*)Cb)[crow * N + col] = Csrc[(size_t)row * N + col] + v;
                } else {
                    ((float*)Cb)[crow * N + col] = Csrc[(size_t)row * N + col] + v + bias[col];
                }
            }
        }
}

// ---------------- parallel stable counting sort: 256 threads, one block per (b,h) ----------------
__global__ __launch_bounds__(256) void sort_kernel(const int* __restrict__ buckets,
                                                   int* __restrict__ sort_idx,
                                                   int* __restrict__ inv) {
    int bh = blockIdx.x;
    const int* bk = buckets + (size_t)bh * NSEQ;
    int* sj = sort_idx + (size_t)bh * NSEQ;
    int* ij = inv + (size_t)bh * NSEQ;
    __shared__ unsigned short cnt[256][258];  // [bin][thread-col], 132 KB
    __shared__ int colsum[256];
    int tid = threadIdx.x;
    unsigned* cz = (unsigned*)&cnt[0][0];
#pragma unroll
    for (int t = 0; t < 129; ++t) cz[tid * 129 + t] = 0;
    __syncthreads();
    int base = tid * 64;  // thread owns 64 contiguous items -> stability
    for (int j = 0; j < 64; j += 4) {
        int4 b4 = *(const int4*)(bk + base + j);
        cnt[b4.x][tid]++; cnt[b4.y][tid]++; cnt[b4.z][tid]++; cnt[b4.w][tid]++;
    }
    __syncthreads();
    {
        int run = 0;
        for (int c = 0; c < 256; ++c) { int v = cnt[tid][c]; cnt[tid][c] = (unsigned short)run; run += v; }
        colsum[tid] = run;
    }
    __syncthreads();
    if (tid == 0) {
        int run = 0;
        for (int j = 0; j < 256; ++j) { int c = colsum[j]; colsum[j] = run; run += c; }
    }
    __syncthreads();
    {
        int bs = colsum[tid];
        for (int c = 0; c < 256; ++c) cnt[tid][c] = (unsigned short)(cnt[tid][c] + bs);
    }
    __syncthreads();
    for (int j = 0; j < 64; j += 4) {
        int4 b4 = *(const int4*)(bk + base + j);
        int i0 = base + j;
        int r;
        r = cnt[b4.x][tid]++; sj[r] = i0;     ij[i0]     = r;
        r = cnt[b4.y][tid]++; sj[r] = i0 + 1; ij[i0 + 1] = r;
        r = cnt[b4.z][tid]++; sj[r] = i0 + 2; ij[i0 + 2] = r;
        r = cnt[b4.w][tid]++; sj[r] = i0 + 3; ij[i0 + 3] = r;
    }
}

// ---------------- MFMA chunked LSH attention (Q in registers; 37.4 KB LDS -> 4 blocks/CU) ----------------
// grid (NCH, NHEADS, 4) -- blockIdx.z = batch; outs split lo (batches 0-1) / hi (2-3)
__global__ __launch_bounds__(256) void attn_mfma(
    const unsigned short* __restrict__ kbf, const unsigned short* __restrict__ vbf,
    const float* __restrict__ qscale, const int* __restrict__ sort_idx,
    unsigned short* __restrict__ outs_lo, unsigned short* __restrict__ outs_hi,
    float* __restrict__ logit_s) {
    __shared__ unsigned short KsPs[128][72];     // Ks during QK^T; Ps [64][136] overlay after
    __shared__ unsigned short VT[64][142];       // stride 142: 8*71 % 32 = 24 -> 4 bank groups
    __shared__ int qid[64];
    __shared__ int kid[128];
    unsigned short (*Ks)[72] = KsPs;
    unsigned short (*Ps)[136] = (unsigned short(*)[136])&KsPs[0][0];
    int c = blockIdx.x, h = blockIdx.y, z = blockIdx.z;
    kbf += (size_t)z * PBE;
    vbf += (size_t)z * PBE;
    qscale += (size_t)z * SS * NHEADS;
    sort_idx += (size_t)z * NHEADS * NSEQ;
    unsigned short* out_s = (z < 2) ? (outs_lo + (size_t)z * HNSD) : (outs_hi + (size_t)(z - 2) * HNSD);
    logit_s += (size_t)z * NHEADS * NSEQ;
    int tid = threadIdx.x;
    const int* si = sort_idx + (size_t)h * NSEQ;
    int cprev = (c == 0) ? (NCH - 1) : (c - 1);
    if (tid < 64) qid[tid] = si[c * 64 + tid];
    else if (tid < 192) {
        int k = tid - 64;
        kid[k] = (k < 64) ? si[cprev * 64 + k] : si[c * 64 + (k - 64)];
    }
    __syncthreads();
    int wave = tid >> 6, lane = tid & 63;
    int lrow = lane & 15, lk = lane >> 4;
    // Q fragments straight to registers: lane covers q-row wave*16+lrow, cols kk*32 + lk*8
    int qsrow = qid[wave * 16 + lrow] & (SS - 1);
    float qsc = qscale[(size_t)qsrow * NHEADS + h];
    int4 qraw[2];
#pragma unroll
    for (int kk = 0; kk < 2; ++kk) {
        int4 raw = *(const int4*)(kbf + ((size_t)qsrow * HID + h * DH + kk * 32 + lk * 8));
        raw.x = (int)scale2((unsigned)raw.x, qsc);
        raw.y = (int)scale2((unsigned)raw.y, qsc);
        raw.z = (int)scale2((unsigned)raw.z, qsc);
        raw.w = (int)scale2((unsigned)raw.w, qsc);
        qraw[kk] = raw;
    }
    // K staging (128 x 64 bf16)
#pragma unroll
    for (int t = 0; t < 4; ++t) {
        int e = tid + t * 256;
        int row = e >> 3, seg = e & 7;
        int s = kid[row] & (SS - 1);
        *(int4*)&Ks[row][seg * 8] = *(const int4*)(kbf + ((size_t)s * HID + h * DH + seg * 8));
    }
    // V staging transposed
#pragma unroll
    for (int t = 0; t < 4; ++t) {
        int e = tid + t * 256;
        int row = e >> 3, seg = e & 7;
        int s = kid[row] & (SS - 1);
        ushort4 a = *(const ushort4*)(vbf + ((size_t)s * HID + h * DH + seg * 8));
        ushort4 bq = *(const ushort4*)(vbf + ((size_t)s * HID + h * DH + seg * 8 + 4));
        int d0 = seg * 8;
        VT[d0 + 0][row] = a.x;  VT[d0 + 1][row] = a.y;  VT[d0 + 2][row] = a.z;  VT[d0 + 3][row] = a.w;
        VT[d0 + 4][row] = bq.x; VT[d0 + 5][row] = bq.y; VT[d0 + 6][row] = bq.z; VT[d0 + 7][row] = bq.w;
    }
    __syncthreads();
    f32x4 zero = {0.f, 0.f, 0.f, 0.f};
    f32x4 sacc[8];
#pragma unroll
    for (int fn = 0; fn < 8; ++fn) sacc[fn] = zero;
#pragma unroll
    for (int kk = 0; kk < 2; ++kk) {
        bf16x8 af = *(bf16x8*)&qraw[kk];
#pragma unroll
        for (int fn = 0; fn < 8; ++fn) {
            bf16x8 bv = *(const bf16x8*)&Ks[fn * 16 + lrow][kk * 32 + lk * 8];
            sacc[fn] = __builtin_amdgcn_mfma_f32_16x16x32_bf16(af, bv, sacc[fn], 0, 0, 0);
        }
    }
    __syncthreads();   // all Ks reads complete before Ps overlays Ks
    int myq[4];
#pragma unroll
    for (int r = 0; r < 4; ++r) myq[r] = qid[wave * 16 + lk * 4 + r];
#pragma unroll
    for (int fn = 0; fn < 8; ++fn) {
        int kv = kid[lrow + fn * 16];
#pragma unroll
        for (int r = 0; r < 4; ++r)
            if (myq[r] == kv) sacc[fn][r] = MASKVAL;
    }
    float mx[4] = {-3.4e38f, -3.4e38f, -3.4e38f, -3.4e38f};
#pragma unroll
    for (int fn = 0; fn < 8; ++fn)
#pragma unroll
        for (int r = 0; r < 4; ++r) mx[r] = fmaxf(mx[r], sacc[fn][r]);
#pragma unroll
    for (int m = 1; m <= 8; m <<= 1)
#pragma unroll
        for (int r = 0; r < 4; ++r) mx[r] = fmaxf(mx[r], __shfl_xor(mx[r], m));
    float se[4] = {0.f, 0.f, 0.f, 0.f};
#pragma unroll
    for (int fn = 0; fn < 8; ++fn)
#pragma unroll
        for (int r = 0; r < 4; ++r) se[r] += __expf(sacc[fn][r] - mx[r]);
#pragma unroll
    for (int m = 1; m <= 8; m <<= 1)
#pragma unroll
        for (int r = 0; r < 4; ++r) se[r] += __shfl_xor(se[r], m);
    float lg[4];
#pragma unroll
    for (int r = 0; r < 4; ++r) lg[r] = mx[r] + __logf(se[r]);
#pragma unroll
    for (int fn = 0; fn < 8; ++fn)
#pragma unroll
        for (int r = 0; r < 4; ++r)
            Ps[wave * 16 + lk * 4 + r][lrow + fn * 16] = f2bf(__expf(sacc[fn][r] - lg[r]));
    if (lrow == 0) {
#pragma unroll
        for (int r = 0; r < 4; ++r)
            logit_s[(size_t)h * NSEQ + c * 64 + wave * 16 + lk * 4 + r] = lg[r];
    }
    __syncthreads();
    f32x4 oacc[4];
#pragma unroll
    for (int fn = 0; fn < 4; ++fn) oacc[fn] = zero;
#pragma unroll
    for (int ks = 0; ks < 4; ++ks) {
        bf16x8 af = *(const bf16x8*)&Ps[wave * 16 + lrow][ks * 32 + lk * 8];
#pragma unroll
        for (int fn = 0; fn < 4; ++fn) {
            bf16x8 bv = *(const bf16x8*)&VT[fn * 16 + lrow][ks * 32 + lk * 8];
            oacc[fn] = __builtin_amdgcn_mfma_f32_16x16x32_bf16(af, bv, oacc[fn], 0, 0, 0);
        }
    }
#pragma unroll
    for (int fn = 0; fn < 4; ++fn)
#pragma unroll
        for (int r = 0; r < 4; ++r) {
            int qrow = c * 64 + wave * 16 + lk * 4 + r;
            out_s[((size_t)h * NSEQ + qrow) * DH + lrow + fn * 16] = f2bf(oacc[fn][r]);
        }
}

// ---------------- unsort + combine hash rounds (all 4 batches) ----------------
__global__ void combine_kernel(const unsigned short* __restrict__ outs_lo,
                               const unsigned short* __restrict__ outs_hi,
                               const float* __restrict__ logit_s,
                               const int* __restrict__ inv, unsigned short* __restrict__ attn_comb) {
    size_t gid = (size_t)blockIdx.x * 256 + threadIdx.x;  // 4*H*S*16 threads
    int d4 = gid & 15;
    size_t r = gid >> 4;
    int s = (int)(r & (SS - 1));
    int h = (int)((r >> 13) & 3);
    int bl = (int)(r >> 15);                              // 0..3
    size_t hb = (size_t)(bl * NHEADS + h) * NSEQ;         // global (b,h) base for inv/logit
    const unsigned short* ob = (bl < 2) ? (outs_lo + (size_t)bl * HNSD)
                                        : (outs_hi + (size_t)(bl - 2) * HNSD);
    int j0 = inv[hb + s];
    int j1 = inv[hb + SS + s];
    float l0 = logit_s[hb + j0];
    float l1 = logit_s[hb + j1];
    float mxv = fmaxf(l0, l1);
    float e0 = __expf(l0 - mxv), e1 = __expf(l1 - mxv);
    float is = 1.f / (e0 + e1);
    float w0 = e0 * is, w1 = e1 * is;
    ushort4 u0 = *(const ushort4*)(ob + ((size_t)h * NSEQ + j0) * DH + d4 * 4);
    ushort4 u1 = *(const ushort4*)(ob + ((size_t)h * NSEQ + j1) * DH + d4 * 4);
    ushort4 o;
    o.x = f2bf(w0 * bf2f(u0.x) + w1 * bf2f(u1.x));
    o.y = f2bf(w0 * bf2f(u0.y) + w1 * bf2f(u1.y));
    o.z = f2bf(w0 * bf2f(u0.z) + w1 * bf2f(u1.z));
    o.w = f2bf(w0 * bf2f(u0.w) + w1 * bf2f(u1.w));
    *(ushort4*)(attn_comb + ((size_t)bl * SS + s) * HID + h * DH + d4 * 4) = o;
}

// ---------------- launch ----------------
extern "C" void kernel_launch(void* const* d_in, const int* in_sizes, int n_in,
                              void* d_out, int out_size, void* d_ws, size_t ws_size,
                              hipStream_t stream) {
    const float* hs  = (const float*)d_in[0];
    const float* g1  = (const float*)d_in[1];
    const float* b1  = (const float*)d_in[2];
    const float* Wqk = (const float*)d_in[3];
    const float* Wv  = (const float*)d_in[4];
    const float* Wo  = (const float*)d_in[5];
    const float* rot = (const float*)d_in[6];
    const float* g2  = (const float*)d_in[7];
    const float* b2  = (const float*)d_in[8];
    const float* W1  = (const float*)d_in[9];
    const float* bf1 = (const float*)d_in[10];
    const float* W2  = (const float*)d_in[11];
    const float* bf2 = (const float*)d_in[12];
    const float* gf  = (const float*)d_in[13];
    const float* bff = (const float*)d_in[14];

    const size_t NE = (size_t)BB * SS * HID;    // 8,388,608
    const size_t MROWS = (size_t)BB * SS;       // 32768

    // ---- d_ws layout (~91.5 MB; <= 93.3 MB proven in R2) ----
    float* f = (float*)d_ws;
    float* attn_out = f;                               // NE f32
    float* hidden   = f + NE;                          // NE f32
    float* mu       = f + 2 * NE;                      // 32768
    float* rstd     = mu + MROWS;                      // 32768
    float* qscale   = rstd + MROWS;                    // B*S*H = 131072
    float* logit_all = qscale + MROWS * NHEADS;        // B*H*NSEQ = 262144
    int* sortx = (int*)(logit_all + (size_t)BB * NHEADS * NSEQ);
    int* invx  = sortx + (size_t)BB * NHEADS * NSEQ;
    int* buckx = invx + (size_t)BB * NHEADS * NSEQ;
    unsigned short* wbf = (unsigned short*)(buckx + (size_t)BB * NHEADS * NSEQ);  // 2*655360 ushort
    unsigned short* outs_hi = wbf + 2 * 655360;        // 16.78 MB: attn outs (b2-3) / ffbuf part2

    // ---- d_out scratch (4 slots of 4,194,304 floats) ----
    float* o = (float*)d_out;
    unsigned short* abuf = (unsigned short*)o;              // slot0: xln_bf / attn_comb / h_ln
    unsigned short* outs_lo = (unsigned short*)(o + 4194304); // slot1: batches 0-1 sorted attn out
    unsigned short* k_bf = (unsigned short*)(o + 8388608);  // slot2
    unsigned short* v_bf = (unsigned short*)(o + 12582912); // slot3
    unsigned short* ffbuf1 = outs_lo;                       // phase D: slots 1-3 = rows [0,24576)
    unsigned short* ffbuf2 = outs_hi;                       // phase D: rows [24576,32768)

    // convert + transpose weights to bf16 once (layer-batched grids)
    wconv_kernel<<<dim3(HID / 32, HID / 32, NLAYERS), 256, 0, stream>>>(Wv, wbf, HID, HID, (size_t)HID * HID, 655360);
    wconv_kernel<<<dim3(HID / 32, HID / 32, NLAYERS), 256, 0, stream>>>(Wo, wbf + 65536, HID, HID, (size_t)HID * HID, 655360);
    wconv_kernel<<<dim3(HID / 32, FFD / 32, NLAYERS), 256, 0, stream>>>(W1, wbf + 131072, HID, FFD, (size_t)HID * FFD, 655360);
    wconv_kernel<<<dim3(FFD / 32, HID / 32, NLAYERS), 256, 0, stream>>>(W2, wbf + 393216, FFD, HID, (size_t)FFD * HID, 655360);

    for (int l = 0; l < NLAYERS; ++l) {
        const float* g1l = g1 + l * HID;
        const float* b1l = b1 + l * HID;
        const float* Wqkl = Wqk + (size_t)l * HID * HID;
        const float* rotl = rot + (size_t)l * NHEADS * DH * NHASH * NROT;
        const float* g2l = g2 + l * HID;
        const float* b2l = b2 + l * HID;
        const float* bf1l = bf1 + l * FFD;
        const float* bf2l = bf2 + l * HID;
        unsigned short* Wv_t = wbf + (size_t)l * 655360;
        unsigned short* Wo_t = Wv_t + 65536;
        unsigned short* W1_t = Wv_t + 131072;
        unsigned short* W2_t = Wv_t + 393216;
        const float* hid_in = (l == 0) ? hs : hidden;   // layer 0 reads inputs directly

        // ---- phase A (all-batch): LN(+stats) -> fused Wqk+hash -> Wv ----
        ln256_kernel<true><<<MROWS, 256, 0, stream>>>(hid_in, g1l, b1l, abuf, mu, rstd);
        qkhash_kernel<<<dim3(MROWS / 64, NHEADS), 256, 0, stream>>>(
            hid_in, mu, rstd, g1l, b1l, Wqkl, rotl, k_bf, qscale, buckx);
        mfma_gemm<4><<<dim3(MROWS / 128, HID / 128), 256, 0, stream>>>(
            abuf, nullptr, Wv_t, nullptr, v_bf, nullptr, MROWS, HID, HID, nullptr);

        // ---- phase B: sort all (b,h) ----
        sort_kernel<<<BB * NHEADS, 256, 0, stream>>>(buckx, sortx, invx);

        // ---- phase C: attention (all 4 batches in one launch) + combine + Wo ----
        attn_mfma<<<dim3(NCH, NHEADS, BB), 256, 0, stream>>>(
            k_bf, v_bf, qscale, sortx, outs_lo, outs_hi, logit_all);
        combine_kernel<<<(BB * NHEADS * SS * 16) / 256, 256, 0, stream>>>(
            outs_lo, outs_hi, logit_all, invx, abuf);
        if (l == 0)
            mfma_gemm<5><<<dim3(MROWS / 128, HID / 128), 256, 0, stream>>>(
                abuf, nullptr, Wo_t, nullptr, attn_out, nullptr, MROWS, HID, HID, hs);
        else
            mfma_gemm<2><<<dim3(MROWS / 128, HID / 128), 256, 0, stream>>>(
                abuf, nullptr, Wo_t, nullptr, attn_out, nullptr, MROWS, HID, HID, nullptr);

        // ---- phase D: FF single-launch over M=32768 with split ffbuf ----
        ln256_kernel<false><<<MROWS, 256, 0, stream>>>(attn_out, g2l, b2l, abuf, nullptr, nullptr);
        mfma_gemm<1><<<dim3(MROWS / 128, FFD / 128), 256, 0, stream>>>(
            abuf, nullptr, W1_t, bf1l, ffbuf1, ffbuf2, MROWS, FFD, HID, nullptr);
        if (l == 0)
            mfma_gemm<6><<<dim3(MROWS / 128, HID / 128), 256, 0, stream>>>(
                ffbuf1, ffbuf2, W2_t, bf2l, hidden, nullptr, MROWS, HID, FFD, hs);
        else
            mfma_gemm<3><<<dim3(MROWS / 128, HID / 128), 256, 0, stream>>>(
                ffbuf1, ffbuf2, W2_t, bf2l, hidden, nullptr, MROWS, HID, FFD, nullptr);
    }
    ln512_kernel<<<MROWS, 256, 0, stream>>>(attn_out, hidden, gf, bff, (float*)d_out);
}

// Round 15
// 654.284 us; speedup vs baseline: 1.3732x; 1.0868x over previous
//
#include <hip/hip_runtime.h>
#include <math.h>

#define BB 4
#define SS 8192
#define HID 256
#define NHEADS 4
#define DH 64
#define FFD 1024
#define NLAYERS 2
#define NHASH 2
#define NBUCK 128
#define NROT 64          // NBUCK/2
#define NSEQ (NHASH*SS)  // 16384
#define NCH (NSEQ/64)    // 256 chunks of 64
#define MASKVAL -1e5f
#define PBE ((size_t)SS*HID)
#define HNSD ((size_t)NHEADS*NSEQ*DH)   // per-batch outs elems (ushort)
#define SPLITROW 24576                  // ffbuf part1 holds rows [0,24576), part2 the rest

typedef __bf16 bf16x8 __attribute__((ext_vector_type(8)));
typedef float f32x4 __attribute__((ext_vector_type(4)));

__device__ __forceinline__ unsigned short f2bf(float x) {
    unsigned u = __float_as_uint(x);
    unsigned r = (u >> 16) & 1;
    u += 0x7fffu + r;              // RNE
    return (unsigned short)(u >> 16);
}
__device__ __forceinline__ float bf2f(unsigned short h) {
    return __uint_as_float(((unsigned)h) << 16);
}
__device__ __forceinline__ unsigned scale2(unsigned u, float qs) {
    float lo = __uint_as_float(u << 16) * qs;
    float hi = __uint_as_float(u & 0xffff0000u) * qs;
    return (unsigned)f2bf(lo) | (((unsigned)f2bf(hi)) << 16);
}

// ---------------- LayerNorm over 256: one wave per row, float4, shfl-only ----------------
template <bool STATS>
__global__ __launch_bounds__(256) void ln256_kernel(
    const float* __restrict__ x, const float* __restrict__ g,
    const float* __restrict__ b, unsigned short* __restrict__ ybf,
    float* __restrict__ mu_out, float* __restrict__ rstd_out) {
    int wave = threadIdx.x >> 6, lane = threadIdx.x & 63;
    int row = blockIdx.x * 4 + wave;
    float4 v = *(const float4*)(x + (size_t)row * HID + lane * 4);
    float s = v.x + v.y + v.z + v.w;
#pragma unroll
    for (int off = 32; off; off >>= 1) s += __shfl_xor(s, off);
    float mu = s * (1.f / 256.f);
    float dx = v.x - mu, dy = v.y - mu, dz = v.z - mu, dw = v.w - mu;
    float ss = dx * dx + dy * dy + dz * dz + dw * dw;
#pragma unroll
    for (int off = 32; off; off >>= 1) ss += __shfl_xor(ss, off);
    float rstd = rsqrtf(ss * (1.f / 256.f) + 1e-12f);
    float4 g4 = *(const float4*)(g + lane * 4);
    float4 b4 = *(const float4*)(b + lane * 4);
    ushort4 o;
    o.x = f2bf(dx * rstd * g4.x + b4.x);
    o.y = f2bf(dy * rstd * g4.y + b4.y);
    o.z = f2bf(dz * rstd * g4.z + b4.z);
    o.w = f2bf(dw * rstd * g4.w + b4.w);
    *(ushort4*)(ybf + (size_t)row * HID + lane * 4) = o;
    if (STATS && lane == 0) { mu_out[row] = mu; rstd_out[row] = rstd; }
}

// ---------------- Final LayerNorm over concat(512): one wave per row ----------------
__global__ __launch_bounds__(256) void ln512_kernel(
    const float* __restrict__ a, const float* __restrict__ hd,
    const float* __restrict__ g, const float* __restrict__ b,
    float* __restrict__ out) {
    int wave = threadIdx.x >> 6, lane = threadIdx.x & 63;
    int row = blockIdx.x * 4 + wave;
    float4 v0 = *(const float4*)(a + (size_t)row * HID + lane * 4);
    float4 v1 = *(const float4*)(hd + (size_t)row * HID + lane * 4);
    float s = v0.x + v0.y + v0.z + v0.w + v1.x + v1.y + v1.z + v1.w;
#pragma unroll
    for (int off = 32; off; off >>= 1) s += __shfl_xor(s, off);
    float mu = s * (1.f / 512.f);
    float d0x = v0.x - mu, d0y = v0.y - mu, d0z = v0.z - mu, d0w = v0.w - mu;
    float d1x = v1.x - mu, d1y = v1.y - mu, d1z = v1.z - mu, d1w = v1.w - mu;
    float ss = d0x * d0x + d0y * d0y + d0z * d0z + d0w * d0w
             + d1x * d1x + d1y * d1y + d1z * d1z + d1w * d1w;
#pragma unroll
    for (int off = 32; off; off >>= 1) ss += __shfl_xor(ss, off);
    float r = rsqrtf(ss * (1.f / 512.f) + 1e-12f);
    float4 ga = *(const float4*)(g + lane * 4);
    float4 gb = *(const float4*)(g + 256 + lane * 4);
    float4 ba = *(const float4*)(b + lane * 4);
    float4 bb = *(const float4*)(b + 256 + lane * 4);
    float4 oa, ob;
    oa.x = d0x * r * ga.x + ba.x; oa.y = d0y * r * ga.y + ba.y;
    oa.z = d0z * r * ga.z + ba.z; oa.w = d0w * r * ga.w + ba.w;
    ob.x = d1x * r * gb.x + bb.x; ob.y = d1y * r * gb.y + bb.y;
    ob.z = d1z * r * gb.z + bb.z; ob.w = d1w * r * gb.w + bb.w;
    *(float4*)(out + (size_t)row * 512 + lane * 4) = oa;
    *(float4*)(out + (size_t)row * 512 + 256 + lane * 4) = ob;
}

// ---------------- weight transpose + f32->bf16, layer batched: W[K,N] -> Wt[N,K] ----------------
__global__ void wconv_kernel(const float* __restrict__ W, unsigned short* __restrict__ Wt,
                             int K, int N, size_t wstride, size_t tstride) {
    __shared__ float t[32][33];
    int l = blockIdx.z;
    W += (size_t)l * wstride;
    Wt += (size_t)l * tstride;
    int k0 = blockIdx.x * 32, n0 = blockIdx.y * 32;
    int tx = threadIdx.x & 31, ty = threadIdx.x >> 5;  // 32 x 8
#pragma unroll
    for (int i = 0; i < 32; i += 8) t[ty + i][tx] = W[(size_t)(k0 + ty + i) * N + n0 + tx];
    __syncthreads();
#pragma unroll
    for (int i = 0; i < 32; i += 8) Wt[(size_t)(n0 + ty + i) * K + k0 + tx] = f2bf(t[tx][ty + i]);
}

// ---------------- fused fp32 Wqk GEMM + LN-on-the-fly + qk-norm + LSH hash ----------------
// R10 structure exactly (K-step 16, separate LDS arrays): frozen local optimum, 135 us.
__global__ __launch_bounds__(256) void qkhash_kernel(
    const float* __restrict__ hid, const float* __restrict__ mu,
    const float* __restrict__ rstd, const float* __restrict__ gamma,
    const float* __restrict__ beta, const float* __restrict__ Wqk,
    const float* __restrict__ rot, unsigned short* __restrict__ kb,
    float* __restrict__ qscale, int* __restrict__ buckets) {
    __shared__ float As[16][68];
    __shared__ float Bs[16][68];
    __shared__ float QsT[64][68];     // [d][row]
    __shared__ float rotLDS[64][132]; // [d][col], both hash rounds
    int bm = blockIdx.x * 64;
    int h = blockIdx.y;
    int tid = threadIdx.x;
    int tx = tid & 15, ty = tid >> 4;
    float acc[4][4] = {};
    for (int k0 = 0; k0 < HID; k0 += 16) {
#pragma unroll
        for (int t = 0; t < 4; ++t) {
            int e = tid + t * 256;
            int m = e >> 4, kk = e & 15;
            int row = bm + m;
            float x = hid[(size_t)row * HID + k0 + kk];
            As[kk][m] = (x - mu[row]) * rstd[row] * gamma[k0 + kk] + beta[k0 + kk];
        }
#pragma unroll
        for (int t = 0; t < 4; ++t) {
            int e = tid + t * 256;
            int kk = e >> 6, n = e & 63;
            Bs[kk][n] = Wqk[(size_t)(k0 + kk) * HID + h * DH + n];
        }
        __syncthreads();
#pragma unroll
        for (int kk = 0; kk < 16; ++kk) {
            float4 a4 = *(float4*)&As[kk][ty * 4];
            float4 b4 = *(float4*)&Bs[kk][tx * 4];
            float a0[4] = {a4.x, a4.y, a4.z, a4.w};
            float b0[4] = {b4.x, b4.y, b4.z, b4.w};
#pragma unroll
            for (int i = 0; i < 4; ++i)
#pragma unroll
                for (int j = 0; j < 4; ++j) acc[i][j] += a0[i] * b0[j];
        }
        __syncthreads();
    }
    // per-row ||q||^2 over this head's 64 dims (reduce across tx group)
    float ssq_[4];
#pragma unroll
    for (int i = 0; i < 4; ++i) {
        float s = 0;
#pragma unroll
        for (int j = 0; j < 4; ++j) s += acc[i][j] * acc[i][j];
        ssq_[i] = s;
    }
#pragma unroll
    for (int mask = 1; mask <= 8; mask <<= 1)
#pragma unroll
        for (int i = 0; i < 4; ++i) ssq_[i] += __shfl_xor(ssq_[i], mask);
    // write k_bf + qscale
#pragma unroll
    for (int i = 0; i < 4; ++i) {
        int row = bm + ty * 4 + i;
        float nrm = fmaxf(sqrtf(ssq_[i]), 1e-12f);
        float sc = 0.125f / nrm;
        ushort4 kv;
        kv.x = f2bf(acc[i][0] * sc); kv.y = f2bf(acc[i][1] * sc);
        kv.z = f2bf(acc[i][2] * sc); kv.w = f2bf(acc[i][3] * sc);
        *(ushort4*)(kb + (size_t)row * HID + h * DH + tx * 4) = kv;
        if (tx == 0) qscale[(size_t)row * NHEADS + h] = 8.f * nrm;
    }
    // stage QsT via contiguous float4 in transposed layout
#pragma unroll
    for (int j = 0; j < 4; ++j) {
        float4 v = make_float4(acc[0][j], acc[1][j], acc[2][j], acc[3][j]);
        *(float4*)&QsT[tx * 4 + j][ty * 4] = v;
    }
    // load rot[h]: both rounds
    const float* rp = rot + (size_t)h * DH * NHASH * NROT;
#pragma unroll
    for (int t = 0; t < 8; ++t) {
        int e = tid + t * 256;
        int d = e >> 5, c4 = e & 31;
        *(float4*)&rotLDS[d][c4 * 4] = *(const float4*)(rp + d * 128 + c4 * 4);
    }
    __syncthreads();
    // hash: rotated = qk_tile @ rot, argmax over [rot, -rot]
    float acc2[4][8] = {};
#pragma unroll 2
    for (int d = 0; d < 64; ++d) {
        float4 a4 = *(float4*)&QsT[d][ty * 4];
        float a_[4] = {a4.x, a4.y, a4.z, a4.w};
        float4 b0 = *(float4*)&rotLDS[d][tx * 8];
        float4 b1v = *(float4*)&rotLDS[d][tx * 8 + 4];
#pragma unroll
        for (int i = 0; i < 4; ++i) {
            acc2[i][0] += a_[i] * b0.x;  acc2[i][1] += a_[i] * b0.y;
            acc2[i][2] += a_[i] * b0.z;  acc2[i][3] += a_[i] * b0.w;
            acc2[i][4] += a_[i] * b1v.x; acc2[i][5] += a_[i] * b1v.y;
            acc2[i][6] += a_[i] * b1v.z; acc2[i][7] += a_[i] * b1v.w;
        }
    }
    int n = tx >> 3;
#pragma unroll
    for (int i = 0; i < 4; ++i) {
        float bp = -3.4e38f, bn = -3.4e38f;
        int ipx = 0, inx = 0;
#pragma unroll
        for (int j = 0; j < 8; ++j) {
            float v = acc2[i][j];
            int r = ((tx & 7) * 8 + j);
            if (v > bp)  { bp = v;  ipx = r; }
            if (-v > bn) { bn = -v; inx = r; }
        }
#pragma unroll
        for (int mask = 1; mask <= 4; mask <<= 1) {
            float obp = __shfl_xor(bp, mask); int oip = __shfl_xor(ipx, mask);
            float obn = __shfl_xor(bn, mask); int oin = __shfl_xor(inx, mask);
            if (obp > bp || (obp == bp && oip < ipx)) { bp = obp; ipx = oip; }
            if (obn > bn || (obn == bn && oin < inx)) { bn = obn; inx = oin; }
        }
        if ((tx & 7) == 0) {
            int bucket = (bn > bp) ? (NROT + inx) : ipx;
            int row = bm + ty * 4 + i;
            int bb = row >> 13, sl = row & (SS - 1);
            buckets[(size_t)bb * NHEADS * NSEQ + h * NSEQ + n * SS + sl] = bucket + n * NBUCK;
        }
    }
}

// ---------------- bf16 MFMA GEMM with optional split-A / split-C at row SPLITROW ----------------
// EPI: 1 = bias+relu -> bf16, 2 = f32 C += acc, 3 = f32 C += acc + bias, 4 = store bf16,
//      5 = f32 C = Csrc + acc, 6 = f32 C = Csrc + acc + bias
template <int EPI>
__global__ __launch_bounds__(256) void mfma_gemm(
    const unsigned short* __restrict__ A, const unsigned short* __restrict__ A2,
    const unsigned short* __restrict__ Bt, const float* __restrict__ bias,
    void* __restrict__ Cv, void* __restrict__ Cv2,
    int M, int N, int K, const float* __restrict__ Csrc) {
    __shared__ unsigned short Asl[128 * 64];
    __shared__ unsigned short Bsl[128 * 64];
    int bm = blockIdx.x * 128, bn = blockIdx.y * 128;
    int tid = threadIdx.x;
    int wave = tid >> 6, lane = tid & 63;
    int wm = (wave >> 1) * 64, wn = (wave & 1) * 64;
    int lrow = lane & 15, lk = lane >> 4;
    const unsigned short* Ab = A + (size_t)bm * K;
    if (A2 != nullptr && bm >= SPLITROW) Ab = A2 + (size_t)(bm - SPLITROW) * K;
    bool chi = (Cv2 != nullptr) && (bm >= SPLITROW);
    void* Cb = chi ? Cv2 : Cv;
    int crow0 = chi ? SPLITROW : 0;
    f32x4 zero = {0.f, 0.f, 0.f, 0.f};
    f32x4 acc[4][4];
#pragma unroll
    for (int i = 0; i < 4; ++i)
#pragma unroll
        for (int j = 0; j < 4; ++j) acc[i][j] = zero;

    for (int k0 = 0; k0 < K; k0 += 64) {
#pragma unroll
        for (int t = 0; t < 4; ++t) {
            int e = tid + t * 256;
            int r = e >> 3, kc = (e & 7) * 8;
            int4 v = *(const int4*)(Ab + (size_t)r * K + k0 + kc);
            *(int4*)((char*)Asl + r * 128 + ((kc * 2) ^ ((r & 7) << 4))) = v;
        }
#pragma unroll
        for (int t = 0; t < 4; ++t) {
            int e = tid + t * 256;
            int r = e >> 3, kc = (e & 7) * 8;
            int4 v = *(const int4*)(Bt + (size_t)(bn + r) * K + k0 + kc);
            *(int4*)((char*)Bsl + r * 128 + ((kc * 2) ^ ((r & 7) << 4))) = v;
        }
        __syncthreads();
#pragma unroll
        for (int kk = 0; kk < 2; ++kk) {
            int klocal = kk * 32 + lk * 8;
            bf16x8 af[4], bfv[4];
#pragma unroll
            for (int fm = 0; fm < 4; ++fm) {
                int r = wm + fm * 16 + lrow;
                af[fm] = *(const bf16x8*)((const char*)Asl + r * 128 + ((klocal * 2) ^ ((r & 7) << 4)));
            }
#pragma unroll
            for (int fn = 0; fn < 4; ++fn) {
                int r = wn + fn * 16 + lrow;
                bfv[fn] = *(const bf16x8*)((const char*)Bsl + r * 128 + ((klocal * 2) ^ ((r & 7) << 4)));
            }
#pragma unroll
            for (int fm = 0; fm < 4; ++fm)
#pragma unroll
                for (int fn = 0; fn < 4; ++fn)
                    acc[fm][fn] = __builtin_amdgcn_mfma_f32_16x16x32_bf16(af[fm], bfv[fn], acc[fm][fn], 0, 0, 0);
        }
        __syncthreads();
    }
#pragma unroll
    for (int fm = 0; fm < 4; ++fm)
#pragma unroll
        for (int fn = 0; fn < 4; ++fn) {
            int col = bn + wn + fn * 16 + lrow;
#pragma unroll
            for (int r = 0; r < 4; ++r) {
                int row = bm + wm + fm * 16 + lk * 4 + r;
                size_t crow = (size_t)(row - crow0);
                float v = acc[fm][fn][r];
                if (EPI == 1) {
                    v += bias[col]; v = fmaxf(v, 0.f);
                    ((unsigned short*)Cb)[crow * N + col] = f2bf(v);
                } else if (EPI == 2) {
                    ((float*)Cb)[crow * N + col] += v;
                } else if (EPI == 3) {
                    ((float*)Cb)[crow * N + col] += v + bias[col];
                } else if (EPI == 4) {
                    ((unsigned short*)Cb)[crow * N + col] = f2bf(v);
                } else if (EPI == 5) {
                    ((float*)Cb)[crow * N + col] = Csrc[(size_t)row * N + col] + v;
                } else {
                    ((float*)Cb)[crow * N + col] = Csrc[(size_t)row * N + col] + v + bias[col];
                }
            }
        }
}

// ---------------- parallel stable counting sort: 256 threads, one block per (b,h) ----------------
__global__ __launch_bounds__(256) void sort_kernel(const int* __restrict__ buckets,
                                                   int* __restrict__ sort_idx,
                                                   int* __restrict__ inv) {
    int bh = blockIdx.x;
    const int* bk = buckets + (size_t)bh * NSEQ;
    int* sj = sort_idx + (size_t)bh * NSEQ;
    int* ij = inv + (size_t)bh * NSEQ;
    __shared__ unsigned short cnt[256][258];  // [bin][thread-col], 132 KB
    __shared__ int colsum[256];
    int tid = threadIdx.x;
    unsigned* cz = (unsigned*)&cnt[0][0];
#pragma unroll
    for (int t = 0; t < 129; ++t) cz[tid * 129 + t] = 0;
    __syncthreads();
    int base = tid * 64;  // thread owns 64 contiguous items -> stability
    for (int j = 0; j < 64; j += 4) {
        int4 b4 = *(const int4*)(bk + base + j);
        cnt[b4.x][tid]++; cnt[b4.y][tid]++; cnt[b4.z][tid]++; cnt[b4.w][tid]++;
    }
    __syncthreads();
    {
        int run = 0;
        for (int c = 0; c < 256; ++c) { int v = cnt[tid][c]; cnt[tid][c] = (unsigned short)run; run += v; }
        colsum[tid] = run;
    }
    __syncthreads();
    if (tid == 0) {
        int run = 0;
        for (int j = 0; j < 256; ++j) { int c = colsum[j]; colsum[j] = run; run += c; }
    }
    __syncthreads();
    {
        int bs = colsum[tid];
        for (int c = 0; c < 256; ++c) cnt[tid][c] = (unsigned short)(cnt[tid][c] + bs);
    }
    __syncthreads();
    for (int j = 0; j < 64; j += 4) {
        int4 b4 = *(const int4*)(bk + base + j);
        int i0 = base + j;
        int r;
        r = cnt[b4.x][tid]++; sj[r] = i0;     ij[i0]     = r;
        r = cnt[b4.y][tid]++; sj[r] = i0 + 1; ij[i0 + 1] = r;
        r = cnt[b4.z][tid]++; sj[r] = i0 + 2; ij[i0 + 2] = r;
        r = cnt[b4.w][tid]++; sj[r] = i0 + 3; ij[i0 + 3] = r;
    }
}

// ---------------- MFMA chunked LSH attention (Q in registers; 37.4 KB LDS) ----------------
// grid (NCH, NHEADS, 4) -- blockIdx.z = batch; outs split lo (batches 0-1) / hi (2-3)
__global__ __launch_bounds__(256) void attn_mfma(
    const unsigned short* __restrict__ kbf, const unsigned short* __restrict__ vbf,
    const float* __restrict__ qscale, const int* __restrict__ sort_idx,
    unsigned short* __restrict__ outs_lo, unsigned short* __restrict__ outs_hi,
    float* __restrict__ logit_s) {
    __shared__ unsigned short KsPs[128][72];     // Ks during QK^T; Ps [64][136] overlay after
    __shared__ unsigned short VT[64][142];       // stride 142: 8*71 % 32 = 24 -> 4 bank groups
    __shared__ int qid[64];
    __shared__ int kid[128];
    unsigned short (*Ks)[72] = KsPs;
    unsigned short (*Ps)[136] = (unsigned short(*)[136])&KsPs[0][0];
    int c = blockIdx.x, h = blockIdx.y, z = blockIdx.z;
    kbf += (size_t)z * PBE;
    vbf += (size_t)z * PBE;
    qscale += (size_t)z * SS * NHEADS;
    sort_idx += (size_t)z * NHEADS * NSEQ;
    unsigned short* out_s = (z < 2) ? (outs_lo + (size_t)z * HNSD) : (outs_hi + (size_t)(z - 2) * HNSD);
    logit_s += (size_t)z * NHEADS * NSEQ;
    int tid = threadIdx.x;
    const int* si = sort_idx + (size_t)h * NSEQ;
    int cprev = (c == 0) ? (NCH - 1) : (c - 1);
    if (tid < 64) qid[tid] = si[c * 64 + tid];
    else if (tid < 192) {
        int k = tid - 64;
        kid[k] = (k < 64) ? si[cprev * 64 + k] : si[c * 64 + (k - 64)];
    }
    __syncthreads();
    int wave = tid >> 6, lane = tid & 63;
    int lrow = lane & 15, lk = lane >> 4;
    // Q fragments straight to registers
    int qsrow = qid[wave * 16 + lrow] & (SS - 1);
    float qsc = qscale[(size_t)qsrow * NHEADS + h];
    int4 qraw[2];
#pragma unroll
    for (int kk = 0; kk < 2; ++kk) {
        int4 raw = *(const int4*)(kbf + ((size_t)qsrow * HID + h * DH + kk * 32 + lk * 8));
        raw.x = (int)scale2((unsigned)raw.x, qsc);
        raw.y = (int)scale2((unsigned)raw.y, qsc);
        raw.z = (int)scale2((unsigned)raw.z, qsc);
        raw.w = (int)scale2((unsigned)raw.w, qsc);
        qraw[kk] = raw;
    }
    // K staging (128 x 64 bf16)
#pragma unroll
    for (int t = 0; t < 4; ++t) {
        int e = tid + t * 256;
        int row = e >> 3, seg = e & 7;
        int s = kid[row] & (SS - 1);
        *(int4*)&Ks[row][seg * 8] = *(const int4*)(kbf + ((size_t)s * HID + h * DH + seg * 8));
    }
    // V staging transposed
#pragma unroll
    for (int t = 0; t < 4; ++t) {
        int e = tid + t * 256;
        int row = e >> 3, seg = e & 7;
        int s = kid[row] & (SS - 1);
        ushort4 a = *(const ushort4*)(vbf + ((size_t)s * HID + h * DH + seg * 8));
        ushort4 bq = *(const ushort4*)(vbf + ((size_t)s * HID + h * DH + seg * 8 + 4));
        int d0 = seg * 8;
        VT[d0 + 0][row] = a.x;  VT[d0 + 1][row] = a.y;  VT[d0 + 2][row] = a.z;  VT[d0 + 3][row] = a.w;
        VT[d0 + 4][row] = bq.x; VT[d0 + 5][row] = bq.y; VT[d0 + 6][row] = bq.z; VT[d0 + 7][row] = bq.w;
    }
    __syncthreads();
    f32x4 zero = {0.f, 0.f, 0.f, 0.f};
    f32x4 sacc[8];
#pragma unroll
    for (int fn = 0; fn < 8; ++fn) sacc[fn] = zero;
#pragma unroll
    for (int kk = 0; kk < 2; ++kk) {
        bf16x8 af = *(bf16x8*)&qraw[kk];
#pragma unroll
        for (int fn = 0; fn < 8; ++fn) {
            bf16x8 bv = *(const bf16x8*)&Ks[fn * 16 + lrow][kk * 32 + lk * 8];
            sacc[fn] = __builtin_amdgcn_mfma_f32_16x16x32_bf16(af, bv, sacc[fn], 0, 0, 0);
        }
    }
    __syncthreads();   // all Ks reads complete before Ps overlays Ks
    int myq[4];
#pragma unroll
    for (int r = 0; r < 4; ++r) myq[r] = qid[wave * 16 + lk * 4 + r];
#pragma unroll
    for (int fn = 0; fn < 8; ++fn) {
        int kv = kid[lrow + fn * 16];
#pragma unroll
        for (int r = 0; r < 4; ++r)
            if (myq[r] == kv) sacc[fn][r] = MASKVAL;
    }
    float mx[4] = {-3.4e38f, -3.4e38f, -3.4e38f, -3.4e38f};
#pragma unroll
    for (int fn = 0; fn < 8; ++fn)
#pragma unroll
        for (int r = 0; r < 4; ++r) mx[r] = fmaxf(mx[r], sacc[fn][r]);
#pragma unroll
    for (int m = 1; m <= 8; m <<= 1)
#pragma unroll
        for (int r = 0; r < 4; ++r) mx[r] = fmaxf(mx[r], __shfl_xor(mx[r], m));
    float se[4] = {0.f, 0.f, 0.f, 0.f};
#pragma unroll
    for (int fn = 0; fn < 8; ++fn)
#pragma unroll
        for (int r = 0; r < 4; ++r) se[r] += __expf(sacc[fn][r] - mx[r]);
#pragma unroll
    for (int m = 1; m <= 8; m <<= 1)
#pragma unroll
        for (int r = 0; r < 4; ++r) se[r] += __shfl_xor(se[r], m);
    float lg[4];
#pragma unroll
    for (int r = 0; r < 4; ++r) lg[r] = mx[r] + __logf(se[r]);
#pragma unroll
    for (int fn = 0; fn < 8; ++fn)
#pragma unroll
        for (int r = 0; r < 4; ++r)
            Ps[wave * 16 + lk * 4 + r][lrow + fn * 16] = f2bf(__expf(sacc[fn][r] - lg[r]));
    if (lrow == 0) {
#pragma unroll
        for (int r = 0; r < 4; ++r)
            logit_s[(size_t)h * NSEQ + c * 64 + wave * 16 + lk * 4 + r] = lg[r];
    }
    __syncthreads();
    f32x4 oacc[4];
#pragma unroll
    for (int fn = 0; fn < 4; ++fn) oacc[fn] = zero;
#pragma unroll
    for (int ks = 0; ks < 4; ++ks) {
        bf16x8 af = *(const bf16x8*)&Ps[wave * 16 + lrow][ks * 32 + lk * 8];
#pragma unroll
        for (int fn = 0; fn < 4; ++fn) {
            bf16x8 bv = *(const bf16x8*)&VT[fn * 16 + lrow][ks * 32 + lk * 8];
            oacc[fn] = __builtin_amdgcn_mfma_f32_16x16x32_bf16(af, bv, oacc[fn], 0, 0, 0);
        }
    }
#pragma unroll
    for (int fn = 0; fn < 4; ++fn)
#pragma unroll
        for (int r = 0; r < 4; ++r) {
            int qrow = c * 64 + wave * 16 + lk * 4 + r;
            out_s[((size_t)h * NSEQ + qrow) * DH + lrow + fn * 16] = f2bf(oacc[fn][r]);
        }
}

// ---------------- unsort + combine hash rounds (all 4 batches) ----------------
__global__ void combine_kernel(const unsigned short* __restrict__ outs_lo,
                               const unsigned short* __restrict__ outs_hi,
                               const float* __restrict__ logit_s,
                               const int* __restrict__ inv, unsigned short* __restrict__ attn_comb) {
    size_t gid = (size_t)blockIdx.x * 256 + threadIdx.x;  // 4*H*S*16 threads
    int d4 = gid & 15;
    size_t r = gid >> 4;
    int s = (int)(r & (SS - 1));
    int h = (int)((r >> 13) & 3);
    int bl = (int)(r >> 15);                              // 0..3
    size_t hb = (size_t)(bl * NHEADS + h) * NSEQ;         // global (b,h) base for inv/logit
    const unsigned short* ob = (bl < 2) ? (outs_lo + (size_t)bl * HNSD)
                                        : (outs_hi + (size_t)(bl - 2) * HNSD);
    int j0 = inv[hb + s];
    int j1 = inv[hb + SS + s];
    float l0 = logit_s[hb + j0];
    float l1 = logit_s[hb + j1];
    float mxv = fmaxf(l0, l1);
    float e0 = __expf(l0 - mxv), e1 = __expf(l1 - mxv);
    float is = 1.f / (e0 + e1);
    float w0 = e0 * is, w1 = e1 * is;
    ushort4 u0 = *(const ushort4*)(ob + ((size_t)h * NSEQ + j0) * DH + d4 * 4);
    ushort4 u1 = *(const ushort4*)(ob + ((size_t)h * NSEQ + j1) * DH + d4 * 4);
    ushort4 o;
    o.x = f2bf(w0 * bf2f(u0.x) + w1 * bf2f(u1.x));
    o.y = f2bf(w0 * bf2f(u0.y) + w1 * bf2f(u1.y));
    o.z = f2bf(w0 * bf2f(u0.z) + w1 * bf2f(u1.z));
    o.w = f2bf(w0 * bf2f(u0.w) + w1 * bf2f(u1.w));
    *(ushort4*)(attn_comb + ((size_t)bl * SS + s) * HID + h * DH + d4 * 4) = o;
}

// ---------------- launch ----------------
extern "C" void kernel_launch(void* const* d_in, const int* in_sizes, int n_in,
                              void* d_out, int out_size, void* d_ws, size_t ws_size,
                              hipStream_t stream) {
    const float* hs  = (const float*)d_in[0];
    const float* g1  = (const float*)d_in[1];
    const float* b1  = (const float*)d_in[2];
    const float* Wqk = (const float*)d_in[3];
    const float* Wv  = (const float*)d_in[4];
    const float* Wo  = (const float*)d_in[5];
    const float* rot = (const float*)d_in[6];
    const float* g2  = (const float*)d_in[7];
    const float* b2  = (const float*)d_in[8];
    const float* W1  = (const float*)d_in[9];
    const float* bf1 = (const float*)d_in[10];
    const float* W2  = (const float*)d_in[11];
    const float* bf2 = (const float*)d_in[12];
    const float* gf  = (const float*)d_in[13];
    const float* bff = (const float*)d_in[14];

    const size_t NE = (size_t)BB * SS * HID;    // 8,388,608
    const size_t MROWS = (size_t)BB * SS;       // 32768

    // ---- d_ws layout (~91.5 MB; <= 93.3 MB proven in R2) ----
    float* f = (float*)d_ws;
    float* attn_out = f;                               // NE f32
    float* hidden   = f + NE;                          // NE f32
    float* mu       = f + 2 * NE;                      // 32768
    float* rstd     = mu + MROWS;                      // 32768
    float* qscale   = rstd + MROWS;                    // B*S*H = 131072
    float* logit_all = qscale + MROWS * NHEADS;        // B*H*NSEQ = 262144
    int* sortx = (int*)(logit_all + (size_t)BB * NHEADS * NSEQ);
    int* invx  = sortx + (size_t)BB * NHEADS * NSEQ;
    int* buckx = invx + (size_t)BB * NHEADS * NSEQ;
    unsigned short* wbf = (unsigned short*)(buckx + (size_t)BB * NHEADS * NSEQ);  // 2*655360 ushort
    unsigned short* outs_hi = wbf + 2 * 655360;        // 16.78 MB: attn outs (b2-3) / ffbuf part2

    // ---- d_out scratch (4 slots of 4,194,304 floats) ----
    float* o = (float*)d_out;
    unsigned short* abuf = (unsigned short*)o;              // slot0: xln_bf / attn_comb / h_ln
    unsigned short* outs_lo = (unsigned short*)(o + 4194304); // slot1: batches 0-1 sorted attn out
    unsigned short* k_bf = (unsigned short*)(o + 8388608);  // slot2
    unsigned short* v_bf = (unsigned short*)(o + 12582912); // slot3
    unsigned short* ffbuf1 = outs_lo;                       // phase D: slots 1-3 = rows [0,24576)
    unsigned short* ffbuf2 = outs_hi;                       // phase D: rows [24576,32768)

    // convert + transpose weights to bf16 once (layer-batched grids)
    wconv_kernel<<<dim3(HID / 32, HID / 32, NLAYERS), 256, 0, stream>>>(Wv, wbf, HID, HID, (size_t)HID * HID, 655360);
    wconv_kernel<<<dim3(HID / 32, HID / 32, NLAYERS), 256, 0, stream>>>(Wo, wbf + 65536, HID, HID, (size_t)HID * HID, 655360);
    wconv_kernel<<<dim3(HID / 32, FFD / 32, NLAYERS), 256, 0, stream>>>(W1, wbf + 131072, HID, FFD, (size_t)HID * FFD, 655360);
    wconv_kernel<<<dim3(FFD / 32, HID / 32, NLAYERS), 256, 0, stream>>>(W2, wbf + 393216, FFD, HID, (size_t)FFD * HID, 655360);

    for (int l = 0; l < NLAYERS; ++l) {
        const float* g1l = g1 + l * HID;
        const float* b1l = b1 + l * HID;
        const float* Wqkl = Wqk + (size_t)l * HID * HID;
        const float* rotl = rot + (size_t)l * NHEADS * DH * NHASH * NROT;
        const float* g2l = g2 + l * HID;
        const float* b2l = b2 + l * HID;
        const float* bf1l = bf1 + l * FFD;
        const float* bf2l = bf2 + l * HID;
        unsigned short* Wv_t = wbf + (size_t)l * 655360;
        unsigned short* Wo_t = Wv_t + 65536;
        unsigned short* W1_t = Wv_t + 131072;
        unsigned short* W2_t = Wv_t + 393216;
        const float* hid_in = (l == 0) ? hs : hidden;   // layer 0 reads inputs directly

        // ---- phase A (all-batch): LN(+stats) -> fused Wqk+hash -> Wv ----
        ln256_kernel<true><<<MROWS / 4, 256, 0, stream>>>(hid_in, g1l, b1l, abuf, mu, rstd);
        qkhash_kernel<<<dim3(MROWS / 64, NHEADS), 256, 0, stream>>>(
            hid_in, mu, rstd, g1l, b1l, Wqkl, rotl, k_bf, qscale, buckx);
        mfma_gemm<4><<<dim3(MROWS / 128, HID / 128), 256, 0, stream>>>(
            abuf, nullptr, Wv_t, nullptr, v_bf, nullptr, MROWS, HID, HID, nullptr);

        // ---- phase B: sort all (b,h) ----
        sort_kernel<<<BB * NHEADS, 256, 0, stream>>>(buckx, sortx, invx);

        // ---- phase C: attention (all 4 batches in one launch) + combine + Wo ----
        attn_mfma<<<dim3(NCH, NHEADS, BB), 256, 0, stream>>>(
            k_bf, v_bf, qscale, sortx, outs_lo, outs_hi, logit_all);
        combine_kernel<<<(BB * NHEADS * SS * 16) / 256, 256, 0, stream>>>(
            outs_lo, outs_hi, logit_all, invx, abuf);
        if (l == 0)
            mfma_gemm<5><<<dim3(MROWS / 128, HID / 128), 256, 0, stream>>>(
                abuf, nullptr, Wo_t, nullptr, attn_out, nullptr, MROWS, HID, HID, hs);
        else
            mfma_gemm<2><<<dim3(MROWS / 128, HID / 128), 256, 0, stream>>>(
                abuf, nullptr, Wo_t, nullptr, attn_out, nullptr, MROWS, HID, HID, nullptr);

        // ---- phase D: FF single-launch over M=32768 with split ffbuf ----
        ln256_kernel<false><<<MROWS / 4, 256, 0, stream>>>(attn_out, g2l, b2l, abuf, nullptr, nullptr);
        mfma_gemm<1><<<dim3(MROWS / 128, FFD / 128), 256, 0, stream>>>(
            abuf, nullptr, W1_t, bf1l, ffbuf1, ffbuf2, MROWS, FFD, HID, nullptr);
        if (l == 0)
            mfma_gemm<6><<<dim3(MROWS / 128, HID / 128), 256, 0, stream>>>(
                ffbuf1, ffbuf2, W2_t, bf2l, hidden, nullptr, MROWS, HID, FFD, hs);
        else
            mfma_gemm<3><<<dim3(MROWS / 128, HID / 128), 256, 0, stream>>>(
                ffbuf1, ffbuf2, W2_t, bf2l, hidden, nullptr, MROWS, HID, FFD, nullptr);
    }
    ln512_kernel<<<MROWS / 4, 256, 0, stream>>>(attn_out, hidden, gf, bff, (float*)d_out);
}

// Round 16
// 647.804 us; speedup vs baseline: 1.3869x; 1.0100x over previous
//
#include <hip/hip_runtime.h>
#include <math.h>

#define BB 4
#define SS 8192
#define HID 256
#define NHEADS 4
#define DH 64
#define FFD 1024
#define NLAYERS 2
#define NHASH 2
#define NBUCK 128
#define NROT 64          // NBUCK/2
#define NSEQ (NHASH*SS)  // 16384
#define NCH (NSEQ/64)    // 256 chunks of 64
#define MASKVAL -1e5f
#define PBE ((size_t)SS*HID)
#define HNSD ((size_t)NHEADS*NSEQ*DH)   // per-batch outs elems (ushort)
#define SPLITROW 24576                  // ffbuf part1 holds rows [0,24576), part2 the rest

typedef __bf16 bf16x8 __attribute__((ext_vector_type(8)));
typedef float f32x4 __attribute__((ext_vector_type(4)));

__device__ __forceinline__ unsigned short f2bf(float x) {
    unsigned u = __float_as_uint(x);
    unsigned r = (u >> 16) & 1;
    u += 0x7fffu + r;              // RNE
    return (unsigned short)(u >> 16);
}
__device__ __forceinline__ float bf2f(unsigned short h) {
    return __uint_as_float(((unsigned)h) << 16);
}
__device__ __forceinline__ unsigned scale2(unsigned u, float qs) {
    float lo = __uint_as_float(u << 16) * qs;
    float hi = __uint_as_float(u & 0xffff0000u) * qs;
    return (unsigned)f2bf(lo) | (((unsigned)f2bf(hi)) << 16);
}

// ---------------- LayerNorm over 256: one wave per row, float4, shfl-only ----------------
template <bool STATS>
__global__ __launch_bounds__(256) void ln256_kernel(
    const float* __restrict__ x, const float* __restrict__ g,
    const float* __restrict__ b, unsigned short* __restrict__ ybf,
    float* __restrict__ mu_out, float* __restrict__ rstd_out) {
    int wave = threadIdx.x >> 6, lane = threadIdx.x & 63;
    int row = blockIdx.x * 4 + wave;
    float4 v = *(const float4*)(x + (size_t)row * HID + lane * 4);
    float s = v.x + v.y + v.z + v.w;
#pragma unroll
    for (int off = 32; off; off >>= 1) s += __shfl_xor(s, off);
    float mu = s * (1.f / 256.f);
    float dx = v.x - mu, dy = v.y - mu, dz = v.z - mu, dw = v.w - mu;
    float ss = dx * dx + dy * dy + dz * dz + dw * dw;
#pragma unroll
    for (int off = 32; off; off >>= 1) ss += __shfl_xor(ss, off);
    float rstd = rsqrtf(ss * (1.f / 256.f) + 1e-12f);
    float4 g4 = *(const float4*)(g + lane * 4);
    float4 b4 = *(const float4*)(b + lane * 4);
    ushort4 o;
    o.x = f2bf(dx * rstd * g4.x + b4.x);
    o.y = f2bf(dy * rstd * g4.y + b4.y);
    o.z = f2bf(dz * rstd * g4.z + b4.z);
    o.w = f2bf(dw * rstd * g4.w + b4.w);
    *(ushort4*)(ybf + (size_t)row * HID + lane * 4) = o;
    if (STATS && lane == 0) { mu_out[row] = mu; rstd_out[row] = rstd; }
}

// ---------------- Final LayerNorm over concat(512): one wave per row ----------------
__global__ __launch_bounds__(256) void ln512_kernel(
    const float* __restrict__ a, const float* __restrict__ hd,
    const float* __restrict__ g, const float* __restrict__ b,
    float* __restrict__ out) {
    int wave = threadIdx.x >> 6, lane = threadIdx.x & 63;
    int row = blockIdx.x * 4 + wave;
    float4 v0 = *(const float4*)(a + (size_t)row * HID + lane * 4);
    float4 v1 = *(const float4*)(hd + (size_t)row * HID + lane * 4);
    float s = v0.x + v0.y + v0.z + v0.w + v1.x + v1.y + v1.z + v1.w;
#pragma unroll
    for (int off = 32; off; off >>= 1) s += __shfl_xor(s, off);
    float mu = s * (1.f / 512.f);
    float d0x = v0.x - mu, d0y = v0.y - mu, d0z = v0.z - mu, d0w = v0.w - mu;
    float d1x = v1.x - mu, d1y = v1.y - mu, d1z = v1.z - mu, d1w = v1.w - mu;
    float ss = d0x * d0x + d0y * d0y + d0z * d0z + d0w * d0w
             + d1x * d1x + d1y * d1y + d1z * d1z + d1w * d1w;
#pragma unroll
    for (int off = 32; off; off >>= 1) ss += __shfl_xor(ss, off);
    float r = rsqrtf(ss * (1.f / 512.f) + 1e-12f);
    float4 ga = *(const float4*)(g + lane * 4);
    float4 gb = *(const float4*)(g + 256 + lane * 4);
    float4 ba = *(const float4*)(b + lane * 4);
    float4 bb = *(const float4*)(b + 256 + lane * 4);
    float4 oa, ob;
    oa.x = d0x * r * ga.x + ba.x; oa.y = d0y * r * ga.y + ba.y;
    oa.z = d0z * r * ga.z + ba.z; oa.w = d0w * r * ga.w + ba.w;
    ob.x = d1x * r * gb.x + bb.x; ob.y = d1y * r * gb.y + bb.y;
    ob.z = d1z * r * gb.z + bb.z; ob.w = d1w * r * gb.w + bb.w;
    *(float4*)(out + (size_t)row * 512 + lane * 4) = oa;
    *(float4*)(out + (size_t)row * 512 + 256 + lane * 4) = ob;
}

// ---------------- weight transpose + f32->bf16, layer batched: W[K,N] -> Wt[N,K] ----------------
__global__ void wconv_kernel(const float* __restrict__ W, unsigned short* __restrict__ Wt,
                             int K, int N, size_t wstride, size_t tstride) {
    __shared__ float t[32][33];
    int l = blockIdx.z;
    W += (size_t)l * wstride;
    Wt += (size_t)l * tstride;
    int k0 = blockIdx.x * 32, n0 = blockIdx.y * 32;
    int tx = threadIdx.x & 31, ty = threadIdx.x >> 5;  // 32 x 8
#pragma unroll
    for (int i = 0; i < 32; i += 8) t[ty + i][tx] = W[(size_t)(k0 + ty + i) * N + n0 + tx];
    __syncthreads();
#pragma unroll
    for (int i = 0; i < 32; i += 8) Wt[(size_t)(n0 + ty + i) * K + k0 + tx] = f2bf(t[tx][ty + i]);
}

// ---------------- fused fp32 Wqk GEMM + LN-on-the-fly + qk-norm + LSH hash ----------------
// R10 structure; ONLY change: rot->rotLDS copy issued at kernel top (latency hidden under GEMM).
__global__ __launch_bounds__(256) void qkhash_kernel(
    const float* __restrict__ hid, const float* __restrict__ mu,
    const float* __restrict__ rstd, const float* __restrict__ gamma,
    const float* __restrict__ beta, const float* __restrict__ Wqk,
    const float* __restrict__ rot, unsigned short* __restrict__ kb,
    float* __restrict__ qscale, int* __restrict__ buckets) {
    __shared__ float As[16][68];
    __shared__ float Bs[16][68];
    __shared__ float QsT[64][68];     // [d][row]
    __shared__ float rotLDS[64][132]; // [d][col], both hash rounds
    int bm = blockIdx.x * 64;
    int h = blockIdx.y;
    int tid = threadIdx.x;
    int tx = tid & 15, ty = tid >> 4;
    // preload rot[h] (both rounds) -- distinct LDS region; fetch hidden under the GEMM
    const float* rp = rot + (size_t)h * DH * NHASH * NROT;
#pragma unroll
    for (int t = 0; t < 8; ++t) {
        int e = tid + t * 256;
        int d = e >> 5, c4 = e & 31;
        *(float4*)&rotLDS[d][c4 * 4] = *(const float4*)(rp + d * 128 + c4 * 4);
    }
    float acc[4][4] = {};
    for (int k0 = 0; k0 < HID; k0 += 16) {
#pragma unroll
        for (int t = 0; t < 4; ++t) {
            int e = tid + t * 256;
            int m = e >> 4, kk = e & 15;
            int row = bm + m;
            float x = hid[(size_t)row * HID + k0 + kk];
            As[kk][m] = (x - mu[row]) * rstd[row] * gamma[k0 + kk] + beta[k0 + kk];
        }
#pragma unroll
        for (int t = 0; t < 4; ++t) {
            int e = tid + t * 256;
            int kk = e >> 6, n = e & 63;
            Bs[kk][n] = Wqk[(size_t)(k0 + kk) * HID + h * DH + n];
        }
        __syncthreads();
#pragma unroll
        for (int kk = 0; kk < 16; ++kk) {
            float4 a4 = *(float4*)&As[kk][ty * 4];
            float4 b4 = *(float4*)&Bs[kk][tx * 4];
            float a0[4] = {a4.x, a4.y, a4.z, a4.w};
            float b0[4] = {b4.x, b4.y, b4.z, b4.w};
#pragma unroll
            for (int i = 0; i < 4; ++i)
#pragma unroll
                for (int j = 0; j < 4; ++j) acc[i][j] += a0[i] * b0[j];
        }
        __syncthreads();
    }
    // per-row ||q||^2 over this head's 64 dims (reduce across tx group)
    float ssq_[4];
#pragma unroll
    for (int i = 0; i < 4; ++i) {
        float s = 0;
#pragma unroll
        for (int j = 0; j < 4; ++j) s += acc[i][j] * acc[i][j];
        ssq_[i] = s;
    }
#pragma unroll
    for (int mask = 1; mask <= 8; mask <<= 1)
#pragma unroll
        for (int i = 0; i < 4; ++i) ssq_[i] += __shfl_xor(ssq_[i], mask);
    // write k_bf + qscale
#pragma unroll
    for (int i = 0; i < 4; ++i) {
        int row = bm + ty * 4 + i;
        float nrm = fmaxf(sqrtf(ssq_[i]), 1e-12f);
        float sc = 0.125f / nrm;
        ushort4 kv;
        kv.x = f2bf(acc[i][0] * sc); kv.y = f2bf(acc[i][1] * sc);
        kv.z = f2bf(acc[i][2] * sc); kv.w = f2bf(acc[i][3] * sc);
        *(ushort4*)(kb + (size_t)row * HID + h * DH + tx * 4) = kv;
        if (tx == 0) qscale[(size_t)row * NHEADS + h] = 8.f * nrm;
    }
    // stage QsT via contiguous float4 in transposed layout
#pragma unroll
    for (int j = 0; j < 4; ++j) {
        float4 v = make_float4(acc[0][j], acc[1][j], acc[2][j], acc[3][j]);
        *(float4*)&QsT[tx * 4 + j][ty * 4] = v;
    }
    __syncthreads();
    // hash: rotated = qk_tile @ rot, argmax over [rot, -rot]
    float acc2[4][8] = {};
#pragma unroll 2
    for (int d = 0; d < 64; ++d) {
        float4 a4 = *(float4*)&QsT[d][ty * 4];
        float a_[4] = {a4.x, a4.y, a4.z, a4.w};
        float4 b0 = *(float4*)&rotLDS[d][tx * 8];
        float4 b1v = *(float4*)&rotLDS[d][tx * 8 + 4];
#pragma unroll
        for (int i = 0; i < 4; ++i) {
            acc2[i][0] += a_[i] * b0.x;  acc2[i][1] += a_[i] * b0.y;
            acc2[i][2] += a_[i] * b0.z;  acc2[i][3] += a_[i] * b0.w;
            acc2[i][4] += a_[i] * b1v.x; acc2[i][5] += a_[i] * b1v.y;
            acc2[i][6] += a_[i] * b1v.z; acc2[i][7] += a_[i] * b1v.w;
        }
    }
    int n = tx >> 3;
#pragma unroll
    for (int i = 0; i < 4; ++i) {
        float bp = -3.4e38f, bn = -3.4e38f;
        int ipx = 0, inx = 0;
#pragma unroll
        for (int j = 0; j < 8; ++j) {
            float v = acc2[i][j];
            int r = ((tx & 7) * 8 + j);
            if (v > bp)  { bp = v;  ipx = r; }
            if (-v > bn) { bn = -v; inx = r; }
        }
#pragma unroll
        for (int mask = 1; mask <= 4; mask <<= 1) {
            float obp = __shfl_xor(bp, mask); int oip = __shfl_xor(ipx, mask);
            float obn = __shfl_xor(bn, mask); int oin = __shfl_xor(inx, mask);
            if (obp > bp || (obp == bp && oip < ipx)) { bp = obp; ipx = oip; }
            if (obn > bn || (obn == bn && oin < inx)) { bn = obn; inx = oin; }
        }
        if ((tx & 7) == 0) {
            int bucket = (bn > bp) ? (NROT + inx) : ipx;
            int row = bm + ty * 4 + i;
            int bb = row >> 13, sl = row & (SS - 1);
            buckets[(size_t)bb * NHEADS * NSEQ + h * NSEQ + n * SS + sl] = bucket + n * NBUCK;
        }
    }
}

// ---------------- bf16 MFMA GEMM with optional split-A / split-C at row SPLITROW ----------------
// EPI: 1 = bias+relu -> bf16, 2 = f32 C += acc, 3 = f32 C += acc + bias, 4 = store bf16,
//      5 = f32 C = Csrc + acc, 6 = f32 C = Csrc + acc + bias
template <int EPI>
__global__ __launch_bounds__(256) void mfma_gemm(
    const unsigned short* __restrict__ A, const unsigned short* __restrict__ A2,
    const unsigned short* __restrict__ Bt, const float* __restrict__ bias,
    void* __restrict__ Cv, void* __restrict__ Cv2,
    int M, int N, int K, const float* __restrict__ Csrc) {
    __shared__ unsigned short Asl[128 * 64];
    __shared__ unsigned short Bsl[128 * 64];
    int bm = blockIdx.x * 128, bn = blockIdx.y * 128;
    int tid = threadIdx.x;
    int wave = tid >> 6, lane = tid & 63;
    int wm = (wave >> 1) * 64, wn = (wave & 1) * 64;
    int lrow = lane & 15, lk = lane >> 4;
    const unsigned short* Ab = A + (size_t)bm * K;
    if (A2 != nullptr && bm >= SPLITROW) Ab = A2 + (size_t)(bm - SPLITROW) * K;
    bool chi = (Cv2 != nullptr) && (bm >= SPLITROW);
    void* Cb = chi ? Cv2 : Cv;
    int crow0 = chi ? SPLITROW : 0;
    f32x4 zero = {0.f, 0.f, 0.f, 0.f};
    f32x4 acc[4][4];
#pragma unroll
    for (int i = 0; i < 4; ++i)
#pragma unroll
        for (int j = 0; j < 4; ++j) acc[i][j] = zero;

    for (int k0 = 0; k0 < K; k0 += 64) {
#pragma unroll
        for (int t = 0; t < 4; ++t) {
            int e = tid + t * 256;
            int r = e >> 3, kc = (e & 7) * 8;
            int4 v = *(const int4*)(Ab + (size_t)r * K + k0 + kc);
            *(int4*)((char*)Asl + r * 128 + ((kc * 2) ^ ((r & 7) << 4))) = v;
        }
#pragma unroll
        for (int t = 0; t < 4; ++t) {
            int e = tid + t * 256;
            int r = e >> 3, kc = (e & 7) * 8;
            int4 v = *(const int4*)(Bt + (size_t)(bn + r) * K + k0 + kc);
            *(int4*)((char*)Bsl + r * 128 + ((kc * 2) ^ ((r & 7) << 4))) = v;
        }
        __syncthreads();
#pragma unroll
        for (int kk = 0; kk < 2; ++kk) {
            int klocal = kk * 32 + lk * 8;
            bf16x8 af[4], bfv[4];
#pragma unroll
            for (int fm = 0; fm < 4; ++fm) {
                int r = wm + fm * 16 + lrow;
                af[fm] = *(const bf16x8*)((const char*)Asl + r * 128 + ((klocal * 2) ^ ((r & 7) << 4)));
            }
#pragma unroll
            for (int fn = 0; fn < 4; ++fn) {
                int r = wn + fn * 16 + lrow;
                bfv[fn] = *(const bf16x8*)((const char*)Bsl + r * 128 + ((klocal * 2) ^ ((r & 7) << 4)));
            }
#pragma unroll
            for (int fm = 0; fm < 4; ++fm)
#pragma unroll
                for (int fn = 0; fn < 4; ++fn)
                    acc[fm][fn] = __builtin_amdgcn_mfma_f32_16x16x32_bf16(af[fm], bfv[fn], acc[fm][fn], 0, 0, 0);
        }
        __syncthreads();
    }
#pragma unroll
    for (int fm = 0; fm < 4; ++fm)
#pragma unroll
        for (int fn = 0; fn < 4; ++fn) {
            int col = bn + wn + fn * 16 + lrow;
#pragma unroll
            for (int r = 0; r < 4; ++r) {
                int row = bm + wm + fm * 16 + lk * 4 + r;
                size_t crow = (size_t)(row - crow0);
                float v = acc[fm][fn][r];
                if (EPI == 1) {
                    v += bias[col]; v = fmaxf(v, 0.f);
                    ((unsigned short*)Cb)[crow * N + col] = f2bf(v);
                } else if (EPI == 2) {
                    ((float*)Cb)[crow * N + col] += v;
                } else if (EPI == 3) {
                    ((float*)Cb)[crow * N + col] += v + bias[col];
                } else if (EPI == 4) {
                    ((unsigned short*)Cb)[crow * N + col] = f2bf(v);
                } else if (EPI == 5) {
                    ((float*)Cb)[crow * N + col] = Csrc[(size_t)row * N + col] + v;
                } else {
                    ((float*)Cb)[crow * N + col] = Csrc[(size_t)row * N + col] + v + bias[col];
                }
            }
        }
}

// ---------------- parallel stable counting sort: 256 threads, one block per (b,h) ----------------
// v2: parallel block scan for bin bases; bin base folded into replay (no add-back pass).
__global__ __launch_bounds__(256) void sort_kernel(const int* __restrict__ buckets,
                                                   int* __restrict__ sort_idx,
                                                   int* __restrict__ inv) {
    int bh = blockIdx.x;
    const int* bk = buckets + (size_t)bh * NSEQ;
    int* sj = sort_idx + (size_t)bh * NSEQ;
    int* ij = inv + (size_t)bh * NSEQ;
    __shared__ unsigned short cnt[256][258];  // [bin][thread-col], 132 KB
    __shared__ int colsum[256];
    __shared__ int wsum[4];
    int tid = threadIdx.x;
    unsigned* cz = (unsigned*)&cnt[0][0];
#pragma unroll
    for (int t = 0; t < 129; ++t) cz[tid * 129 + t] = 0;
    __syncthreads();
    int base = tid * 64;  // thread owns 64 contiguous items -> stability
    for (int j = 0; j < 64; j += 4) {
        int4 b4 = *(const int4*)(bk + base + j);
        cnt[b4.x][tid]++; cnt[b4.y][tid]++; cnt[b4.z][tid]++; cnt[b4.w][tid]++;
    }
    __syncthreads();
    {   // per-bin exclusive prefix across thread columns (bin = tid)
        int run = 0;
        for (int c = 0; c < 256; ++c) { int v = cnt[tid][c]; cnt[tid][c] = (unsigned short)run; run += v; }
        colsum[tid] = run;
    }
    __syncthreads();
    {   // block-wide exclusive scan of colsum (256 bins over 256 threads)
        int lane = tid & 63, wid = tid >> 6;
        int v = colsum[tid];
        int x = v;
#pragma unroll
        for (int off = 1; off < 64; off <<= 1) {
            int y = __shfl_up(x, off);
            if (lane >= off) x += y;
        }
        if (lane == 63) wsum[wid] = x;
        __syncthreads();
        int add = 0;
#pragma unroll
        for (int w = 0; w < 4; ++w) add += (w < wid) ? wsum[w] : 0;
        colsum[tid] = x - v + add;   // exclusive prefix = bin base
    }
    __syncthreads();
    // replay: rank = bin base + within-bin offset (cnt col prefix + running count)
    for (int j = 0; j < 64; j += 4) {
        int4 b4 = *(const int4*)(bk + base + j);
        int i0 = base + j;
        int r;
        r = (cnt[b4.x][tid]++) + colsum[b4.x]; sj[r] = i0;     ij[i0]     = r;
        r = (cnt[b4.y][tid]++) + colsum[b4.y]; sj[r] = i0 + 1; ij[i0 + 1] = r;
        r = (cnt[b4.z][tid]++) + colsum[b4.z]; sj[r] = i0 + 2; ij[i0 + 2] = r;
        r = (cnt[b4.w][tid]++) + colsum[b4.w]; sj[r] = i0 + 3; ij[i0 + 3] = r;
    }
}

// ---------------- MFMA chunked LSH attention (Q in registers; 37.4 KB LDS) ----------------
// grid (NCH, NHEADS, 4) -- blockIdx.z = batch; outs split lo (batches 0-1) / hi (2-3)
__global__ __launch_bounds__(256) void attn_mfma(
    const unsigned short* __restrict__ kbf, const unsigned short* __restrict__ vbf,
    const float* __restrict__ qscale, const int* __restrict__ sort_idx,
    unsigned short* __restrict__ outs_lo, unsigned short* __restrict__ outs_hi,
    float* __restrict__ logit_s) {
    __shared__ unsigned short KsPs[128][72];     // Ks during QK^T; Ps [64][136] overlay after
    __shared__ unsigned short VT[64][142];       // stride 142: 8*71 % 32 = 24 -> 4 bank groups
    __shared__ int qid[64];
    __shared__ int kid[128];
    unsigned short (*Ks)[72] = KsPs;
    unsigned short (*Ps)[136] = (unsigned short(*)[136])&KsPs[0][0];
    int c = blockIdx.x, h = blockIdx.y, z = blockIdx.z;
    kbf += (size_t)z * PBE;
    vbf += (size_t)z * PBE;
    qscale += (size_t)z * SS * NHEADS;
    sort_idx += (size_t)z * NHEADS * NSEQ;
    unsigned short* out_s = (z < 2) ? (outs_lo + (size_t)z * HNSD) : (outs_hi + (size_t)(z - 2) * HNSD);
    logit_s += (size_t)z * NHEADS * NSEQ;
    int tid = threadIdx.x;
    const int* si = sort_idx + (size_t)h * NSEQ;
    int cprev = (c == 0) ? (NCH - 1) : (c - 1);
    if (tid < 64) qid[tid] = si[c * 64 + tid];
    else if (tid < 192) {
        int k = tid - 64;
        kid[k] = (k < 64) ? si[cprev * 64 + k] : si[c * 64 + (k - 64)];
    }
    __syncthreads();
    int wave = tid >> 6, lane = tid & 63;
    int lrow = lane & 15, lk = lane >> 4;
    // Q fragments straight to registers
    int qsrow = qid[wave * 16 + lrow] & (SS - 1);
    float qsc = qscale[(size_t)qsrow * NHEADS + h];
    int4 qraw[2];
#pragma unroll
    for (int kk = 0; kk < 2; ++kk) {
        int4 raw = *(const int4*)(kbf + ((size_t)qsrow * HID + h * DH + kk * 32 + lk * 8));
        raw.x = (int)scale2((unsigned)raw.x, qsc);
        raw.y = (int)scale2((unsigned)raw.y, qsc);
        raw.z = (int)scale2((unsigned)raw.z, qsc);
        raw.w = (int)scale2((unsigned)raw.w, qsc);
        qraw[kk] = raw;
    }
    // K staging (128 x 64 bf16)
#pragma unroll
    for (int t = 0; t < 4; ++t) {
        int e = tid + t * 256;
        int row = e >> 3, seg = e & 7;
        int s = kid[row] & (SS - 1);
        *(int4*)&Ks[row][seg * 8] = *(const int4*)(kbf + ((size_t)s * HID + h * DH + seg * 8));
    }
    // V staging transposed
#pragma unroll
    for (int t = 0; t < 4; ++t) {
        int e = tid + t * 256;
        int row = e >> 3, seg = e & 7;
        int s = kid[row] & (SS - 1);
        ushort4 a = *(const ushort4*)(vbf + ((size_t)s * HID + h * DH + seg * 8));
        ushort4 bq = *(const ushort4*)(vbf + ((size_t)s * HID + h * DH + seg * 8 + 4));
        int d0 = seg * 8;
        VT[d0 + 0][row] = a.x;  VT[d0 + 1][row] = a.y;  VT[d0 + 2][row] = a.z;  VT[d0 + 3][row] = a.w;
        VT[d0 + 4][row] = bq.x; VT[d0 + 5][row] = bq.y; VT[d0 + 6][row] = bq.z; VT[d0 + 7][row] = bq.w;
    }
    __syncthreads();
    f32x4 zero = {0.f, 0.f, 0.f, 0.f};
    f32x4 sacc[8];
#pragma unroll
    for (int fn = 0; fn < 8; ++fn) sacc[fn] = zero;
#pragma unroll
    for (int kk = 0; kk < 2; ++kk) {
        bf16x8 af = *(bf16x8*)&qraw[kk];
#pragma unroll
        for (int fn = 0; fn < 8; ++fn) {
            bf16x8 bv = *(const bf16x8*)&Ks[fn * 16 + lrow][kk * 32 + lk * 8];
            sacc[fn] = __builtin_amdgcn_mfma_f32_16x16x32_bf16(af, bv, sacc[fn], 0, 0, 0);
        }
    }
    __syncthreads();   // all Ks reads complete before Ps overlays Ks
    int myq[4];
#pragma unroll
    for (int r = 0; r < 4; ++r) myq[r] = qid[wave * 16 + lk * 4 + r];
#pragma unroll
    for (int fn = 0; fn < 8; ++fn) {
        int kv = kid[lrow + fn * 16];
#pragma unroll
        for (int r = 0; r < 4; ++r)
            if (myq[r] == kv) sacc[fn][r] = MASKVAL;
    }
    float mx[4] = {-3.4e38f, -3.4e38f, -3.4e38f, -3.4e38f};
#pragma unroll
    for (int fn = 0; fn < 8; ++fn)
#pragma unroll
        for (int r = 0; r < 4; ++r) mx[r] = fmaxf(mx[r], sacc[fn][r]);
#pragma unroll
    for (int m = 1; m <= 8; m <<= 1)
#pragma unroll
        for (int r = 0; r < 4; ++r) mx[r] = fmaxf(mx[r], __shfl_xor(mx[r], m));
    float se[4] = {0.f, 0.f, 0.f, 0.f};
#pragma unroll
    for (int fn = 0; fn < 8; ++fn)
#pragma unroll
        for (int r = 0; r < 4; ++r) se[r] += __expf(sacc[fn][r] - mx[r]);
#pragma unroll
    for (int m = 1; m <= 8; m <<= 1)
#pragma unroll
        for (int r = 0; r < 4; ++r) se[r] += __shfl_xor(se[r], m);
    float lg[4];
#pragma unroll
    for (int r = 0; r < 4; ++r) lg[r] = mx[r] + __logf(se[r]);
#pragma unroll
    for (int fn = 0; fn < 8; ++fn)
#pragma unroll
        for (int r = 0; r < 4; ++r)
            Ps[wave * 16 + lk * 4 + r][lrow + fn * 16] = f2bf(__expf(sacc[fn][r] - lg[r]));
    if (lrow == 0) {
#pragma unroll
        for (int r = 0; r < 4; ++r)
            logit_s[(size_t)h * NSEQ + c * 64 + wave * 16 + lk * 4 + r] = lg[r];
    }
    __syncthreads();
    f32x4 oacc[4];
#pragma unroll
    for (int fn = 0; fn < 4; ++fn) oacc[fn] = zero;
#pragma unroll
    for (int ks = 0; ks < 4; ++ks) {
        bf16x8 af = *(const bf16x8*)&Ps[wave * 16 + lrow][ks * 32 + lk * 8];
#pragma unroll
        for (int fn = 0; fn < 4; ++fn) {
            bf16x8 bv = *(const bf16x8*)&VT[fn * 16 + lrow][ks * 32 + lk * 8];
            oacc[fn] = __builtin_amdgcn_mfma_f32_16x16x32_bf16(af, bv, oacc[fn], 0, 0, 0);
        }
    }
#pragma unroll
    for (int fn = 0; fn < 4; ++fn)
#pragma unroll
        for (int r = 0; r < 4; ++r) {
            int qrow = c * 64 + wave * 16 + lk * 4 + r;
            out_s[((size_t)h * NSEQ + qrow) * DH + lrow + fn * 16] = f2bf(oacc[fn][r]);
        }
}

// ---------------- unsort + combine hash rounds (all 4 batches) ----------------
__global__ void combine_kernel(const unsigned short* __restrict__ outs_lo,
                               const unsigned short* __restrict__ outs_hi,
                               const float* __restrict__ logit_s,
                               const int* __restrict__ inv, unsigned short* __restrict__ attn_comb) {
    size_t gid = (size_t)blockIdx.x * 256 + threadIdx.x;  // 4*H*S*16 threads
    int d4 = gid & 15;
    size_t r = gid >> 4;
    int s = (int)(r & (SS - 1));
    int h = (int)((r >> 13) & 3);
    int bl = (int)(r >> 15);                              // 0..3
    size_t hb = (size_t)(bl * NHEADS + h) * NSEQ;         // global (b,h) base for inv/logit
    const unsigned short* ob = (bl < 2) ? (outs_lo + (size_t)bl * HNSD)
                                        : (outs_hi + (size_t)(bl - 2) * HNSD);
    int j0 = inv[hb + s];
    int j1 = inv[hb + SS + s];
    float l0 = logit_s[hb + j0];
    float l1 = logit_s[hb + j1];
    float mxv = fmaxf(l0, l1);
    float e0 = __expf(l0 - mxv), e1 = __expf(l1 - mxv);
    float is = 1.f / (e0 + e1);
    float w0 = e0 * is, w1 = e1 * is;
    ushort4 u0 = *(const ushort4*)(ob + ((size_t)h * NSEQ + j0) * DH + d4 * 4);
    ushort4 u1 = *(const ushort4*)(ob + ((size_t)h * NSEQ + j1) * DH + d4 * 4);
    ushort4 o;
    o.x = f2bf(w0 * bf2f(u0.x) + w1 * bf2f(u1.x));
    o.y = f2bf(w0 * bf2f(u0.y) + w1 * bf2f(u1.y));
    o.z = f2bf(w0 * bf2f(u0.z) + w1 * bf2f(u1.z));
    o.w = f2bf(w0 * bf2f(u0.w) + w1 * bf2f(u1.w));
    *(ushort4*)(attn_comb + ((size_t)bl * SS + s) * HID + h * DH + d4 * 4) = o;
}

// ---------------- launch ----------------
extern "C" void kernel_launch(void* const* d_in, const int* in_sizes, int n_in,
                              void* d_out, int out_size, void* d_ws, size_t ws_size,
                              hipStream_t stream) {
    const float* hs  = (const float*)d_in[0];
    const float* g1  = (const float*)d_in[1];
    const float* b1  = (const float*)d_in[2];
    const float* Wqk = (const float*)d_in[3];
    const float* Wv  = (const float*)d_in[4];
    const float* Wo  = (const float*)d_in[5];
    const float* rot = (const float*)d_in[6];
    const float* g2  = (const float*)d_in[7];
    const float* b2  = (const float*)d_in[8];
    const float* W1  = (const float*)d_in[9];
    const float* bf1 = (const float*)d_in[10];
    const float* W2  = (const float*)d_in[11];
    const float* bf2 = (const float*)d_in[12];
    const float* gf  = (const float*)d_in[13];
    const float* bff = (const float*)d_in[14];

    const size_t NE = (size_t)BB * SS * HID;    // 8,388,608
    const size_t MROWS = (size_t)BB * SS;       // 32768

    // ---- d_ws layout (~91.5 MB; <= 93.3 MB proven in R2) ----
    float* f = (float*)d_ws;
    float* attn_out = f;                               // NE f32
    float* hidden   = f + NE;                          // NE f32
    float* mu       = f + 2 * NE;                      // 32768
    float* rstd     = mu + MROWS;                      // 32768
    float* qscale   = rstd + MROWS;                    // B*S*H = 131072
    float* logit_all = qscale + MROWS * NHEADS;        // B*H*NSEQ = 262144
    int* sortx = (int*)(logit_all + (size_t)BB * NHEADS * NSEQ);
    int* invx  = sortx + (size_t)BB * NHEADS * NSEQ;
    int* buckx = invx + (size_t)BB * NHEADS * NSEQ;
    unsigned short* wbf = (unsigned short*)(buckx + (size_t)BB * NHEADS * NSEQ);  // 2*655360 ushort
    unsigned short* outs_hi = wbf + 2 * 655360;        // 16.78 MB: attn outs (b2-3) / ffbuf part2

    // ---- d_out scratch (4 slots of 4,194,304 floats) ----
    float* o = (float*)d_out;
    unsigned short* abuf = (unsigned short*)o;              // slot0: xln_bf / attn_comb / h_ln
    unsigned short* outs_lo = (unsigned short*)(o + 4194304); // slot1: batches 0-1 sorted attn out
    unsigned short* k_bf = (unsigned short*)(o + 8388608);  // slot2
    unsigned short* v_bf = (unsigned short*)(o + 12582912); // slot3
    unsigned short* ffbuf1 = outs_lo;                       // phase D: slots 1-3 = rows [0,24576)
    unsigned short* ffbuf2 = outs_hi;                       // phase D: rows [24576,32768)

    // convert + transpose weights to bf16 once (layer-batched grids)
    wconv_kernel<<<dim3(HID / 32, HID / 32, NLAYERS), 256, 0, stream>>>(Wv, wbf, HID, HID, (size_t)HID * HID, 655360);
    wconv_kernel<<<dim3(HID / 32, HID / 32, NLAYERS), 256, 0, stream>>>(Wo, wbf + 65536, HID, HID, (size_t)HID * HID, 655360);
    wconv_kernel<<<dim3(HID / 32, FFD / 32, NLAYERS), 256, 0, stream>>>(W1, wbf + 131072, HID, FFD, (size_t)HID * FFD, 655360);
    wconv_kernel<<<dim3(FFD / 32, HID / 32, NLAYERS), 256, 0, stream>>>(W2, wbf + 393216, FFD, HID, (size_t)FFD * HID, 655360);

    for (int l = 0; l < NLAYERS; ++l) {
        const float* g1l = g1 + l * HID;
        const float* b1l = b1 + l * HID;
        const float* Wqkl = Wqk + (size_t)l * HID * HID;
        const float* rotl = rot + (size_t)l * NHEADS * DH * NHASH * NROT;
        const float* g2l = g2 + l * HID;
        const float* b2l = b2 + l * HID;
        const float* bf1l = bf1 + l * FFD;
        const float* bf2l = bf2 + l * HID;
        unsigned short* Wv_t = wbf + (size_t)l * 655360;
        unsigned short* Wo_t = Wv_t + 65536;
        unsigned short* W1_t = Wv_t + 131072;
        unsigned short* W2_t = Wv_t + 393216;
        const float* hid_in = (l == 0) ? hs : hidden;   // layer 0 reads inputs directly

        // ---- phase A (all-batch): LN(+stats) -> fused Wqk+hash -> Wv ----
        ln256_kernel<true><<<MROWS / 4, 256, 0, stream>>>(hid_in, g1l, b1l, abuf, mu, rstd);
        qkhash_kernel<<<dim3(MROWS / 64, NHEADS), 256, 0, stream>>>(
            hid_in, mu, rstd, g1l, b1l, Wqkl, rotl, k_bf, qscale, buckx);
        mfma_gemm<4><<<dim3(MROWS / 128, HID / 128), 256, 0, stream>>>(
            abuf, nullptr, Wv_t, nullptr, v_bf, nullptr, MROWS, HID, HID, nullptr);

        // ---- phase B: sort all (b,h) ----
        sort_kernel<<<BB * NHEADS, 256, 0, stream>>>(buckx, sortx, invx);

        // ---- phase C: attention (all 4 batches in one launch) + combine + Wo ----
        attn_mfma<<<dim3(NCH, NHEADS, BB), 256, 0, stream>>>(
            k_bf, v_bf, qscale, sortx, outs_lo, outs_hi, logit_all);
        combine_kernel<<<(BB * NHEADS * SS * 16) / 256, 256, 0, stream>>>(
            outs_lo, outs_hi, logit_all, invx, abuf);
        if (l == 0)
            mfma_gemm<5><<<dim3(MROWS / 128, HID / 128), 256, 0, stream>>>(
                abuf, nullptr, Wo_t, nullptr, attn_out, nullptr, MROWS, HID, HID, hs);
        else
            mfma_gemm<2><<<dim3(MROWS / 128, HID / 128), 256, 0, stream>>>(
                abuf, nullptr, Wo_t, nullptr, attn_out, nullptr, MROWS, HID, HID, nullptr);

        // ---- phase D: FF single-launch over M=32768 with split ffbuf ----
        ln256_kernel<false><<<MROWS / 4, 256, 0, stream>>>(attn_out, g2l, b2l, abuf, nullptr, nullptr);
        mfma_gemm<1><<<dim3(MROWS / 128, FFD / 128), 256, 0, stream>>>(
            abuf, nullptr, W1_t, bf1l, ffbuf1, ffbuf2, MROWS, FFD, HID, nullptr);
        if (l == 0)
            mfma_gemm<6><<<dim3(MROWS / 128, HID / 128), 256, 0, stream>>>(
                ffbuf1, ffbuf2, W2_t, bf2l, hidden, nullptr, MROWS, HID, FFD, hs);
        else
            mfma_gemm<3><<<dim3(MROWS / 128, HID / 128), 256, 0, stream>>>(
                ffbuf1, ffbuf2, W2_t, bf2l, hidden, nullptr, MROWS, HID, FFD, nullptr);
    }
    ln512_kernel<<<MROWS / 4, 256, 0, stream>>>(attn_out, hidden, gf, bff, (float*)d_out);
}